// Round 7
// baseline (350.038 us; speedup 1.0000x reference)
//
#include <hip/hip_runtime.h>
#include <math.h>

#define B_ 16
#define N_ 1024
#define KNN 20
#define NPAIR (B_*N_)

typedef __attribute__((ext_vector_type(8))) short bf16x8;
typedef __attribute__((ext_vector_type(4))) float f32x4;

// ---------- helpers ----------
__device__ __forceinline__ unsigned fkey(float f) {
  unsigned u = __float_as_uint(f);
  return (u & 0x80000000u) ? ~u : (u | 0x80000000u);
}
__device__ __forceinline__ float fkeyinv(unsigned u) {
  unsigned b = (u & 0x80000000u) ? (u ^ 0x80000000u) : ~u;
  return __uint_as_float(b);
}
__device__ __forceinline__ unsigned short f2bf(float x) {  // RNE float->bf16
  unsigned u = __float_as_uint(x);
  unsigned r = (u + 0x7FFFu + ((u >> 16) & 1u)) >> 16;
  return (unsigned short)r;
}
__device__ __forceinline__ float bf2f(unsigned short u) {
  return __uint_as_float(((unsigned)u) << 16);
}
__device__ __forceinline__ unsigned short f2h(float x) {   // RNE float->fp16
  _Float16 h = (_Float16)x;
  return *(unsigned short*)&h;
}
__device__ __forceinline__ float h2f(unsigned short u) {
  _Float16 h = *(_Float16*)&u;
  return (float)h;
}
// packed knn key: top 22 bits of fkey(d) | (1023 - idx). u32 '>' == dist desc, idx asc.
__device__ __forceinline__ unsigned knnkey(float d, int idx) {
  return (fkey(d) & 0xFFFFFC00u) | (unsigned)(1023 - idx);
}

// Branchless sorted-insert (descending) of packed u32 key: 2 ops/stage.
__device__ __forceinline__ void topk_insert_u32(unsigned (&kl)[KNN], unsigned nk) {
  kl[KNN-1] = nk;
  #pragma unroll
  for (int i = KNN-1; i > 0; i--) {
    unsigned hi = max(kl[i-1], kl[i]);
    unsigned lo = min(kl[i-1], kl[i]);
    kl[i-1] = hi; kl[i] = lo;
  }
}

// count of elements strictly greater than v in sorted-desc list L of 20 (5-step bsearch)
__device__ __forceinline__ int cnt_gt(const unsigned* __restrict__ L, unsigned v) {
  int j = 0;
  #pragma unroll
  for (int s = 16; s; s >>= 1) {
    int nj = j + s;
    if (nj <= KNN && L[nj-1] > v) j = nj;
  }
  return j;
}

// ---------- 1) fused prep + knn1: blocks 0..511 = knn1 8-way split; 512..1535 = prep ----------
__global__ void __launch_bounds__(256) k_prep_knn1(const float* __restrict__ x,
        float* __restrict__ xp1, const float* __restrict__ w2, const float* __restrict__ w3,
        unsigned short* __restrict__ w2h, unsigned short* __restrict__ wt3h,
        unsigned* __restrict__ keypart) {
  __shared__ float P[N_*3];
  __shared__ float XX[N_];
  if (blockIdx.x >= 512) {
    int i = (blockIdx.x - 512) * 256 + threadIdx.x;
    if (i < NPAIR) {
      float a0 = x[i*3+0], a1 = x[i*3+1], a2 = x[i*3+2];
      float n = sqrtf(a0*a0 + a1*a1 + a2*a2);
      n = fmaxf(n, 1e-15f);
      float th = tanhf(0.1f * n);
      float sc = th / (0.1f * n);
      float ny = fmaxf(th * 10.0f, 1e-15f);
      float mxn = (1.0f - 4e-3f) / 0.1f;
      if (ny > mxn) sc *= mxn / ny;
      xp1[i*3+0] = sc*a0; xp1[i*3+1] = sc*a1; xp1[i*3+2] = sc*a2;
    }
    if (i < 192*128) w2h[i] = f2bf(w2[i]);
    wt3h[i] = f2bf(w3[i]);
    return;
  }
  int blk = blockIdx.x;
  int b = blk >> 5, rc = (blk >> 3) & 3, cc = blk & 7;
  const float* xb = x + b*N_*3;
  for (int e = threadIdx.x; e < N_*3; e += 256) P[e] = xb[e];
  __syncthreads();
  for (int j = threadIdx.x; j < N_; j += 256) {
    float q0 = P[j*3], q1 = P[j*3+1], q2 = P[j*3+2];
    XX[j] = q0*q0 + q1*q1 + q2*q2;
  }
  __syncthreads();
  int r = rc*256 + threadIdx.x;
  float q0 = P[r*3], q1 = P[r*3+1], q2 = P[r*3+2];
  float xxq = XX[r];
  unsigned kl[KNN];
  #pragma unroll
  for (int i = 0; i < KNN; i++) kl[i] = 0u;
  int cbase = cc*128;
  for (int jj = 0; jj < 128; jj++) {
    int j = cbase + jj;
    float dot = q0*P[j*3] + q1*P[j*3+1] + q2*P[j*3+2];
    float d = 2.0f*dot - xxq - XX[j];
    unsigned nk = knnkey(d, j);
    if (nk > kl[KNN-1]) topk_insert_u32(kl, nk);
  }
  int p = b*N_ + r;
  unsigned* pe = keypart + (size_t)p*160 + cc*20;
  #pragma unroll
  for (int i = 0; i < KNN; i++) pe[i] = kl[i];
}

// ---------- 3) conv1 fused v2: parallel pairwise merge tree (8->4->2->1), fp32 stats ----------
__global__ void __launch_bounds__(256) k_conv1(const float* __restrict__ xp1,
                        const unsigned* __restrict__ keypart,
                        const float* __restrict__ w1, float* __restrict__ hmax1,
                        float* __restrict__ hmin1, float* __restrict__ stats1sh) {
  __shared__ float F[4][KNN][6];
  __shared__ float red[4][64][2];
  __shared__ int idxs[16][KNN];
  __shared__ unsigned keybuf[2560];   // 16 pairs x 160 keys, 10 KB
  __shared__ unsigned out1[1280];     // level-1 merged: 16 pts x 4 lists x 20
  __shared__ unsigned out2[640];      // level-2 merged: 16 pts x 2 lists x 20
  int g = threadIdx.x >> 6, lane = threadIdx.x & 63;
  int tid = threadIdx.x;
  int pbase = blockIdx.x * 16;
  {
    const unsigned* src = keypart + (size_t)pbase*160;
    for (int e = tid; e < 2560; e += 256) keybuf[e] = src[e];
  }
  float w[6];
  #pragma unroll
  for (int c = 0; c < 6; c++) w[c] = w1[lane*6 + c];
  __syncthreads();
  // L1: merge (2m, 2m+1) -> out1[pt][m][.]  (2560 items, all parallel)
  for (int e = tid; e < 2560; e += 256) {
    int pt = e / 160, rem = e - pt*160;
    int m = rem / 40, i = rem - m*40;
    const unsigned* A = keybuf + pt*160 + (2*m)*20;
    const unsigned* Bl = A + 20;
    unsigned v; const unsigned* S; int own;
    if (i < 20) { v = A[i]; S = Bl; own = i; }
    else { v = Bl[i-20]; S = A; own = i-20; }
    int rank = own + cnt_gt(S, v);
    if (rank < KNN) out1[(pt*4 + m)*20 + rank] = v;
  }
  __syncthreads();
  // L2: merge (2m2, 2m2+1) of out1 -> out2[pt][m2][.]  (1280 items)
  for (int e = tid; e < 1280; e += 256) {
    int pt = e / 80, rem = e - pt*80;
    int m2 = rem / 40, i = rem - m2*40;
    const unsigned* A = out1 + (pt*4 + 2*m2)*20;
    const unsigned* Bl = A + 20;
    unsigned v; const unsigned* S; int own;
    if (i < 20) { v = A[i]; S = Bl; own = i; }
    else { v = Bl[i-20]; S = A; own = i-20; }
    int rank = own + cnt_gt(S, v);
    if (rank < KNN) out2[(pt*2 + m2)*20 + rank] = v;
  }
  __syncthreads();
  // L3: final merge -> idxs  (640 items)
  for (int e = tid; e < 640; e += 256) {
    int pt = e / 40, i = e - pt*40;
    const unsigned* A = out2 + pt*40;
    const unsigned* Bl = A + 20;
    unsigned v; const unsigned* S; int own;
    if (i < 20) { v = A[i]; S = Bl; own = i; }
    else { v = Bl[i-20]; S = A; own = i-20; }
    int rank = own + cnt_gt(S, v);
    if (rank < KNN) idxs[pt][rank] = 1023 - (int)(v & 1023u);
  }
  float sum = 0.f, sumsq = 0.f;
  __syncthreads();
  for (int it = 0; it < 4; ++it) {
    int p = pbase + it*4 + g;
    if (lane < KNN) {
      int nb = idxs[it*4 + g][lane];
      int bb = p >> 10;
      const float* xc = xp1 + p*3;
      const float* ft = xp1 + (bb*N_ + nb)*3;
      float x0 = ft[0], x1 = ft[1], x2v = ft[2];
      float c0 = xc[0], c1 = xc[1], c2 = xc[2];
      float X2 = x0*x0 + x1*x1 + x2v*x2v;
      float Y2 = c0*c0 + c1*c1 + c2*c2;
      float XY = -(x0*c0 + x1*c1 + x2v*c2);
      float den = fmaxf(1.0f + 0.02f*XY + 1e-4f*X2*Y2, 1e-15f);
      float s1 = (1.0f + 0.02f*XY + 0.01f*Y2) / den;
      float s2 = (1.0f - 0.01f*X2) / den;
      F[g][lane][0] = s1*x0 - s2*c0;
      F[g][lane][1] = s1*x1 - s2*c1;
      F[g][lane][2] = s1*x2v - s2*c2;
      F[g][lane][3] = c0; F[g][lane][4] = c1; F[g][lane][5] = c2;
    }
    __syncthreads();
    float mx = -__builtin_inff(), mn = __builtin_inff();
    for (int k = 0; k < KNN; k++) {
      float h = 0.f;
      #pragma unroll
      for (int c = 0; c < 6; c++) h = fmaf(w[c], F[g][k][c], h);
      mx = fmaxf(mx, h); mn = fminf(mn, h);
      sum += h; sumsq += h*h;
    }
    hmax1[(pbase + it*4 + g)*64 + lane] = mx;
    hmin1[(pbase + it*4 + g)*64 + lane] = mn;
    __syncthreads();
  }
  red[g][lane][0] = sum; red[g][lane][1] = sumsq;
  __syncthreads();
  if (g == 0) {
    float s  = red[0][lane][0] + red[1][lane][0] + red[2][lane][0] + red[3][lane][0];
    float s2 = red[0][lane][1] + red[1][lane][1] + red[2][lane][1] + red[3][lane][1];
    float* dst = stats1sh + ((size_t)(blockIdx.x & 63)*64 + lane)*2;
    atomicAdd(dst, s);
    atomicAdd(dst + 1, s2);
  }
}

// ---------- BN stat reduce v4 (fp32 slots, f64 cross-slot accumulation) ----------
__global__ void __launch_bounds__(64) k_bn_reduce(const float* __restrict__ sh, int nch, int nslots,
                            double cnt,
                            const float* __restrict__ g, const float* __restrict__ bb,
                            float* __restrict__ scale, float* __restrict__ shift) {
  int o = blockIdx.x, t = threadIdx.x;
  double s = 0.0, s2 = 0.0;
  for (int sl = t; sl < nslots; sl += 64) {
    s  += (double)sh[((size_t)sl*nch + o)*2];
    s2 += (double)sh[((size_t)sl*nch + o)*2 + 1];
  }
  #pragma unroll
  for (int off = 32; off > 0; off >>= 1) { s += __shfl_xor(s, off); s2 += __shfl_xor(s2, off); }
  if (t == 0) {
    double m = s / cnt;
    double v = s2 / cnt - m*m;
    float a = g[o] / sqrtf((float)v + 1e-5f);
    scale[o] = a;
    shift[o] = bb[o] - a * (float)m;
  }
}

// ---------- 5) BN1 apply + relu + e2p + bf16 hi/lo split for MFMA knn2 + |x1|^2 ----------
__global__ void __launch_bounds__(256) k_bn1_apply(const float* __restrict__ hmax1, const float* __restrict__ hmin1,
                            const float* __restrict__ scale1, const float* __restrict__ shift1,
                            float* __restrict__ xp2,
                            unsigned short* __restrict__ x1h, unsigned short* __restrict__ x1l,
                            float* __restrict__ xx1) {
  int b = blockIdx.x >> 4, nc = blockIdx.x & 15;
  int c = threadIdx.x & 63, sub = threadIdx.x >> 6;
  int n0 = nc*64 + sub*16;
  float a = scale1[c], t = shift1[c];
  #pragma unroll
  for (int i = 0; i < 16; i++) {
    int p = b*1024 + n0 + i;
    float h = (a >= 0.f) ? hmax1[(size_t)p*64 + c] : hmin1[(size_t)p*64 + c];
    float x1 = fmaxf(fmaf(a, h, t), 0.f);
    // split-bf16: x1 = hi + lo with both bf16; dot via 4-term MFMA is fp32-accurate to ~2^-17
    unsigned short hb = f2bf(x1);
    x1h[(size_t)p*64 + c] = hb;
    x1l[(size_t)p*64 + c] = f2bf(x1 - bf2f(hb));
    float n2 = x1*x1;
    #pragma unroll
    for (int off = 32; off > 0; off >>= 1) n2 += __shfl_xor(n2, off);
    if (c == 0) xx1[p] = n2;
    float n1 = fmaxf(sqrtf(n2), 1e-15f);
    float th = tanhf(0.1f * n1);
    float sc = th / (0.1f * n1);
    float ny = fmaxf(th * 10.0f, 1e-15f);
    float mxn = (1.0f - 4e-3f) / 0.1f;
    if (ny > mxn) sc *= mxn / ny;
    xp2[(size_t)p*64 + c] = sc * x1;
  }
}

// ---------- 6) knn2 v9: barrier-free scan (private per-wave dist slice) + parallel rank-merge ----------
// Block = 64 queries x 256 candidates (4 stages of 64). Wave w owns cands [w*16, w*16+16) per stage.
// Wave writes D to its OWN pad-17 slice (2-way banks, free) and reads it back -- no cross-wave deps,
// so the scan loop has ZERO barriers. Merge: pairwise parallel rank-merge (L0,L1)x(L2,L3) -> final.
__global__ void __launch_bounds__(256) k_knn2g(const unsigned short* __restrict__ x1h,
        const unsigned short* __restrict__ x1l,
        const float* __restrict__ xx1, unsigned* __restrict__ keypart2) {
  __shared__ __align__(16) float SLC[4352];      // 4 waves x 64q x 17 floats (17 KB); merge M overlay
  __shared__ unsigned LU[5376];                  // 4 lists x 64q x 21 (21 KB)
  int tid = threadIdx.x;
  int bi = blockIdx.x;
  int blk = ((bi & 7) << 7) + (bi >> 3);     // XCD-affine swizzle (1024 = 8*128, bijective)
  int b = blk >> 6, qc = (blk >> 2) & 15, cc = blk & 3;
  int qbase = qc*64, ccbase = cc*256;
  int wave = tid >> 6, lane = tid & 63;
  int lm = lane & 15, kq = lane >> 4;
  const size_t base = (size_t)b * 65536;     // b*1024*64
  float* SW = SLC + wave*1088;               // private 64x17 slice

  // Q fragments (hi/lo) held in registers for the whole kernel: 4 qtiles x 2 ksteps
  bf16x8 Qh[4][2], Ql[4][2];
  #pragma unroll
  for (int qt = 0; qt < 4; qt++) {
    size_t ro = base + (size_t)(qbase + qt*16 + lm)*64 + kq*8;
    #pragma unroll
    for (int ks = 0; ks < 2; ks++) {
      Qh[qt][ks] = *((const bf16x8*)(x1h + ro + ks*32));
      Ql[qt][ks] = *((const bf16x8*)(x1l + ro + ks*32));
    }
  }
  unsigned kl[KNN];
  #pragma unroll
  for (int i = 0; i < KNN; i++) kl[i] = 0u;

  for (int st = 0; st < 4; ++st) {
    int cb0 = ccbase + st*64;
    // A fragments: this wave's 16 candidates, hi/lo
    size_t co = base + (size_t)(cb0 + wave*16 + lm)*64 + kq*8;
    bf16x8 Ah[2], Al[2];
    #pragma unroll
    for (int ks = 0; ks < 2; ks++) {
      Ah[ks] = *((const bf16x8*)(x1h + co + ks*32));
      Al[ks] = *((const bf16x8*)(x1l + co + ks*32));
    }
    float4 xxc = *((const float4*)(xx1 + b*1024 + cb0 + wave*16 + kq*4));
    f32x4 acc[4];
    #pragma unroll
    for (int qt = 0; qt < 4; qt++) acc[qt] = (f32x4){0.f, 0.f, 0.f, 0.f};
    #pragma unroll
    for (int ks = 0; ks < 2; ks++) {
      #pragma unroll
      for (int qt = 0; qt < 4; qt++) {
        acc[qt] = __builtin_amdgcn_mfma_f32_16x16x32_bf16(Ah[ks], Qh[qt][ks], acc[qt], 0, 0, 0);
        acc[qt] = __builtin_amdgcn_mfma_f32_16x16x32_bf16(Ah[ks], Ql[qt][ks], acc[qt], 0, 0, 0);
        acc[qt] = __builtin_amdgcn_mfma_f32_16x16x32_bf16(Al[ks], Qh[qt][ks], acc[qt], 0, 0, 0);
        acc[qt] = __builtin_amdgcn_mfma_f32_16x16x32_bf16(Al[ks], Ql[qt][ks], acc[qt], 0, 0, 0);
      }
    }
    float xxcv[4] = {xxc.x, xxc.y, xxc.z, xxc.w};
    // write own slice: row = query, col = local cand (kq*4+r); pad-17 rows, 2-way banks
    #pragma unroll
    for (int qt = 0; qt < 4; qt++) {
      int q = qt*16 + lm;
      #pragma unroll
      for (int r = 0; r < 4; r++) {
        // -xxq omitted: constant per query row, rank-invariant
        SW[q*17 + kq*4 + r] = 2.0f*acc[qt][r] - xxcv[r];
      }
    }
    // read back: lane = query, scan the wave's 16 candidates (in-order DS per wave -> no barrier)
    #pragma unroll
    for (int j = 0; j < 16; j++) {
      float d = SW[lane*17 + j];
      unsigned nk = knnkey(d, cb0 + wave*16 + j);
      if (nk > kl[KNN-1]) topk_insert_u32(kl, nk);
    }
  }
  // publish per-wave lists
  #pragma unroll
  for (int i = 0; i < KNN; i++) LU[wave*1344 + lane*21 + i] = kl[i];
  __syncthreads();
  // merge level 1: (L0,L1)->M0, (L2,L3)->M1.  5120 items, rank = own idx + 1 bsearch.
  unsigned* MU = (unsigned*)SLC;
  for (int e = tid; e < 5120; e += 256) {
    int pair = e / 2560;
    int rem = e - pair*2560;
    int q = rem / 40;
    int i40 = rem - q*40;
    int side = (i40 >= 20) ? 1 : 0;
    int idx = i40 - side*20;
    int own = pair*2 + side, oth = pair*2 + (1 - side);
    unsigned v = LU[own*1344 + q*21 + idx];
    int rank = idx + cnt_gt(LU + oth*1344 + q*21, v);
    if (rank < KNN) MU[pair*1344 + q*21 + rank] = v;
  }
  __syncthreads();
  // merge level 2: (M0,M1) -> keypart2.  2560 items.
  for (int e = tid; e < 2560; e += 256) {
    int q = e / 40;
    int i40 = e - q*40;
    int side = (i40 >= 20) ? 1 : 0;
    int idx = i40 - side*20;
    unsigned v = MU[side*1344 + q*21 + idx];
    int rank = idx + cnt_gt(MU + (1 - side)*1344 + q*21, v);
    if (rank < KNN)
      keypart2[(size_t)(b*N_ + qbase + q)*80 + cc*20 + rank] = v;
  }
}

// ---------- 9) conv2 via bf16 MFMA v11: v9 structure + fp16 hmax/hmin + fp32 stats ----------
__global__ void __launch_bounds__(256) k_conv2m(const float* __restrict__ xp2,
    const unsigned* __restrict__ keypart2, const unsigned short* __restrict__ w2h,
    unsigned short* __restrict__ hmax2, unsigned short* __restrict__ hmin2,
    float* __restrict__ stats2sh) {
  __shared__ __align__(16) short Abf[80*136];
  __shared__ __align__(16) float Cf[4][64];      // fp32 centers for Mobius math
  __shared__ float Yc[4];
  __shared__ int nbr[80];                        // logical order [pt*20 + k]
  __shared__ unsigned keybuf[320];               // 4 pairs x 80 keys
  int tid = threadIdx.x;
  int bi = blockIdx.x;
  int g512 = ((bi & 7) << 9) + (bi >> 3);
  int p0 = g512 * 4;
  int b = p0 >> 10;
  // Region A: stage merge keys (all threads) + center rows/Y2 (first wave) concurrently
  for (int e = tid; e < 320; e += 256) keybuf[e] = keypart2[(size_t)p0*80 + e];
  if (tid < 64) {
    int pt = tid >> 4, qq = tid & 15;
    float4 cv = *((const float4*)(xp2 + (size_t)(p0 + pt)*64) + qq);
    *((float4*)&Cf[pt][qq*4]) = cv;
    float y2 = cv.x*cv.x + cv.y*cv.y + cv.z*cv.z + cv.w*cv.w;
    #pragma unroll
    for (int off = 8; off > 0; off >>= 1) y2 += __shfl_xor(y2, off);
    if (qq == 0) Yc[pt] = y2;
    ushort4 cb;
    cb.x = f2bf(cv.x); cb.y = f2bf(cv.y); cb.z = f2bf(cv.z); cb.w = f2bf(cv.w);
    // replicate center into the 20 MFMA rows of this point: rows a*16 + pt*4 + j
    #pragma unroll
    for (int a = 0; a < 5; a++)
      #pragma unroll
      for (int j2 = 0; j2 < 4; j2++)
        *((ushort4*)(Abf + (a*16 + pt*4 + j2)*136 + 64 + qq*4)) = cb;
  }
  __syncthreads();
  // Region B: parallel rank-based 4-way merge. 320 items; rank = own idx + 3 binary searches.
  for (int e = tid; e < 320; e += 256) {
    int pt = e / 80;
    int rem = e - pt*80;
    int c = rem / 20;
    int i = rem - c*20;
    const unsigned* LB = keybuf + pt*80;
    unsigned v = LB[c*20 + i];
    int rank = i;
    #pragma unroll
    for (int c2 = 0; c2 < 4; c2++) {
      if (c2 == c) continue;
      rank += cnt_gt(LB + c2*20, v);
    }
    if (rank < KNN) nbr[pt*20 + rank] = 1023 - (int)(v & 1023u);
  }
  __syncthreads();
  // Region C: gather + Mobius in one pass, all fp32 (center from Cf), single divide
  for (int e = tid; e < 80*16; e += 256) {
    int r = e >> 4, qq = e & 15;
    int q = (r >> 2) & 3;
    int L = 20*q + 4*(r >> 4) + (r & 3);
    float4 f = *((const float4*)(xp2 + (size_t)(b*N_ + nbr[L])*64) + qq);
    float4 cvf = *((const float4*)&Cf[q][qq*4]);
    float X2 = f.x*f.x + f.y*f.y + f.z*f.z + f.w*f.w;
    float XY = -(f.x*cvf.x + f.y*cvf.y + f.z*cvf.z + f.w*cvf.w);
    #pragma unroll
    for (int off = 8; off > 0; off >>= 1) {
      X2 += __shfl_xor(X2, off);
      XY += __shfl_xor(XY, off);
    }
    float Y2 = Yc[q];
    float den = fmaxf(1.0f + 0.02f*XY + 1e-4f*X2*Y2, 1e-15f);
    float inv = 1.0f / den;
    float s1 = (1.0f + 0.02f*XY + 0.01f*Y2) * inv;
    float s2 = (1.0f - 0.01f*X2) * inv;
    ushort4 mo;
    mo.x = f2bf(s1*f.x - s2*cvf.x);
    mo.y = f2bf(s1*f.y - s2*cvf.y);
    mo.z = f2bf(s1*f.z - s2*cvf.z);
    mo.w = f2bf(s1*f.w - s2*cvf.w);
    *((ushort4*)(Abf + r*136 + qq*4)) = mo;
  }
  __syncthreads();
  // Region D: MFMA + register epilogue (fp16 max/min stores, fp32 stats atomics)
  int wave = tid >> 6, lane = tid & 63;
  int quad = lane >> 4, lm = lane & 15;
  int colbase = wave*48;
  f32x4 acc[5][3];
  #pragma unroll
  for (int rt = 0; rt < 5; rt++)
    #pragma unroll
    for (int cj = 0; cj < 3; cj++) acc[rt][cj] = (f32x4){0.f, 0.f, 0.f, 0.f};
  #pragma unroll
  for (int kt = 0; kt < 4; kt++) {
    int k0 = kt*32 + quad*8;
    bf16x8 bf[3];
    #pragma unroll
    for (int cj = 0; cj < 3; cj++)
      bf[cj] = *((const bf16x8*)(w2h + (size_t)(colbase + cj*16 + lm)*128 + k0));
    bf16x8 af[5];
    #pragma unroll
    for (int rt = 0; rt < 5; rt++)
      af[rt] = *((const bf16x8*)(Abf + (rt*16 + lm)*136 + k0));
    #pragma unroll
    for (int rt = 0; rt < 5; rt++)
      #pragma unroll
      for (int cj = 0; cj < 3; cj++)
        acc[rt][cj] = __builtin_amdgcn_mfma_f32_16x16x32_bf16(af[rt], bf[cj], acc[rt][cj], 0, 0, 0);
  }
  #pragma unroll
  for (int cj = 0; cj < 3; cj++) {
    int o = colbase + cj*16 + lm;
    float s = 0.f, s2 = 0.f, mx = -__builtin_inff(), mn = __builtin_inff();
    #pragma unroll
    for (int rt = 0; rt < 5; rt++) {
      #pragma unroll
      for (int reg = 0; reg < 4; reg++) {
        float h = acc[rt][cj][reg];
        s += h; s2 += h*h;
        mx = fmaxf(mx, h); mn = fminf(mn, h);
      }
    }
    hmax2[(size_t)(p0 + quad)*192 + o] = f2h(mx);
    hmin2[(size_t)(p0 + quad)*192 + o] = f2h(mn);
    s  += __shfl_xor(s, 16);  s  += __shfl_xor(s, 32);
    s2 += __shfl_xor(s2, 16); s2 += __shfl_xor(s2, 32);
    if (lane < 16) {
      float* dst = stats2sh + ((size_t)(bi & 255)*192 + o)*2;
      atomicAdd(dst, s); atomicAdd(dst + 1, s2);
    }
  }
}

// ---------- 11) conv3 via bf16 MFMA: ch0-63 from x1h (already bf16), ch64-255 from fp16 hmax2/hmin2 ----------
__global__ void __launch_bounds__(256) k_conv3m(
   const unsigned short* __restrict__ x1h,
   const unsigned short* __restrict__ hmax2, const unsigned short* __restrict__ hmin2,
   const float* __restrict__ scale2, const float* __restrict__ shift2,
   const unsigned short* __restrict__ wt3h, float* __restrict__ stats3sh,
   unsigned* __restrict__ hmax3u, unsigned* __restrict__ hmin3u) {
  __shared__ short As[64*264];
  int tid = threadIdx.x;
  int mt = blockIdx.x >> 2, cb = blockIdx.x & 3;
  int rowbase = mt*64;
  int b = rowbase >> 10;
  int c4 = tid & 63;
  float4 sc, sh;
  if (c4 >= 16) {
    sc = *((const float4*)(scale2 + (c4*4 - 64)));
    sh = *((const float4*)(shift2 + (c4*4 - 64)));
  }
  #pragma unroll 4
  for (int i = 0; i < 16; i++) {
    int r = (tid >> 6) + i*4;
    int p = rowbase + r;
    if (c4 < 16) {
      // channels 0..63: x1h already holds f2bf(relu(BN1(h))) in (B,N,64) layout
      *((ushort4*)(As + r*264 + c4*4)) =
        *((const ushort4*)(x1h + (size_t)p*64 + c4*4));
    } else {
      ushort4 hx4 = *((const ushort4*)(hmax2 + (size_t)p*192 + (c4*4 - 64)));
      ushort4 hn4 = *((const ushort4*)(hmin2 + (size_t)p*192 + (c4*4 - 64)));
      ushort4 o4;
      o4.x = f2bf(fmaxf(fmaf(sc.x, (sc.x >= 0.f ? h2f(hx4.x) : h2f(hn4.x)), sh.x), 0.f));
      o4.y = f2bf(fmaxf(fmaf(sc.y, (sc.y >= 0.f ? h2f(hx4.y) : h2f(hn4.y)), sh.y), 0.f));
      o4.z = f2bf(fmaxf(fmaf(sc.z, (sc.z >= 0.f ? h2f(hx4.z) : h2f(hn4.z)), sh.z), 0.f));
      o4.w = f2bf(fmaxf(fmaf(sc.w, (sc.w >= 0.f ? h2f(hx4.w) : h2f(hn4.w)), sh.w), 0.f));
      *((ushort4*)(As + r*264 + c4*4)) = o4;
    }
  }
  __syncthreads();
  int wave = tid >> 6, lane = tid & 63;
  int quad = lane >> 4, lm = lane & 15;
  int colbase = cb*256 + wave*64;
  f32x4 acc[4][4];
  #pragma unroll
  for (int ri = 0; ri < 4; ri++)
    #pragma unroll
    for (int cj = 0; cj < 4; cj++) acc[ri][cj] = (f32x4){0.f, 0.f, 0.f, 0.f};
  for (int kt = 0; kt < 8; kt++) {
    int k0 = kt*32 + quad*8;
    bf16x8 bf[4];
    #pragma unroll
    for (int cj = 0; cj < 4; cj++)
      bf[cj] = *((const bf16x8*)(wt3h + (size_t)(colbase + cj*16 + lm)*256 + k0));
    bf16x8 af[4];
    #pragma unroll
    for (int ri = 0; ri < 4; ri++)
      af[ri] = *((const bf16x8*)(As + (ri*16 + lm)*264 + k0));
    #pragma unroll
    for (int ri = 0; ri < 4; ri++)
      #pragma unroll
      for (int cj = 0; cj < 4; cj++)
        acc[ri][cj] = __builtin_amdgcn_mfma_f32_16x16x32_bf16(af[ri], bf[cj], acc[ri][cj], 0, 0, 0);
  }
  #pragma unroll
  for (int cj = 0; cj < 4; cj++) {
    float s = 0.f, s2 = 0.f, mx = -__builtin_inff(), mn = __builtin_inff();
    #pragma unroll
    for (int ri = 0; ri < 4; ri++) {
      #pragma unroll
      for (int reg = 0; reg < 4; reg++) {
        float h = acc[ri][cj][reg];
        s += h; s2 += h*h; mx = fmaxf(mx, h); mn = fminf(mn, h);
      }
    }
    s  += __shfl_xor(s, 16);  s  += __shfl_xor(s, 32);
    s2 += __shfl_xor(s2, 16); s2 += __shfl_xor(s2, 32);
    mx = fmaxf(mx, __shfl_xor(mx, 16)); mx = fmaxf(mx, __shfl_xor(mx, 32));
    mn = fminf(mn, __shfl_xor(mn, 16)); mn = fminf(mn, __shfl_xor(mn, 32));
    if (lane < 16) {
      int col = colbase + cj*16 + lane;
      float* dst = stats3sh + ((size_t)(blockIdx.x & 63)*1024 + col)*2;
      atomicAdd(dst, s);
      atomicAdd(dst + 1, s2);
      atomicMax(hmax3u + b*1024 + col, fkey(mx));
      atomicMin(hmin3u + b*1024 + col, fkey(mn));
    }
  }
}

// ---------- 12) head, split for weight-read parallelism ----------
__device__ float blk_reduce(float v, float* red, int tid) {
  red[tid] = v; __syncthreads();
  for (int st = 128; st > 0; st >>= 1) {
    if (tid < st) red[tid] += red[tid + st];
    __syncthreads();
  }
  float r = red[0]; __syncthreads();
  return r;
}

__global__ void __launch_bounds__(256) k_head1(const unsigned* __restrict__ hmax3u,
    const unsigned* __restrict__ hmin3u,
    const float* __restrict__ scale3, const float* __restrict__ shift3,
    const float* __restrict__ fc1w, const float* __restrict__ fc1b,
    float* __restrict__ h1buf) {
  __shared__ __align__(16) float V[1024];
  int b = blockIdx.x >> 5, oc = blockIdx.x & 31;
  int tid = threadIdx.x;
  for (int o = tid; o < 1024; o += 256) {
    float a = scale3[o];
    unsigned u = (a >= 0.f) ? hmax3u[b*1024 + o] : hmin3u[b*1024 + o];
    V[o] = fmaxf(fmaf(a, fkeyinv(u), shift3[o]), 0.f);
  }
  __syncthreads();
  int ty = tid >> 4, tx = tid & 15;
  int o = oc*16 + ty;
  const float4* wr = (const float4*)(fc1w + (size_t)o*1024) + tx*16;
  const float4* vv = (const float4*)V + tx*16;
  float s = 0.f;
  #pragma unroll
  for (int i = 0; i < 16; i++) {
    float4 w = wr[i]; float4 v = vv[i];
    s = fmaf(w.x, v.x, s); s = fmaf(w.y, v.y, s);
    s = fmaf(w.z, v.z, s); s = fmaf(w.w, v.w, s);
  }
  s += __shfl_xor(s, 1); s += __shfl_xor(s, 2);
  s += __shfl_xor(s, 4); s += __shfl_xor(s, 8);
  if (tx == 0) h1buf[b*512 + o] = s + fc1b[o];
}

__global__ void __launch_bounds__(256) k_head2(const float* __restrict__ h1buf,
    const float* __restrict__ ln1g, const float* __restrict__ ln1b,
    const float* __restrict__ fc2w, const float* __restrict__ fc2b,
    float* __restrict__ h2buf) {
  __shared__ __align__(16) float H1[512];
  __shared__ float red[256];
  int b = blockIdx.x >> 3, oc = blockIdx.x & 7;
  int tid = threadIdx.x;
  float v0 = h1buf[b*512 + tid], v1 = h1buf[b*512 + 256 + tid];
  float s = blk_reduce(v0 + v1, red, tid);
  float s2 = blk_reduce(v0*v0 + v1*v1, red, tid);
  float m = s / 512.f;
  float var = s2 / 512.f - m*m;
  float inv = 1.0f / sqrtf(var + 1e-5f);
  H1[tid] = fmaxf((v0 - m)*inv*ln1g[tid] + ln1b[tid], 0.f);
  H1[256 + tid] = fmaxf((v1 - m)*inv*ln1g[256 + tid] + ln1b[256 + tid], 0.f);
  __syncthreads();
  int ty = tid >> 3, tx = tid & 7;
  int o = oc*32 + ty;
  const float4* wr = (const float4*)(fc2w + (size_t)o*512) + tx*16;
  const float4* vv = (const float4*)H1 + tx*16;
  float t = 0.f;
  #pragma unroll
  for (int i = 0; i < 16; i++) {
    float4 w = wr[i]; float4 v = vv[i];
    t = fmaf(w.x, v.x, t); t = fmaf(w.y, v.y, t);
    t = fmaf(w.z, v.z, t); t = fmaf(w.w, v.w, t);
  }
  t += __shfl_xor(t, 1); t += __shfl_xor(t, 2); t += __shfl_xor(t, 4);
  if (tx == 0) h2buf[b*256 + o] = t + fc2b[o];
}

__global__ void __launch_bounds__(256) k_head3(const float* __restrict__ h2buf,
    const float* __restrict__ ln2g, const float* __restrict__ ln2b,
    const float* __restrict__ outw, const float* __restrict__ outb,
    float* __restrict__ out) {
  __shared__ __align__(16) float H2[256];
  __shared__ float red[256];
  int b = blockIdx.x, tid = threadIdx.x;
  float h2v = h2buf[b*256 + tid];
  float ss = blk_reduce(h2v, red, tid);
  float ss2 = blk_reduce(h2v*h2v, red, tid);
  float m2 = ss / 256.f;
  float var2 = ss2 / 256.f - m2*m2;
  float inv2 = 1.0f / sqrtf(var2 + 1e-5f);
  H2[tid] = fmaxf((h2v - m2)*inv2*ln2g[tid] + ln2b[tid], 0.f);
  __syncthreads();
  if (tid < 40) {
    const float4* wr = (const float4*)(outw + (size_t)tid*256);
    float t = 0.f;
    for (int c4 = 0; c4 < 64; c4++) {
      float4 w = wr[c4]; float4 vv = ((const float4*)H2)[c4];
      t = fmaf(w.x, vv.x, t); t = fmaf(w.y, vv.y, t);
      t = fmaf(w.z, vv.z, t); t = fmaf(w.w, vv.w, t);
    }
    red[tid] = t + outb[tid];
  }
  __syncthreads();
  if (tid == 0) {
    float mx = -__builtin_inff();
    for (int i2 = 0; i2 < 40; i2++) mx = fmaxf(mx, red[i2]);
    float se = 0.f;
    for (int i2 = 0; i2 < 40; i2++) se += expf(red[i2] - mx);
    float lse = mx + logf(se);
    for (int i2 = 0; i2 < 40; i2++) out[b*40 + i2] = red[i2] - lse;
  }
}

extern "C" void kernel_launch(void* const* d_in, const int* in_sizes, int n_in,
                              void* d_out, int out_size, void* d_ws, size_t ws_size,
                              hipStream_t stream) {
  (void)in_sizes; (void)n_in; (void)out_size; (void)ws_size;
  const float* x    = (const float*)d_in[0];
  const float* w1   = (const float*)d_in[1];
  const float* bn1g = (const float*)d_in[2];
  const float* bn1b = (const float*)d_in[3];
  const float* w2   = (const float*)d_in[4];
  const float* bn2g = (const float*)d_in[5];
  const float* bn2b = (const float*)d_in[6];
  const float* w3   = (const float*)d_in[7];
  const float* bn3g = (const float*)d_in[8];
  const float* bn3b = (const float*)d_in[9];
  const float* fc1w = (const float*)d_in[10];
  const float* fc1b = (const float*)d_in[11];
  const float* ln1g = (const float*)d_in[12];
  const float* ln1b = (const float*)d_in[13];
  const float* fc2w = (const float*)d_in[14];
  const float* fc2b = (const float*)d_in[15];
  const float* ln2g = (const float*)d_in[16];
  const float* ln2b = (const float*)d_in[17];
  const float* outw = (const float*)d_in[18];
  const float* outb = (const float*)d_in[19];
  float* out = (float*)d_out;

  float* ws = (float*)d_ws;
  size_t off = 0;
  float* xp1   = ws + off; off += 49152;
  float* hmax1 = ws + off; off += 1048576;
  float* hmin1 = ws + off; off += 1048576;
  float* xp2   = ws + off; off += 1048576;
  float* hmax2f = ws + off; off += 3145728;  // holds keypartA (knn1 partials) then fp16 hmax2
  float* hmin2f = ws + off; off += 3145728;  // fp16 hmin2
  unsigned* keypart2 = (unsigned*)(ws + off); off += 1310720;  // knn2 partials, 80/pt
  unsigned short* w2h = (unsigned short*)(ws + off); off += 24576;
  unsigned short* wt3h = (unsigned short*)(ws + off); off += 131072;
  float* x1bf  = ws + off; off += 1048576;   // x1 bf16 hi (2MB) + lo (2MB), (B,N,64) layout
  float* xx1   = ws + off; off += 16384;
  float* h1buf = ws + off; off += 8192;
  float* h2buf = ws + off; off += 4096;
  float* scale1 = ws + off; off += 64;
  float* shift1 = ws + off; off += 64;
  float* scale2 = ws + off; off += 192;
  float* shift2 = ws + off; off += 192;
  float* scale3 = ws + off; off += 1024;
  float* shift3 = ws + off; off += 1024;
  float* stats1sh = ws + off;                         // fp32 stats
  float* stats2sh = stats1sh + 64*64*2;
  float* stats3sh = stats2sh + (size_t)256*192*2;
  unsigned* hmax3u = (unsigned*)(stats3sh + (size_t)64*1024*2);
  unsigned* hmin3u = hmax3u + 16384;
  unsigned* keypartA = (unsigned*)hmax2f;
  unsigned short* x1h = (unsigned short*)x1bf;
  unsigned short* x1l = x1h + 1048576;
  unsigned short* hmax2 = (unsigned short*)hmax2f;
  unsigned short* hmin2 = (unsigned short*)hmin2f;

  size_t zero_bytes = ((size_t)64*64*2 + (size_t)256*192*2 + (size_t)64*1024*2)*4 + (size_t)16384*4;
  hipMemsetAsync(stats1sh, 0, zero_bytes, stream);
  hipMemsetAsync(hmin3u, 0xFF, (size_t)16384*4, stream);

  k_prep_knn1<<<1536, 256, 0, stream>>>(x, xp1, w2, w3, w2h, wt3h, keypartA);
  k_conv1<<<1024, 256, 0, stream>>>(xp1, keypartA, w1, hmax1, hmin1, stats1sh);
  k_bn_reduce<<<64, 64, 0, stream>>>(stats1sh, 64, 64, 327680.0, bn1g, bn1b, scale1, shift1);
  k_bn1_apply<<<256, 256, 0, stream>>>(hmax1, hmin1, scale1, shift1, xp2, x1h, x1l, xx1);
  k_knn2g<<<1024, 256, 0, stream>>>(x1h, x1l, xx1, keypart2);
  k_conv2m<<<4096, 256, 0, stream>>>(xp2, keypart2, w2h, hmax2, hmin2, stats2sh);
  k_bn_reduce<<<192, 64, 0, stream>>>(stats2sh, 192, 256, 327680.0, bn2g, bn2b, scale2, shift2);
  k_conv3m<<<1024, 256, 0, stream>>>(x1h, hmax2, hmin2, scale2, shift2,
                                     wt3h, stats3sh, hmax3u, hmin3u);
  k_bn_reduce<<<1024, 64, 0, stream>>>(stats3sh, 1024, 64, 16384.0, bn3g, bn3b, scale3, shift3);
  k_head1<<<512, 256, 0, stream>>>(hmax3u, hmin3u, scale3, shift3, fc1w, fc1b, h1buf);
  k_head2<<<128, 256, 0, stream>>>(h1buf, ln1g, ln1b, fc2w, fc2b, h2buf);
  k_head3<<<16, 256, 0, stream>>>(h2buf, ln2g, ln2b, outw, outb, out);
}

// Round 8
// 347.496 us; speedup vs baseline: 1.0073x; 1.0073x over previous
//
#include <hip/hip_runtime.h>
#include <math.h>

#define B_ 16
#define N_ 1024
#define KNN 20
#define NPAIR (B_*N_)

typedef __attribute__((ext_vector_type(8))) short bf16x8;
typedef __attribute__((ext_vector_type(4))) float f32x4;

// ---------- helpers ----------
__device__ __forceinline__ unsigned fkey(float f) {
  unsigned u = __float_as_uint(f);
  return (u & 0x80000000u) ? ~u : (u | 0x80000000u);
}
__device__ __forceinline__ float fkeyinv(unsigned u) {
  unsigned b = (u & 0x80000000u) ? (u ^ 0x80000000u) : ~u;
  return __uint_as_float(b);
}
__device__ __forceinline__ unsigned short f2bf(float x) {  // RNE float->bf16
  unsigned u = __float_as_uint(x);
  unsigned r = (u + 0x7FFFu + ((u >> 16) & 1u)) >> 16;
  return (unsigned short)r;
}
__device__ __forceinline__ float bf2f(unsigned short u) {
  return __uint_as_float(((unsigned)u) << 16);
}
__device__ __forceinline__ unsigned short f2h(float x) {   // RNE float->fp16
  _Float16 h = (_Float16)x;
  return *(unsigned short*)&h;
}
__device__ __forceinline__ float h2f(unsigned short u) {
  _Float16 h = *(_Float16*)&u;
  return (float)h;
}
// packed knn key: top 22 bits of fkey(d) | (1023 - idx). u32 '>' == dist desc, idx asc.
__device__ __forceinline__ unsigned knnkey(float d, int idx) {
  return (fkey(d) & 0xFFFFFC00u) | (unsigned)(1023 - idx);
}

// Branchless sorted-insert (descending) of packed u32 key: 2 ops/stage.
__device__ __forceinline__ void topk_insert_u32(unsigned (&kl)[KNN], unsigned nk) {
  kl[KNN-1] = nk;
  #pragma unroll
  for (int i = KNN-1; i > 0; i--) {
    unsigned hi = max(kl[i-1], kl[i]);
    unsigned lo = min(kl[i-1], kl[i]);
    kl[i-1] = hi; kl[i] = lo;
  }
}

// count of elements strictly greater than v in sorted-desc list L of 20 (5-step bsearch)
__device__ __forceinline__ int cnt_gt(const unsigned* __restrict__ L, unsigned v) {
  int j = 0;
  #pragma unroll
  for (int s = 16; s; s >>= 1) {
    int nj = j + s;
    if (nj <= KNN && L[nj-1] > v) j = nj;
  }
  return j;
}

// ---------- 1) fused prep + knn1: blocks 0..511 = knn1 8-way split; 512..1535 = prep ----------
__global__ void __launch_bounds__(256) k_prep_knn1(const float* __restrict__ x,
        float* __restrict__ xp1, const float* __restrict__ w2, const float* __restrict__ w3,
        unsigned short* __restrict__ w2h, unsigned short* __restrict__ wt3h,
        unsigned* __restrict__ keypart) {
  __shared__ float P[N_*3];
  __shared__ float XX[N_];
  if (blockIdx.x >= 512) {
    int i = (blockIdx.x - 512) * 256 + threadIdx.x;
    if (i < NPAIR) {
      float a0 = x[i*3+0], a1 = x[i*3+1], a2 = x[i*3+2];
      float n = sqrtf(a0*a0 + a1*a1 + a2*a2);
      n = fmaxf(n, 1e-15f);
      float th = tanhf(0.1f * n);
      float sc = th / (0.1f * n);
      float ny = fmaxf(th * 10.0f, 1e-15f);
      float mxn = (1.0f - 4e-3f) / 0.1f;
      if (ny > mxn) sc *= mxn / ny;
      xp1[i*3+0] = sc*a0; xp1[i*3+1] = sc*a1; xp1[i*3+2] = sc*a2;
    }
    if (i < 192*128) w2h[i] = f2bf(w2[i]);
    wt3h[i] = f2bf(w3[i]);
    return;
  }
  int blk = blockIdx.x;
  int b = blk >> 5, rc = (blk >> 3) & 3, cc = blk & 7;
  const float* xb = x + b*N_*3;
  for (int e = threadIdx.x; e < N_*3; e += 256) P[e] = xb[e];
  __syncthreads();
  for (int j = threadIdx.x; j < N_; j += 256) {
    float q0 = P[j*3], q1 = P[j*3+1], q2 = P[j*3+2];
    XX[j] = q0*q0 + q1*q1 + q2*q2;
  }
  __syncthreads();
  int r = rc*256 + threadIdx.x;
  float q0 = P[r*3], q1 = P[r*3+1], q2 = P[r*3+2];
  float xxq = XX[r];
  unsigned kl[KNN];
  #pragma unroll
  for (int i = 0; i < KNN; i++) kl[i] = 0u;
  int cbase = cc*128;
  for (int jj = 0; jj < 128; jj++) {
    int j = cbase + jj;
    float dot = q0*P[j*3] + q1*P[j*3+1] + q2*P[j*3+2];
    float d = 2.0f*dot - xxq - XX[j];
    unsigned nk = knnkey(d, j);
    if (nk > kl[KNN-1]) topk_insert_u32(kl, nk);
  }
  int p = b*N_ + r;
  unsigned* pe = keypart + (size_t)p*160 + cc*20;
  #pragma unroll
  for (int i = 0; i < KNN; i++) pe[i] = kl[i];
}

// ---------- 3) conv1 fused v2: parallel pairwise merge tree (8->4->2->1), fp32 stats ----------
__global__ void __launch_bounds__(256) k_conv1(const float* __restrict__ xp1,
                        const unsigned* __restrict__ keypart,
                        const float* __restrict__ w1, float* __restrict__ hmax1,
                        float* __restrict__ hmin1, float* __restrict__ stats1sh) {
  __shared__ float F[4][KNN][6];
  __shared__ float red[4][64][2];
  __shared__ int idxs[16][KNN];
  __shared__ unsigned keybuf[2560];   // 16 pairs x 160 keys, 10 KB
  __shared__ unsigned out1[1280];     // level-1 merged: 16 pts x 4 lists x 20
  __shared__ unsigned out2[640];      // level-2 merged: 16 pts x 2 lists x 20
  int g = threadIdx.x >> 6, lane = threadIdx.x & 63;
  int tid = threadIdx.x;
  int pbase = blockIdx.x * 16;
  {
    const unsigned* src = keypart + (size_t)pbase*160;
    for (int e = tid; e < 2560; e += 256) keybuf[e] = src[e];
  }
  float w[6];
  #pragma unroll
  for (int c = 0; c < 6; c++) w[c] = w1[lane*6 + c];
  __syncthreads();
  // L1: merge (2m, 2m+1) -> out1[pt][m][.]  (2560 items, all parallel)
  for (int e = tid; e < 2560; e += 256) {
    int pt = e / 160, rem = e - pt*160;
    int m = rem / 40, i = rem - m*40;
    const unsigned* A = keybuf + pt*160 + (2*m)*20;
    const unsigned* Bl = A + 20;
    unsigned v; const unsigned* S; int own;
    if (i < 20) { v = A[i]; S = Bl; own = i; }
    else { v = Bl[i-20]; S = A; own = i-20; }
    int rank = own + cnt_gt(S, v);
    if (rank < KNN) out1[(pt*4 + m)*20 + rank] = v;
  }
  __syncthreads();
  // L2: merge (2m2, 2m2+1) of out1 -> out2[pt][m2][.]  (1280 items)
  for (int e = tid; e < 1280; e += 256) {
    int pt = e / 80, rem = e - pt*80;
    int m2 = rem / 40, i = rem - m2*40;
    const unsigned* A = out1 + (pt*4 + 2*m2)*20;
    const unsigned* Bl = A + 20;
    unsigned v; const unsigned* S; int own;
    if (i < 20) { v = A[i]; S = Bl; own = i; }
    else { v = Bl[i-20]; S = A; own = i-20; }
    int rank = own + cnt_gt(S, v);
    if (rank < KNN) out2[(pt*2 + m2)*20 + rank] = v;
  }
  __syncthreads();
  // L3: final merge -> idxs  (640 items)
  for (int e = tid; e < 640; e += 256) {
    int pt = e / 40, i = e - pt*40;
    const unsigned* A = out2 + pt*40;
    const unsigned* Bl = A + 20;
    unsigned v; const unsigned* S; int own;
    if (i < 20) { v = A[i]; S = Bl; own = i; }
    else { v = Bl[i-20]; S = A; own = i-20; }
    int rank = own + cnt_gt(S, v);
    if (rank < KNN) idxs[pt][rank] = 1023 - (int)(v & 1023u);
  }
  float sum = 0.f, sumsq = 0.f;
  __syncthreads();
  for (int it = 0; it < 4; ++it) {
    int p = pbase + it*4 + g;
    if (lane < KNN) {
      int nb = idxs[it*4 + g][lane];
      int bb = p >> 10;
      const float* xc = xp1 + p*3;
      const float* ft = xp1 + (bb*N_ + nb)*3;
      float x0 = ft[0], x1 = ft[1], x2v = ft[2];
      float c0 = xc[0], c1 = xc[1], c2 = xc[2];
      float X2 = x0*x0 + x1*x1 + x2v*x2v;
      float Y2 = c0*c0 + c1*c1 + c2*c2;
      float XY = -(x0*c0 + x1*c1 + x2v*c2);
      float den = fmaxf(1.0f + 0.02f*XY + 1e-4f*X2*Y2, 1e-15f);
      float s1 = (1.0f + 0.02f*XY + 0.01f*Y2) / den;
      float s2 = (1.0f - 0.01f*X2) / den;
      F[g][lane][0] = s1*x0 - s2*c0;
      F[g][lane][1] = s1*x1 - s2*c1;
      F[g][lane][2] = s1*x2v - s2*c2;
      F[g][lane][3] = c0; F[g][lane][4] = c1; F[g][lane][5] = c2;
    }
    __syncthreads();
    float mx = -__builtin_inff(), mn = __builtin_inff();
    for (int k = 0; k < KNN; k++) {
      float h = 0.f;
      #pragma unroll
      for (int c = 0; c < 6; c++) h = fmaf(w[c], F[g][k][c], h);
      mx = fmaxf(mx, h); mn = fminf(mn, h);
      sum += h; sumsq += h*h;
    }
    hmax1[(pbase + it*4 + g)*64 + lane] = mx;
    hmin1[(pbase + it*4 + g)*64 + lane] = mn;
    __syncthreads();
  }
  red[g][lane][0] = sum; red[g][lane][1] = sumsq;
  __syncthreads();
  if (g == 0) {
    float s  = red[0][lane][0] + red[1][lane][0] + red[2][lane][0] + red[3][lane][0];
    float s2 = red[0][lane][1] + red[1][lane][1] + red[2][lane][1] + red[3][lane][1];
    float* dst = stats1sh + ((size_t)(blockIdx.x & 63)*64 + lane)*2;
    atomicAdd(dst, s);
    atomicAdd(dst + 1, s2);
  }
}

// ---------- BN stat reduce v4 (fp32 slots, f64 cross-slot accumulation) ----------
__global__ void __launch_bounds__(64) k_bn_reduce(const float* __restrict__ sh, int nch, int nslots,
                            double cnt,
                            const float* __restrict__ g, const float* __restrict__ bb,
                            float* __restrict__ scale, float* __restrict__ shift) {
  int o = blockIdx.x, t = threadIdx.x;
  double s = 0.0, s2 = 0.0;
  for (int sl = t; sl < nslots; sl += 64) {
    s  += (double)sh[((size_t)sl*nch + o)*2];
    s2 += (double)sh[((size_t)sl*nch + o)*2 + 1];
  }
  #pragma unroll
  for (int off = 32; off > 0; off >>= 1) { s += __shfl_xor(s, off); s2 += __shfl_xor(s2, off); }
  if (t == 0) {
    double m = s / cnt;
    double v = s2 / cnt - m*m;
    float a = g[o] / sqrtf((float)v + 1e-5f);
    scale[o] = a;
    shift[o] = bb[o] - a * (float)m;
  }
}

// ---------- 5) BN1 apply + relu + e2p + bf16 hi/lo split for MFMA knn2 + |x1|^2 ----------
__global__ void __launch_bounds__(256) k_bn1_apply(const float* __restrict__ hmax1, const float* __restrict__ hmin1,
                            const float* __restrict__ scale1, const float* __restrict__ shift1,
                            float* __restrict__ xp2,
                            unsigned short* __restrict__ x1h, unsigned short* __restrict__ x1l,
                            float* __restrict__ xx1) {
  int b = blockIdx.x >> 4, nc = blockIdx.x & 15;
  int c = threadIdx.x & 63, sub = threadIdx.x >> 6;
  int n0 = nc*64 + sub*16;
  float a = scale1[c], t = shift1[c];
  #pragma unroll
  for (int i = 0; i < 16; i++) {
    int p = b*1024 + n0 + i;
    float h = (a >= 0.f) ? hmax1[(size_t)p*64 + c] : hmin1[(size_t)p*64 + c];
    float x1 = fmaxf(fmaf(a, h, t), 0.f);
    // split-bf16: x1 = hi + lo with both bf16; dot via 4-term MFMA is fp32-accurate to ~2^-17
    unsigned short hb = f2bf(x1);
    x1h[(size_t)p*64 + c] = hb;
    x1l[(size_t)p*64 + c] = f2bf(x1 - bf2f(hb));
    float n2 = x1*x1;
    #pragma unroll
    for (int off = 32; off > 0; off >>= 1) n2 += __shfl_xor(n2, off);
    if (c == 0) xx1[p] = n2;
    float n1 = fmaxf(sqrtf(n2), 1e-15f);
    float th = tanhf(0.1f * n1);
    float sc = th / (0.1f * n1);
    float ny = fmaxf(th * 10.0f, 1e-15f);
    float mxn = (1.0f - 4e-3f) / 0.1f;
    if (ny > mxn) sc *= mxn / ny;
    xp2[(size_t)p*64 + c] = sc * x1;
  }
}

// ---------- 6) knn2 v10: register-only scan via cross-lane 4x4 transpose + parallel rank-merge ----------
// Block = 64 queries x 256 candidates (4 stages of 64). Wave w owns cands [w*16, w*16+16) per stage.
// MFMA leaves D[qt*16+lm][kq*4+r] in acc[qt][r]; two shfl_xor butterfly rounds (16, 32) transpose the
// 4x4 block within lane group {lm,lm+16,lm+32,lm+48} so each lane holds its query's 16 distances in
// REGISTERS -- zero LDS, zero barriers in the scan. Tail: parallel rank-merge (verified in v9 run).
__global__ void __launch_bounds__(256) k_knn2g(const unsigned short* __restrict__ x1h,
        const unsigned short* __restrict__ x1l,
        const float* __restrict__ xx1, unsigned* __restrict__ keypart2) {
  __shared__ unsigned LU[5376];                  // 4 lists x 64q x 21 (21 KB)
  __shared__ unsigned MU[2688];                  // 2 merged x 64q x 21 (10.5 KB)
  int tid = threadIdx.x;
  int bi = blockIdx.x;
  int blk = ((bi & 7) << 7) + (bi >> 3);     // XCD-affine swizzle (1024 = 8*128, bijective)
  int b = blk >> 6, qc = (blk >> 2) & 15, cc = blk & 3;
  int qbase = qc*64, ccbase = cc*256;
  int wave = tid >> 6, lane = tid & 63;
  int lm = lane & 15, kq = lane >> 4;
  const size_t base = (size_t)b * 65536;     // b*1024*64

  // Q fragments (hi/lo) held in registers for the whole kernel: 4 qtiles x 2 ksteps
  bf16x8 Qh[4][2], Ql[4][2];
  #pragma unroll
  for (int qt = 0; qt < 4; qt++) {
    size_t ro = base + (size_t)(qbase + qt*16 + lm)*64 + kq*8;
    #pragma unroll
    for (int ks = 0; ks < 2; ks++) {
      Qh[qt][ks] = *((const bf16x8*)(x1h + ro + ks*32));
      Ql[qt][ks] = *((const bf16x8*)(x1l + ro + ks*32));
    }
  }
  unsigned kl[KNN];
  #pragma unroll
  for (int i = 0; i < KNN; i++) kl[i] = 0u;

  for (int st = 0; st < 4; ++st) {
    int cb0 = ccbase + st*64;
    // A fragments: this wave's 16 candidates, hi/lo
    size_t co = base + (size_t)(cb0 + wave*16 + lm)*64 + kq*8;
    bf16x8 Ah[2], Al[2];
    #pragma unroll
    for (int ks = 0; ks < 2; ks++) {
      Ah[ks] = *((const bf16x8*)(x1h + co + ks*32));
      Al[ks] = *((const bf16x8*)(x1l + co + ks*32));
    }
    float4 xxc = *((const float4*)(xx1 + b*1024 + cb0 + wave*16 + kq*4));
    f32x4 acc[4];
    #pragma unroll
    for (int qt = 0; qt < 4; qt++) acc[qt] = (f32x4){0.f, 0.f, 0.f, 0.f};
    #pragma unroll
    for (int ks = 0; ks < 2; ks++) {
      #pragma unroll
      for (int qt = 0; qt < 4; qt++) {
        acc[qt] = __builtin_amdgcn_mfma_f32_16x16x32_bf16(Ah[ks], Qh[qt][ks], acc[qt], 0, 0, 0);
        acc[qt] = __builtin_amdgcn_mfma_f32_16x16x32_bf16(Ah[ks], Ql[qt][ks], acc[qt], 0, 0, 0);
        acc[qt] = __builtin_amdgcn_mfma_f32_16x16x32_bf16(Al[ks], Qh[qt][ks], acc[qt], 0, 0, 0);
        acc[qt] = __builtin_amdgcn_mfma_f32_16x16x32_bf16(Al[ks], Ql[qt][ks], acc[qt], 0, 0, 0);
      }
    }
    // dist adjust while layout is [qt][cand r of own kq group]: xxcv[r] matches cand kq*4+r
    // (-xxq omitted: constant per query row, rank-invariant)
    f32x4 xxv = (f32x4){xxc.x, xxc.y, xxc.z, xxc.w};
    #pragma unroll
    for (int qt = 0; qt < 4; qt++) acc[qt] = acc[qt]*2.0f - xxv;
    // 4x4 cross-lane block transpose within {lm, lm+16, lm+32, lm+48}:
    // after: acc[qt][r] = D[lane][qt*4+r]
    {
      f32x4 s0, s1, r0, r1;
      bool h1 = (kq & 1) != 0;
      if (h1) { s0 = acc[0]; s1 = acc[2]; } else { s0 = acc[1]; s1 = acc[3]; }
      #pragma unroll
      for (int e = 0; e < 4; e++) { r0[e] = __shfl_xor(s0[e], 16); r1[e] = __shfl_xor(s1[e], 16); }
      if (h1) { acc[0] = r0; acc[2] = r1; } else { acc[1] = r0; acc[3] = r1; }
      bool h2 = (kq & 2) != 0;
      if (h2) { s0 = acc[0]; s1 = acc[1]; } else { s0 = acc[2]; s1 = acc[3]; }
      #pragma unroll
      for (int e = 0; e < 4; e++) { r0[e] = __shfl_xor(s0[e], 32); r1[e] = __shfl_xor(s1[e], 32); }
      if (h2) { acc[0] = r0; acc[1] = r1; } else { acc[2] = r0; acc[3] = r1; }
    }
    // scan own query's 16 candidates straight from registers
    #pragma unroll
    for (int c = 0; c < 16; c++) {
      float d = acc[c >> 2][c & 3];
      unsigned nk = knnkey(d, cb0 + wave*16 + c);
      if (nk > kl[KNN-1]) topk_insert_u32(kl, nk);
    }
  }
  // publish per-wave lists
  #pragma unroll
  for (int i = 0; i < KNN; i++) LU[wave*1344 + lane*21 + i] = kl[i];
  __syncthreads();
  // merge level 1: (L0,L1)->M0, (L2,L3)->M1.  5120 items, rank = own idx + 1 bsearch.
  for (int e = tid; e < 5120; e += 256) {
    int pair = e / 2560;
    int rem = e - pair*2560;
    int q = rem / 40;
    int i40 = rem - q*40;
    int side = (i40 >= 20) ? 1 : 0;
    int idx = i40 - side*20;
    int own = pair*2 + side, oth = pair*2 + (1 - side);
    unsigned v = LU[own*1344 + q*21 + idx];
    int rank = idx + cnt_gt(LU + oth*1344 + q*21, v);
    if (rank < KNN) MU[pair*1344 + q*21 + rank] = v;
  }
  __syncthreads();
  // merge level 2: (M0,M1) -> keypart2.  2560 items.
  for (int e = tid; e < 2560; e += 256) {
    int q = e / 40;
    int i40 = e - q*40;
    int side = (i40 >= 20) ? 1 : 0;
    int idx = i40 - side*20;
    unsigned v = MU[side*1344 + q*21 + idx];
    int rank = idx + cnt_gt(MU + (1 - side)*1344 + q*21, v);
    if (rank < KNN)
      keypart2[(size_t)(b*N_ + qbase + q)*80 + cc*20 + rank] = v;
  }
}

// ---------- 9) conv2 via bf16 MFMA v11: rank-merge + fp32 center + fp16 hmax/hmin + fp32 stats ----------
__global__ void __launch_bounds__(256) k_conv2m(const float* __restrict__ xp2,
    const unsigned* __restrict__ keypart2, const unsigned short* __restrict__ w2h,
    unsigned short* __restrict__ hmax2, unsigned short* __restrict__ hmin2,
    float* __restrict__ stats2sh) {
  __shared__ __align__(16) short Abf[80*136];
  __shared__ __align__(16) float Cf[4][64];      // fp32 centers for Mobius math
  __shared__ float Yc[4];
  __shared__ int nbr[80];                        // logical order [pt*20 + k]
  __shared__ unsigned keybuf[320];               // 4 pairs x 80 keys
  int tid = threadIdx.x;
  int bi = blockIdx.x;
  int g512 = ((bi & 7) << 9) + (bi >> 3);
  int p0 = g512 * 4;
  int b = p0 >> 10;
  // Region A: stage merge keys (all threads) + center rows/Y2 (first wave) concurrently
  for (int e = tid; e < 320; e += 256) keybuf[e] = keypart2[(size_t)p0*80 + e];
  if (tid < 64) {
    int pt = tid >> 4, qq = tid & 15;
    float4 cv = *((const float4*)(xp2 + (size_t)(p0 + pt)*64) + qq);
    *((float4*)&Cf[pt][qq*4]) = cv;
    float y2 = cv.x*cv.x + cv.y*cv.y + cv.z*cv.z + cv.w*cv.w;
    #pragma unroll
    for (int off = 8; off > 0; off >>= 1) y2 += __shfl_xor(y2, off);
    if (qq == 0) Yc[pt] = y2;
    ushort4 cb;
    cb.x = f2bf(cv.x); cb.y = f2bf(cv.y); cb.z = f2bf(cv.z); cb.w = f2bf(cv.w);
    // replicate center into the 20 MFMA rows of this point: rows a*16 + pt*4 + j
    #pragma unroll
    for (int a = 0; a < 5; a++)
      #pragma unroll
      for (int j2 = 0; j2 < 4; j2++)
        *((ushort4*)(Abf + (a*16 + pt*4 + j2)*136 + 64 + qq*4)) = cb;
  }
  __syncthreads();
  // Region B: parallel rank-based 4-way merge. 320 items; rank = own idx + 3 binary searches.
  for (int e = tid; e < 320; e += 256) {
    int pt = e / 80;
    int rem = e - pt*80;
    int c = rem / 20;
    int i = rem - c*20;
    const unsigned* LB = keybuf + pt*80;
    unsigned v = LB[c*20 + i];
    int rank = i;
    #pragma unroll
    for (int c2 = 0; c2 < 4; c2++) {
      if (c2 == c) continue;
      rank += cnt_gt(LB + c2*20, v);
    }
    if (rank < KNN) nbr[pt*20 + rank] = 1023 - (int)(v & 1023u);
  }
  __syncthreads();
  // Region C: gather + Mobius in one pass, all fp32 (center from Cf), single divide
  for (int e = tid; e < 80*16; e += 256) {
    int r = e >> 4, qq = e & 15;
    int q = (r >> 2) & 3;
    int L = 20*q + 4*(r >> 4) + (r & 3);
    float4 f = *((const float4*)(xp2 + (size_t)(b*N_ + nbr[L])*64) + qq);
    float4 cvf = *((const float4*)&Cf[q][qq*4]);
    float X2 = f.x*f.x + f.y*f.y + f.z*f.z + f.w*f.w;
    float XY = -(f.x*cvf.x + f.y*cvf.y + f.z*cvf.z + f.w*cvf.w);
    #pragma unroll
    for (int off = 8; off > 0; off >>= 1) {
      X2 += __shfl_xor(X2, off);
      XY += __shfl_xor(XY, off);
    }
    float Y2 = Yc[q];
    float den = fmaxf(1.0f + 0.02f*XY + 1e-4f*X2*Y2, 1e-15f);
    float inv = 1.0f / den;
    float s1 = (1.0f + 0.02f*XY + 0.01f*Y2) * inv;
    float s2 = (1.0f - 0.01f*X2) * inv;
    ushort4 mo;
    mo.x = f2bf(s1*f.x - s2*cvf.x);
    mo.y = f2bf(s1*f.y - s2*cvf.y);
    mo.z = f2bf(s1*f.z - s2*cvf.z);
    mo.w = f2bf(s1*f.w - s2*cvf.w);
    *((ushort4*)(Abf + r*136 + qq*4)) = mo;
  }
  __syncthreads();
  // Region D: MFMA + register epilogue (fp16 max/min stores, fp32 stats atomics)
  int wave = tid >> 6, lane = tid & 63;
  int quad = lane >> 4, lm = lane & 15;
  int colbase = wave*48;
  f32x4 acc[5][3];
  #pragma unroll
  for (int rt = 0; rt < 5; rt++)
    #pragma unroll
    for (int cj = 0; cj < 3; cj++) acc[rt][cj] = (f32x4){0.f, 0.f, 0.f, 0.f};
  #pragma unroll
  for (int kt = 0; kt < 4; kt++) {
    int k0 = kt*32 + quad*8;
    bf16x8 bf[3];
    #pragma unroll
    for (int cj = 0; cj < 3; cj++)
      bf[cj] = *((const bf16x8*)(w2h + (size_t)(colbase + cj*16 + lm)*128 + k0));
    bf16x8 af[5];
    #pragma unroll
    for (int rt = 0; rt < 5; rt++)
      af[rt] = *((const bf16x8*)(Abf + (rt*16 + lm)*136 + k0));
    #pragma unroll
    for (int rt = 0; rt < 5; rt++)
      #pragma unroll
      for (int cj = 0; cj < 3; cj++)
        acc[rt][cj] = __builtin_amdgcn_mfma_f32_16x16x32_bf16(af[rt], bf[cj], acc[rt][cj], 0, 0, 0);
  }
  #pragma unroll
  for (int cj = 0; cj < 3; cj++) {
    int o = colbase + cj*16 + lm;
    float s = 0.f, s2 = 0.f, mx = -__builtin_inff(), mn = __builtin_inff();
    #pragma unroll
    for (int rt = 0; rt < 5; rt++) {
      #pragma unroll
      for (int reg = 0; reg < 4; reg++) {
        float h = acc[rt][cj][reg];
        s += h; s2 += h*h;
        mx = fmaxf(mx, h); mn = fminf(mn, h);
      }
    }
    hmax2[(size_t)(p0 + quad)*192 + o] = f2h(mx);
    hmin2[(size_t)(p0 + quad)*192 + o] = f2h(mn);
    s  += __shfl_xor(s, 16);  s  += __shfl_xor(s, 32);
    s2 += __shfl_xor(s2, 16); s2 += __shfl_xor(s2, 32);
    if (lane < 16) {
      float* dst = stats2sh + ((size_t)(bi & 255)*192 + o)*2;
      atomicAdd(dst, s); atomicAdd(dst + 1, s2);
    }
  }
}

// ---------- 11) conv3 via bf16 MFMA: ch0-63 from x1h (already bf16), ch64-255 from fp16 hmax2/hmin2 ----------
__global__ void __launch_bounds__(256) k_conv3m(
   const unsigned short* __restrict__ x1h,
   const unsigned short* __restrict__ hmax2, const unsigned short* __restrict__ hmin2,
   const float* __restrict__ scale2, const float* __restrict__ shift2,
   const unsigned short* __restrict__ wt3h, float* __restrict__ stats3sh,
   unsigned* __restrict__ hmax3u, unsigned* __restrict__ hmin3u) {
  __shared__ short As[64*264];
  int tid = threadIdx.x;
  int mt = blockIdx.x >> 2, cb = blockIdx.x & 3;
  int rowbase = mt*64;
  int b = rowbase >> 10;
  int c4 = tid & 63;
  float4 sc, sh;
  if (c4 >= 16) {
    sc = *((const float4*)(scale2 + (c4*4 - 64)));
    sh = *((const float4*)(shift2 + (c4*4 - 64)));
  }
  #pragma unroll 4
  for (int i = 0; i < 16; i++) {
    int r = (tid >> 6) + i*4;
    int p = rowbase + r;
    if (c4 < 16) {
      // channels 0..63: x1h already holds f2bf(relu(BN1(h))) in (B,N,64) layout
      *((ushort4*)(As + r*264 + c4*4)) =
        *((const ushort4*)(x1h + (size_t)p*64 + c4*4));
    } else {
      ushort4 hx4 = *((const ushort4*)(hmax2 + (size_t)p*192 + (c4*4 - 64)));
      ushort4 hn4 = *((const ushort4*)(hmin2 + (size_t)p*192 + (c4*4 - 64)));
      ushort4 o4;
      o4.x = f2bf(fmaxf(fmaf(sc.x, (sc.x >= 0.f ? h2f(hx4.x) : h2f(hn4.x)), sh.x), 0.f));
      o4.y = f2bf(fmaxf(fmaf(sc.y, (sc.y >= 0.f ? h2f(hx4.y) : h2f(hn4.y)), sh.y), 0.f));
      o4.z = f2bf(fmaxf(fmaf(sc.z, (sc.z >= 0.f ? h2f(hx4.z) : h2f(hn4.z)), sh.z), 0.f));
      o4.w = f2bf(fmaxf(fmaf(sc.w, (sc.w >= 0.f ? h2f(hx4.w) : h2f(hn4.w)), sh.w), 0.f));
      *((ushort4*)(As + r*264 + c4*4)) = o4;
    }
  }
  __syncthreads();
  int wave = tid >> 6, lane = tid & 63;
  int quad = lane >> 4, lm = lane & 15;
  int colbase = cb*256 + wave*64;
  f32x4 acc[4][4];
  #pragma unroll
  for (int ri = 0; ri < 4; ri++)
    #pragma unroll
    for (int cj = 0; cj < 4; cj++) acc[ri][cj] = (f32x4){0.f, 0.f, 0.f, 0.f};
  for (int kt = 0; kt < 8; kt++) {
    int k0 = kt*32 + quad*8;
    bf16x8 bf[4];
    #pragma unroll
    for (int cj = 0; cj < 4; cj++)
      bf[cj] = *((const bf16x8*)(wt3h + (size_t)(colbase + cj*16 + lm)*256 + k0));
    bf16x8 af[4];
    #pragma unroll
    for (int ri = 0; ri < 4; ri++)
      af[ri] = *((const bf16x8*)(As + (ri*16 + lm)*264 + k0));
    #pragma unroll
    for (int ri = 0; ri < 4; ri++)
      #pragma unroll
      for (int cj = 0; cj < 4; cj++)
        acc[ri][cj] = __builtin_amdgcn_mfma_f32_16x16x32_bf16(af[ri], bf[cj], acc[ri][cj], 0, 0, 0);
  }
  #pragma unroll
  for (int cj = 0; cj < 4; cj++) {
    float s = 0.f, s2 = 0.f, mx = -__builtin_inff(), mn = __builtin_inff();
    #pragma unroll
    for (int ri = 0; ri < 4; ri++) {
      #pragma unroll
      for (int reg = 0; reg < 4; reg++) {
        float h = acc[ri][cj][reg];
        s += h; s2 += h*h; mx = fmaxf(mx, h); mn = fminf(mn, h);
      }
    }
    s  += __shfl_xor(s, 16);  s  += __shfl_xor(s, 32);
    s2 += __shfl_xor(s2, 16); s2 += __shfl_xor(s2, 32);
    mx = fmaxf(mx, __shfl_xor(mx, 16)); mx = fmaxf(mx, __shfl_xor(mx, 32));
    mn = fminf(mn, __shfl_xor(mn, 16)); mn = fminf(mn, __shfl_xor(mn, 32));
    if (lane < 16) {
      int col = colbase + cj*16 + lane;
      float* dst = stats3sh + ((size_t)(blockIdx.x & 63)*1024 + col)*2;
      atomicAdd(dst, s);
      atomicAdd(dst + 1, s2);
      atomicMax(hmax3u + b*1024 + col, fkey(mx));
      atomicMin(hmin3u + b*1024 + col, fkey(mn));
    }
  }
}

// ---------- 12) head, split for weight-read parallelism ----------
__device__ float blk_reduce(float v, float* red, int tid) {
  red[tid] = v; __syncthreads();
  for (int st = 128; st > 0; st >>= 1) {
    if (tid < st) red[tid] += red[tid + st];
    __syncthreads();
  }
  float r = red[0]; __syncthreads();
  return r;
}

__global__ void __launch_bounds__(256) k_head1(const unsigned* __restrict__ hmax3u,
    const unsigned* __restrict__ hmin3u,
    const float* __restrict__ scale3, const float* __restrict__ shift3,
    const float* __restrict__ fc1w, const float* __restrict__ fc1b,
    float* __restrict__ h1buf) {
  __shared__ __align__(16) float V[1024];
  int b = blockIdx.x >> 5, oc = blockIdx.x & 31;
  int tid = threadIdx.x;
  for (int o = tid; o < 1024; o += 256) {
    float a = scale3[o];
    unsigned u = (a >= 0.f) ? hmax3u[b*1024 + o] : hmin3u[b*1024 + o];
    V[o] = fmaxf(fmaf(a, fkeyinv(u), shift3[o]), 0.f);
  }
  __syncthreads();
  int ty = tid >> 4, tx = tid & 15;
  int o = oc*16 + ty;
  const float4* wr = (const float4*)(fc1w + (size_t)o*1024) + tx*16;
  const float4* vv = (const float4*)V + tx*16;
  float s = 0.f;
  #pragma unroll
  for (int i = 0; i < 16; i++) {
    float4 w = wr[i]; float4 v = vv[i];
    s = fmaf(w.x, v.x, s); s = fmaf(w.y, v.y, s);
    s = fmaf(w.z, v.z, s); s = fmaf(w.w, v.w, s);
  }
  s += __shfl_xor(s, 1); s += __shfl_xor(s, 2);
  s += __shfl_xor(s, 4); s += __shfl_xor(s, 8);
  if (tx == 0) h1buf[b*512 + o] = s + fc1b[o];
}

__global__ void __launch_bounds__(256) k_head2(const float* __restrict__ h1buf,
    const float* __restrict__ ln1g, const float* __restrict__ ln1b,
    const float* __restrict__ fc2w, const float* __restrict__ fc2b,
    float* __restrict__ h2buf) {
  __shared__ __align__(16) float H1[512];
  __shared__ float red[256];
  int b = blockIdx.x >> 3, oc = blockIdx.x & 7;
  int tid = threadIdx.x;
  float v0 = h1buf[b*512 + tid], v1 = h1buf[b*512 + 256 + tid];
  float s = blk_reduce(v0 + v1, red, tid);
  float s2 = blk_reduce(v0*v0 + v1*v1, red, tid);
  float m = s / 512.f;
  float var = s2 / 512.f - m*m;
  float inv = 1.0f / sqrtf(var + 1e-5f);
  H1[tid] = fmaxf((v0 - m)*inv*ln1g[tid] + ln1b[tid], 0.f);
  H1[256 + tid] = fmaxf((v1 - m)*inv*ln1g[256 + tid] + ln1b[256 + tid], 0.f);
  __syncthreads();
  int ty = tid >> 3, tx = tid & 7;
  int o = oc*32 + ty;
  const float4* wr = (const float4*)(fc2w + (size_t)o*512) + tx*16;
  const float4* vv = (const float4*)H1 + tx*16;
  float t = 0.f;
  #pragma unroll
  for (int i = 0; i < 16; i++) {
    float4 w = wr[i]; float4 v = vv[i];
    t = fmaf(w.x, v.x, t); t = fmaf(w.y, v.y, t);
    t = fmaf(w.z, v.z, t); t = fmaf(w.w, v.w, t);
  }
  t += __shfl_xor(t, 1); t += __shfl_xor(t, 2); t += __shfl_xor(t, 4);
  if (tx == 0) h2buf[b*256 + o] = t + fc2b[o];
}

__global__ void __launch_bounds__(256) k_head3(const float* __restrict__ h2buf,
    const float* __restrict__ ln2g, const float* __restrict__ ln2b,
    const float* __restrict__ outw, const float* __restrict__ outb,
    float* __restrict__ out) {
  __shared__ __align__(16) float H2[256];
  __shared__ float red[256];
  int b = blockIdx.x, tid = threadIdx.x;
  float h2v = h2buf[b*256 + tid];
  float ss = blk_reduce(h2v, red, tid);
  float ss2 = blk_reduce(h2v*h2v, red, tid);
  float m2 = ss / 256.f;
  float var2 = ss2 / 256.f - m2*m2;
  float inv2 = 1.0f / sqrtf(var2 + 1e-5f);
  H2[tid] = fmaxf((h2v - m2)*inv2*ln2g[tid] + ln2b[tid], 0.f);
  __syncthreads();
  if (tid < 40) {
    const float4* wr = (const float4*)(outw + (size_t)tid*256);
    float t = 0.f;
    for (int c4 = 0; c4 < 64; c4++) {
      float4 w = wr[c4]; float4 vv = ((const float4*)H2)[c4];
      t = fmaf(w.x, vv.x, t); t = fmaf(w.y, vv.y, t);
      t = fmaf(w.z, vv.z, t); t = fmaf(w.w, vv.w, t);
    }
    red[tid] = t + outb[tid];
  }
  __syncthreads();
  if (tid == 0) {
    float mx = -__builtin_inff();
    for (int i2 = 0; i2 < 40; i2++) mx = fmaxf(mx, red[i2]);
    float se = 0.f;
    for (int i2 = 0; i2 < 40; i2++) se += expf(red[i2] - mx);
    float lse = mx + logf(se);
    for (int i2 = 0; i2 < 40; i2++) out[b*40 + i2] = red[i2] - lse;
  }
}

extern "C" void kernel_launch(void* const* d_in, const int* in_sizes, int n_in,
                              void* d_out, int out_size, void* d_ws, size_t ws_size,
                              hipStream_t stream) {
  (void)in_sizes; (void)n_in; (void)out_size; (void)ws_size;
  const float* x    = (const float*)d_in[0];
  const float* w1   = (const float*)d_in[1];
  const float* bn1g = (const float*)d_in[2];
  const float* bn1b = (const float*)d_in[3];
  const float* w2   = (const float*)d_in[4];
  const float* bn2g = (const float*)d_in[5];
  const float* bn2b = (const float*)d_in[6];
  const float* w3   = (const float*)d_in[7];
  const float* bn3g = (const float*)d_in[8];
  const float* bn3b = (const float*)d_in[9];
  const float* fc1w = (const float*)d_in[10];
  const float* fc1b = (const float*)d_in[11];
  const float* ln1g = (const float*)d_in[12];
  const float* ln1b = (const float*)d_in[13];
  const float* fc2w = (const float*)d_in[14];
  const float* fc2b = (const float*)d_in[15];
  const float* ln2g = (const float*)d_in[16];
  const float* ln2b = (const float*)d_in[17];
  const float* outw = (const float*)d_in[18];
  const float* outb = (const float*)d_in[19];
  float* out = (float*)d_out;

  float* ws = (float*)d_ws;
  size_t off = 0;
  float* xp1   = ws + off; off += 49152;
  float* hmax1 = ws + off; off += 1048576;
  float* hmin1 = ws + off; off += 1048576;
  float* xp2   = ws + off; off += 1048576;
  float* hmax2f = ws + off; off += 3145728;  // holds keypartA (knn1 partials) then fp16 hmax2
  float* hmin2f = ws + off; off += 3145728;  // fp16 hmin2
  unsigned* keypart2 = (unsigned*)(ws + off); off += 1310720;  // knn2 partials, 80/pt
  unsigned short* w2h = (unsigned short*)(ws + off); off += 24576;
  unsigned short* wt3h = (unsigned short*)(ws + off); off += 131072;
  float* x1bf  = ws + off; off += 1048576;   // x1 bf16 hi (2MB) + lo (2MB), (B,N,64) layout
  float* xx1   = ws + off; off += 16384;
  float* h1buf = ws + off; off += 8192;
  float* h2buf = ws + off; off += 4096;
  float* scale1 = ws + off; off += 64;
  float* shift1 = ws + off; off += 64;
  float* scale2 = ws + off; off += 192;
  float* shift2 = ws + off; off += 192;
  float* scale3 = ws + off; off += 1024;
  float* shift3 = ws + off; off += 1024;
  float* stats1sh = ws + off;                         // fp32 stats
  float* stats2sh = stats1sh + 64*64*2;
  float* stats3sh = stats2sh + (size_t)256*192*2;
  unsigned* hmax3u = (unsigned*)(stats3sh + (size_t)64*1024*2);
  unsigned* hmin3u = hmax3u + 16384;
  unsigned* keypartA = (unsigned*)hmax2f;
  unsigned short* x1h = (unsigned short*)x1bf;
  unsigned short* x1l = x1h + 1048576;
  unsigned short* hmax2 = (unsigned short*)hmax2f;
  unsigned short* hmin2 = (unsigned short*)hmin2f;

  size_t zero_bytes = ((size_t)64*64*2 + (size_t)256*192*2 + (size_t)64*1024*2)*4 + (size_t)16384*4;
  hipMemsetAsync(stats1sh, 0, zero_bytes, stream);
  hipMemsetAsync(hmin3u, 0xFF, (size_t)16384*4, stream);

  k_prep_knn1<<<1536, 256, 0, stream>>>(x, xp1, w2, w3, w2h, wt3h, keypartA);
  k_conv1<<<1024, 256, 0, stream>>>(xp1, keypartA, w1, hmax1, hmin1, stats1sh);
  k_bn_reduce<<<64, 64, 0, stream>>>(stats1sh, 64, 64, 327680.0, bn1g, bn1b, scale1, shift1);
  k_bn1_apply<<<256, 256, 0, stream>>>(hmax1, hmin1, scale1, shift1, xp2, x1h, x1l, xx1);
  k_knn2g<<<1024, 256, 0, stream>>>(x1h, x1l, xx1, keypart2);
  k_conv2m<<<4096, 256, 0, stream>>>(xp2, keypart2, w2h, hmax2, hmin2, stats2sh);
  k_bn_reduce<<<192, 64, 0, stream>>>(stats2sh, 192, 256, 327680.0, bn2g, bn2b, scale2, shift2);
  k_conv3m<<<1024, 256, 0, stream>>>(x1h, hmax2, hmin2, scale2, shift2,
                                     wt3h, stats3sh, hmax3u, hmin3u);
  k_bn_reduce<<<1024, 64, 0, stream>>>(stats3sh, 1024, 64, 16384.0, bn3g, bn3b, scale3, shift3);
  k_head1<<<512, 256, 0, stream>>>(hmax3u, hmin3u, scale3, shift3, fc1w, fc1b, h1buf);
  k_head2<<<128, 256, 0, stream>>>(h1buf, ln1g, ln1b, fc2w, fc2b, h2buf);
  k_head3<<<16, 256, 0, stream>>>(h2buf, ln2g, ln2b, outw, outb, out);
}

// Round 9
// 343.431 us; speedup vs baseline: 1.0192x; 1.0118x over previous
//
#include <hip/hip_runtime.h>
#include <math.h>

#define B_ 16
#define N_ 1024
#define KNN 20
#define NPAIR (B_*N_)

typedef __attribute__((ext_vector_type(8))) short bf16x8;
typedef __attribute__((ext_vector_type(4))) float f32x4;

// ---------- helpers ----------
__device__ __forceinline__ unsigned fkey(float f) {
  unsigned u = __float_as_uint(f);
  return (u & 0x80000000u) ? ~u : (u | 0x80000000u);
}
__device__ __forceinline__ float fkeyinv(unsigned u) {
  unsigned b = (u & 0x80000000u) ? (u ^ 0x80000000u) : ~u;
  return __uint_as_float(b);
}
__device__ __forceinline__ unsigned short f2bf(float x) {  // RNE float->bf16
  unsigned u = __float_as_uint(x);
  unsigned r = (u + 0x7FFFu + ((u >> 16) & 1u)) >> 16;
  return (unsigned short)r;
}
__device__ __forceinline__ float bf2f(unsigned short u) {
  return __uint_as_float(((unsigned)u) << 16);
}
__device__ __forceinline__ unsigned short f2h(float x) {   // RNE float->fp16
  _Float16 h = (_Float16)x;
  return *(unsigned short*)&h;
}
__device__ __forceinline__ float h2f(unsigned short u) {
  _Float16 h = *(_Float16*)&u;
  return (float)h;
}
// packed knn key: top 22 bits of fkey(d) | (1023 - idx). u32 '>' == dist desc, idx asc.
__device__ __forceinline__ unsigned knnkey(float d, int idx) {
  return (fkey(d) & 0xFFFFFC00u) | (unsigned)(1023 - idx);
}

// Branchless sorted-insert (descending) of packed u32 key: 2 ops/stage.
__device__ __forceinline__ void topk_insert_u32(unsigned (&kl)[KNN], unsigned nk) {
  kl[KNN-1] = nk;
  #pragma unroll
  for (int i = KNN-1; i > 0; i--) {
    unsigned hi = max(kl[i-1], kl[i]);
    unsigned lo = min(kl[i-1], kl[i]);
    kl[i-1] = hi; kl[i] = lo;
  }
}

// count of elements strictly greater than v in sorted-desc list L of 20 (5-step bsearch)
__device__ __forceinline__ int cnt_gt(const unsigned* __restrict__ L, unsigned v) {
  int j = 0;
  #pragma unroll
  for (int s = 16; s; s >>= 1) {
    int nj = j + s;
    if (nj <= KNN && L[nj-1] > v) j = nj;
  }
  return j;
}

// ---------- 1) fused prep + knn1: blocks 0..511 = knn1 8-way split; 512..1535 = prep ----------
__global__ void __launch_bounds__(256) k_prep_knn1(const float* __restrict__ x,
        float* __restrict__ xp1, const float* __restrict__ w2, const float* __restrict__ w3,
        unsigned short* __restrict__ w2h, unsigned short* __restrict__ wt3h,
        unsigned* __restrict__ keypart) {
  __shared__ float P[N_*3];
  __shared__ float XX[N_];
  if (blockIdx.x >= 512) {
    int i = (blockIdx.x - 512) * 256 + threadIdx.x;
    if (i < NPAIR) {
      float a0 = x[i*3+0], a1 = x[i*3+1], a2 = x[i*3+2];
      float n = sqrtf(a0*a0 + a1*a1 + a2*a2);
      n = fmaxf(n, 1e-15f);
      float th = tanhf(0.1f * n);
      float sc = th / (0.1f * n);
      float ny = fmaxf(th * 10.0f, 1e-15f);
      float mxn = (1.0f - 4e-3f) / 0.1f;
      if (ny > mxn) sc *= mxn / ny;
      xp1[i*3+0] = sc*a0; xp1[i*3+1] = sc*a1; xp1[i*3+2] = sc*a2;
    }
    if (i < 192*128) w2h[i] = f2bf(w2[i]);
    wt3h[i] = f2bf(w3[i]);
    return;
  }
  int blk = blockIdx.x;
  int b = blk >> 5, rc = (blk >> 3) & 3, cc = blk & 7;
  const float* xb = x + b*N_*3;
  for (int e = threadIdx.x; e < N_*3; e += 256) P[e] = xb[e];
  __syncthreads();
  for (int j = threadIdx.x; j < N_; j += 256) {
    float q0 = P[j*3], q1 = P[j*3+1], q2 = P[j*3+2];
    XX[j] = q0*q0 + q1*q1 + q2*q2;
  }
  __syncthreads();
  int r = rc*256 + threadIdx.x;
  float q0 = P[r*3], q1 = P[r*3+1], q2 = P[r*3+2];
  float xxq = XX[r];
  unsigned kl[KNN];
  #pragma unroll
  for (int i = 0; i < KNN; i++) kl[i] = 0u;
  int cbase = cc*128;
  for (int jj = 0; jj < 128; jj++) {
    int j = cbase + jj;
    float dot = q0*P[j*3] + q1*P[j*3+1] + q2*P[j*3+2];
    float d = 2.0f*dot - xxq - XX[j];
    unsigned nk = knnkey(d, j);
    if (nk > kl[KNN-1]) topk_insert_u32(kl, nk);
  }
  int p = b*N_ + r;
  unsigned* pe = keypart + (size_t)p*160 + cc*20;
  #pragma unroll
  for (int i = 0; i < KNN; i++) pe[i] = kl[i];
}

// ---------- 3) conv1 fused v2: parallel pairwise merge tree (8->4->2->1), fp32 stats ----------
__global__ void __launch_bounds__(256) k_conv1(const float* __restrict__ xp1,
                        const unsigned* __restrict__ keypart,
                        const float* __restrict__ w1, float* __restrict__ hmax1,
                        float* __restrict__ hmin1, float* __restrict__ stats1sh) {
  __shared__ float F[4][KNN][6];
  __shared__ float red[4][64][2];
  __shared__ int idxs[16][KNN];
  __shared__ unsigned keybuf[2560];   // 16 pairs x 160 keys, 10 KB
  __shared__ unsigned out1[1280];     // level-1 merged: 16 pts x 4 lists x 20
  __shared__ unsigned out2[640];      // level-2 merged: 16 pts x 2 lists x 20
  int g = threadIdx.x >> 6, lane = threadIdx.x & 63;
  int tid = threadIdx.x;
  int pbase = blockIdx.x * 16;
  {
    const unsigned* src = keypart + (size_t)pbase*160;
    for (int e = tid; e < 2560; e += 256) keybuf[e] = src[e];
  }
  float w[6];
  #pragma unroll
  for (int c = 0; c < 6; c++) w[c] = w1[lane*6 + c];
  __syncthreads();
  // L1: merge (2m, 2m+1) -> out1[pt][m][.]  (2560 items, all parallel)
  for (int e = tid; e < 2560; e += 256) {
    int pt = e / 160, rem = e - pt*160;
    int m = rem / 40, i = rem - m*40;
    const unsigned* A = keybuf + pt*160 + (2*m)*20;
    const unsigned* Bl = A + 20;
    unsigned v; const unsigned* S; int own;
    if (i < 20) { v = A[i]; S = Bl; own = i; }
    else { v = Bl[i-20]; S = A; own = i-20; }
    int rank = own + cnt_gt(S, v);
    if (rank < KNN) out1[(pt*4 + m)*20 + rank] = v;
  }
  __syncthreads();
  // L2: merge (2m2, 2m2+1) of out1 -> out2[pt][m2][.]  (1280 items)
  for (int e = tid; e < 1280; e += 256) {
    int pt = e / 80, rem = e - pt*80;
    int m2 = rem / 40, i = rem - m2*40;
    const unsigned* A = out1 + (pt*4 + 2*m2)*20;
    const unsigned* Bl = A + 20;
    unsigned v; const unsigned* S; int own;
    if (i < 20) { v = A[i]; S = Bl; own = i; }
    else { v = Bl[i-20]; S = A; own = i-20; }
    int rank = own + cnt_gt(S, v);
    if (rank < KNN) out2[(pt*2 + m2)*20 + rank] = v;
  }
  __syncthreads();
  // L3: final merge -> idxs  (640 items)
  for (int e = tid; e < 640; e += 256) {
    int pt = e / 40, i = e - pt*40;
    const unsigned* A = out2 + pt*40;
    const unsigned* Bl = A + 20;
    unsigned v; const unsigned* S; int own;
    if (i < 20) { v = A[i]; S = Bl; own = i; }
    else { v = Bl[i-20]; S = A; own = i-20; }
    int rank = own + cnt_gt(S, v);
    if (rank < KNN) idxs[pt][rank] = 1023 - (int)(v & 1023u);
  }
  float sum = 0.f, sumsq = 0.f;
  __syncthreads();
  for (int it = 0; it < 4; ++it) {
    int p = pbase + it*4 + g;
    if (lane < KNN) {
      int nb = idxs[it*4 + g][lane];
      int bb = p >> 10;
      const float* xc = xp1 + p*3;
      const float* ft = xp1 + (bb*N_ + nb)*3;
      float x0 = ft[0], x1 = ft[1], x2v = ft[2];
      float c0 = xc[0], c1 = xc[1], c2 = xc[2];
      float X2 = x0*x0 + x1*x1 + x2v*x2v;
      float Y2 = c0*c0 + c1*c1 + c2*c2;
      float XY = -(x0*c0 + x1*c1 + x2v*c2);
      float den = fmaxf(1.0f + 0.02f*XY + 1e-4f*X2*Y2, 1e-15f);
      float s1 = (1.0f + 0.02f*XY + 0.01f*Y2) / den;
      float s2 = (1.0f - 0.01f*X2) / den;
      F[g][lane][0] = s1*x0 - s2*c0;
      F[g][lane][1] = s1*x1 - s2*c1;
      F[g][lane][2] = s1*x2v - s2*c2;
      F[g][lane][3] = c0; F[g][lane][4] = c1; F[g][lane][5] = c2;
    }
    __syncthreads();
    float mx = -__builtin_inff(), mn = __builtin_inff();
    for (int k = 0; k < KNN; k++) {
      float h = 0.f;
      #pragma unroll
      for (int c = 0; c < 6; c++) h = fmaf(w[c], F[g][k][c], h);
      mx = fmaxf(mx, h); mn = fminf(mn, h);
      sum += h; sumsq += h*h;
    }
    hmax1[(pbase + it*4 + g)*64 + lane] = mx;
    hmin1[(pbase + it*4 + g)*64 + lane] = mn;
    __syncthreads();
  }
  red[g][lane][0] = sum; red[g][lane][1] = sumsq;
  __syncthreads();
  if (g == 0) {
    float s  = red[0][lane][0] + red[1][lane][0] + red[2][lane][0] + red[3][lane][0];
    float s2 = red[0][lane][1] + red[1][lane][1] + red[2][lane][1] + red[3][lane][1];
    float* dst = stats1sh + ((size_t)(blockIdx.x & 63)*64 + lane)*2;
    atomicAdd(dst, s);
    atomicAdd(dst + 1, s2);
  }
}

// ---------- BN stat reduce v4 (fp32 slots, f64 cross-slot accumulation) ----------
__global__ void __launch_bounds__(64) k_bn_reduce(const float* __restrict__ sh, int nch, int nslots,
                            double cnt,
                            const float* __restrict__ g, const float* __restrict__ bb,
                            float* __restrict__ scale, float* __restrict__ shift) {
  int o = blockIdx.x, t = threadIdx.x;
  double s = 0.0, s2 = 0.0;
  for (int sl = t; sl < nslots; sl += 64) {
    s  += (double)sh[((size_t)sl*nch + o)*2];
    s2 += (double)sh[((size_t)sl*nch + o)*2 + 1];
  }
  #pragma unroll
  for (int off = 32; off > 0; off >>= 1) { s += __shfl_xor(s, off); s2 += __shfl_xor(s2, off); }
  if (t == 0) {
    double m = s / cnt;
    double v = s2 / cnt - m*m;
    float a = g[o] / sqrtf((float)v + 1e-5f);
    scale[o] = a;
    shift[o] = bb[o] - a * (float)m;
  }
}

// ---------- 5) BN1 apply + relu + e2p + bf16 hi/lo split for MFMA knn2 + |x1|^2 ----------
__global__ void __launch_bounds__(256) k_bn1_apply(const float* __restrict__ hmax1, const float* __restrict__ hmin1,
                            const float* __restrict__ scale1, const float* __restrict__ shift1,
                            float* __restrict__ xp2,
                            unsigned short* __restrict__ x1h, unsigned short* __restrict__ x1l,
                            float* __restrict__ xx1) {
  int b = blockIdx.x >> 4, nc = blockIdx.x & 15;
  int c = threadIdx.x & 63, sub = threadIdx.x >> 6;
  int n0 = nc*64 + sub*16;
  float a = scale1[c], t = shift1[c];
  #pragma unroll
  for (int i = 0; i < 16; i++) {
    int p = b*1024 + n0 + i;
    float h = (a >= 0.f) ? hmax1[(size_t)p*64 + c] : hmin1[(size_t)p*64 + c];
    float x1 = fmaxf(fmaf(a, h, t), 0.f);
    // split-bf16: x1 = hi + lo with both bf16; dot via 4-term MFMA is fp32-accurate to ~2^-17
    unsigned short hb = f2bf(x1);
    x1h[(size_t)p*64 + c] = hb;
    x1l[(size_t)p*64 + c] = f2bf(x1 - bf2f(hb));
    float n2 = x1*x1;
    #pragma unroll
    for (int off = 32; off > 0; off >>= 1) n2 += __shfl_xor(n2, off);
    if (c == 0) xx1[p] = n2;
    float n1 = fmaxf(sqrtf(n2), 1e-15f);
    float th = tanhf(0.1f * n1);
    float sc = th / (0.1f * n1);
    float ny = fmaxf(th * 10.0f, 1e-15f);
    float mxn = (1.0f - 4e-3f) / 0.1f;
    if (ny > mxn) sc *= mxn / ny;
    xp2[(size_t)p*64 + c] = sc * x1;
  }
}

// ---------- 6) knn2 v11: register-only scan (v10) + register-linear rank-merge tail ----------
// Scan: MFMA + 2-round shfl_xor butterfly transpose -> each lane holds its query's 16 cands in regs.
// Merge: (L0,L1)->M0, (L2,L3)->M1 with 256 units (pair,side,q): own+other lists loaded to REGISTERS
// (40 pipelined LDS reads), rank = i + 20 unrolled compares -- no dependent-LDS bsearch chains.
__global__ void __launch_bounds__(256) k_knn2g(const unsigned short* __restrict__ x1h,
        const unsigned short* __restrict__ x1l,
        const float* __restrict__ xx1, unsigned* __restrict__ keypart2) {
  __shared__ unsigned LU[5376];                  // 4 lists x 64q x 21 (21 KB)
  __shared__ unsigned MU[2688];                  // 2 merged x 64q x 21 (10.5 KB)
  int tid = threadIdx.x;
  int bi = blockIdx.x;
  int blk = ((bi & 7) << 7) + (bi >> 3);     // XCD-affine swizzle (1024 = 8*128, bijective)
  int b = blk >> 6, qc = (blk >> 2) & 15, cc = blk & 3;
  int qbase = qc*64, ccbase = cc*256;
  int wave = tid >> 6, lane = tid & 63;
  int lm = lane & 15, kq = lane >> 4;
  const size_t base = (size_t)b * 65536;     // b*1024*64

  // Q fragments (hi/lo) held in registers for the whole kernel: 4 qtiles x 2 ksteps
  bf16x8 Qh[4][2], Ql[4][2];
  #pragma unroll
  for (int qt = 0; qt < 4; qt++) {
    size_t ro = base + (size_t)(qbase + qt*16 + lm)*64 + kq*8;
    #pragma unroll
    for (int ks = 0; ks < 2; ks++) {
      Qh[qt][ks] = *((const bf16x8*)(x1h + ro + ks*32));
      Ql[qt][ks] = *((const bf16x8*)(x1l + ro + ks*32));
    }
  }
  unsigned kl[KNN];
  #pragma unroll
  for (int i = 0; i < KNN; i++) kl[i] = 0u;

  for (int st = 0; st < 4; ++st) {
    int cb0 = ccbase + st*64;
    // A fragments: this wave's 16 candidates, hi/lo
    size_t co = base + (size_t)(cb0 + wave*16 + lm)*64 + kq*8;
    bf16x8 Ah[2], Al[2];
    #pragma unroll
    for (int ks = 0; ks < 2; ks++) {
      Ah[ks] = *((const bf16x8*)(x1h + co + ks*32));
      Al[ks] = *((const bf16x8*)(x1l + co + ks*32));
    }
    float4 xxc = *((const float4*)(xx1 + b*1024 + cb0 + wave*16 + kq*4));
    f32x4 acc[4];
    #pragma unroll
    for (int qt = 0; qt < 4; qt++) acc[qt] = (f32x4){0.f, 0.f, 0.f, 0.f};
    #pragma unroll
    for (int ks = 0; ks < 2; ks++) {
      #pragma unroll
      for (int qt = 0; qt < 4; qt++) {
        acc[qt] = __builtin_amdgcn_mfma_f32_16x16x32_bf16(Ah[ks], Qh[qt][ks], acc[qt], 0, 0, 0);
        acc[qt] = __builtin_amdgcn_mfma_f32_16x16x32_bf16(Ah[ks], Ql[qt][ks], acc[qt], 0, 0, 0);
        acc[qt] = __builtin_amdgcn_mfma_f32_16x16x32_bf16(Al[ks], Qh[qt][ks], acc[qt], 0, 0, 0);
        acc[qt] = __builtin_amdgcn_mfma_f32_16x16x32_bf16(Al[ks], Ql[qt][ks], acc[qt], 0, 0, 0);
      }
    }
    // dist adjust while layout is [qt][cand r of own kq group]: xxcv[r] matches cand kq*4+r
    // (-xxq omitted: constant per query row, rank-invariant)
    f32x4 xxv = (f32x4){xxc.x, xxc.y, xxc.z, xxc.w};
    #pragma unroll
    for (int qt = 0; qt < 4; qt++) acc[qt] = acc[qt]*2.0f - xxv;
    // 4x4 cross-lane block transpose within {lm, lm+16, lm+32, lm+48}:
    // after: acc[qt][r] = D[lane][qt*4+r]
    {
      f32x4 s0, s1, r0, r1;
      bool h1 = (kq & 1) != 0;
      if (h1) { s0 = acc[0]; s1 = acc[2]; } else { s0 = acc[1]; s1 = acc[3]; }
      #pragma unroll
      for (int e = 0; e < 4; e++) { r0[e] = __shfl_xor(s0[e], 16); r1[e] = __shfl_xor(s1[e], 16); }
      if (h1) { acc[0] = r0; acc[2] = r1; } else { acc[1] = r0; acc[3] = r1; }
      bool h2 = (kq & 2) != 0;
      if (h2) { s0 = acc[0]; s1 = acc[1]; } else { s0 = acc[2]; s1 = acc[3]; }
      #pragma unroll
      for (int e = 0; e < 4; e++) { r0[e] = __shfl_xor(s0[e], 32); r1[e] = __shfl_xor(s1[e], 32); }
      if (h2) { acc[0] = r0; acc[1] = r1; } else { acc[2] = r0; acc[3] = r1; }
    }
    // scan own query's 16 candidates straight from registers
    #pragma unroll
    for (int c = 0; c < 16; c++) {
      float d = acc[c >> 2][c & 3];
      unsigned nk = knnkey(d, cb0 + wave*16 + c);
      if (nk > kl[KNN-1]) topk_insert_u32(kl, nk);
    }
  }
  // publish per-wave lists
  #pragma unroll
  for (int i = 0; i < KNN; i++) LU[wave*1344 + lane*21 + i] = kl[i];
  __syncthreads();
  // merge L1: (L0,L1)->M0, (L2,L3)->M1.  256 units = (pair, side, q); register-linear rank.
  {
    int pair = tid >> 7, side = (tid >> 6) & 1, q = tid & 63;
    const unsigned* own = LU + (pair*2 + side)*1344 + q*21;
    const unsigned* oth = LU + (pair*2 + 1 - side)*1344 + q*21;
    unsigned ow[KNN], ot[KNN];
    #pragma unroll
    for (int i = 0; i < KNN; i++) { ow[i] = own[i]; ot[i] = oth[i]; }
    unsigned* dst = MU + pair*1344 + q*21;
    #pragma unroll
    for (int i = 0; i < KNN; i++) {
      int r = i;
      #pragma unroll
      for (int j = 0; j < KNN; j++) r += (ot[j] > ow[i]) ? 1 : 0;
      if (r < KNN) dst[r] = ow[i];
    }
  }
  __syncthreads();
  // merge L2: (M0,M1) -> keypart2.  128 units = (side, q); register-linear rank.
  if (tid < 128) {
    int side = tid >> 6, q = tid & 63;
    const unsigned* own = MU + side*1344 + q*21;
    const unsigned* oth = MU + (1 - side)*1344 + q*21;
    unsigned ow[KNN], ot[KNN];
    #pragma unroll
    for (int i = 0; i < KNN; i++) { ow[i] = own[i]; ot[i] = oth[i]; }
    unsigned* pe = keypart2 + (size_t)(b*N_ + qbase + q)*80 + cc*20;
    #pragma unroll
    for (int i = 0; i < KNN; i++) {
      int r = i;
      #pragma unroll
      for (int j = 0; j < KNN; j++) r += (ot[j] > ow[i]) ? 1 : 0;
      if (r < KNN) pe[r] = ow[i];
    }
  }
}

// ---------- 9) conv2 via bf16 MFMA v11: rank-merge + fp32 center + fp16 hmax/hmin + fp32 stats ----------
__global__ void __launch_bounds__(256) k_conv2m(const float* __restrict__ xp2,
    const unsigned* __restrict__ keypart2, const unsigned short* __restrict__ w2h,
    unsigned short* __restrict__ hmax2, unsigned short* __restrict__ hmin2,
    float* __restrict__ stats2sh) {
  __shared__ __align__(16) short Abf[80*136];
  __shared__ __align__(16) float Cf[4][64];      // fp32 centers for Mobius math
  __shared__ float Yc[4];
  __shared__ int nbr[80];                        // logical order [pt*20 + k]
  __shared__ unsigned keybuf[320];               // 4 pairs x 80 keys
  int tid = threadIdx.x;
  int bi = blockIdx.x;
  int g512 = ((bi & 7) << 9) + (bi >> 3);
  int p0 = g512 * 4;
  int b = p0 >> 10;
  // Region A: stage merge keys (all threads) + center rows/Y2 (first wave) concurrently
  for (int e = tid; e < 320; e += 256) keybuf[e] = keypart2[(size_t)p0*80 + e];
  if (tid < 64) {
    int pt = tid >> 4, qq = tid & 15;
    float4 cv = *((const float4*)(xp2 + (size_t)(p0 + pt)*64) + qq);
    *((float4*)&Cf[pt][qq*4]) = cv;
    float y2 = cv.x*cv.x + cv.y*cv.y + cv.z*cv.z + cv.w*cv.w;
    #pragma unroll
    for (int off = 8; off > 0; off >>= 1) y2 += __shfl_xor(y2, off);
    if (qq == 0) Yc[pt] = y2;
    ushort4 cb;
    cb.x = f2bf(cv.x); cb.y = f2bf(cv.y); cb.z = f2bf(cv.z); cb.w = f2bf(cv.w);
    // replicate center into the 20 MFMA rows of this point: rows a*16 + pt*4 + j
    #pragma unroll
    for (int a = 0; a < 5; a++)
      #pragma unroll
      for (int j2 = 0; j2 < 4; j2++)
        *((ushort4*)(Abf + (a*16 + pt*4 + j2)*136 + 64 + qq*4)) = cb;
  }
  __syncthreads();
  // Region B: parallel rank-based 4-way merge. 320 items; rank = own idx + 3 binary searches.
  for (int e = tid; e < 320; e += 256) {
    int pt = e / 80;
    int rem = e - pt*80;
    int c = rem / 20;
    int i = rem - c*20;
    const unsigned* LB = keybuf + pt*80;
    unsigned v = LB[c*20 + i];
    int rank = i;
    #pragma unroll
    for (int c2 = 0; c2 < 4; c2++) {
      if (c2 == c) continue;
      rank += cnt_gt(LB + c2*20, v);
    }
    if (rank < KNN) nbr[pt*20 + rank] = 1023 - (int)(v & 1023u);
  }
  __syncthreads();
  // Region C: gather + Mobius in one pass, all fp32 (center from Cf), single divide
  for (int e = tid; e < 80*16; e += 256) {
    int r = e >> 4, qq = e & 15;
    int q = (r >> 2) & 3;
    int L = 20*q + 4*(r >> 4) + (r & 3);
    float4 f = *((const float4*)(xp2 + (size_t)(b*N_ + nbr[L])*64) + qq);
    float4 cvf = *((const float4*)&Cf[q][qq*4]);
    float X2 = f.x*f.x + f.y*f.y + f.z*f.z + f.w*f.w;
    float XY = -(f.x*cvf.x + f.y*cvf.y + f.z*cvf.z + f.w*cvf.w);
    #pragma unroll
    for (int off = 8; off > 0; off >>= 1) {
      X2 += __shfl_xor(X2, off);
      XY += __shfl_xor(XY, off);
    }
    float Y2 = Yc[q];
    float den = fmaxf(1.0f + 0.02f*XY + 1e-4f*X2*Y2, 1e-15f);
    float inv = 1.0f / den;
    float s1 = (1.0f + 0.02f*XY + 0.01f*Y2) * inv;
    float s2 = (1.0f - 0.01f*X2) * inv;
    ushort4 mo;
    mo.x = f2bf(s1*f.x - s2*cvf.x);
    mo.y = f2bf(s1*f.y - s2*cvf.y);
    mo.z = f2bf(s1*f.z - s2*cvf.z);
    mo.w = f2bf(s1*f.w - s2*cvf.w);
    *((ushort4*)(Abf + r*136 + qq*4)) = mo;
  }
  __syncthreads();
  // Region D: MFMA + register epilogue (fp16 max/min stores, fp32 stats atomics)
  int wave = tid >> 6, lane = tid & 63;
  int quad = lane >> 4, lm = lane & 15;
  int colbase = wave*48;
  f32x4 acc[5][3];
  #pragma unroll
  for (int rt = 0; rt < 5; rt++)
    #pragma unroll
    for (int cj = 0; cj < 3; cj++) acc[rt][cj] = (f32x4){0.f, 0.f, 0.f, 0.f};
  #pragma unroll
  for (int kt = 0; kt < 4; kt++) {
    int k0 = kt*32 + quad*8;
    bf16x8 bf[3];
    #pragma unroll
    for (int cj = 0; cj < 3; cj++)
      bf[cj] = *((const bf16x8*)(w2h + (size_t)(colbase + cj*16 + lm)*128 + k0));
    bf16x8 af[5];
    #pragma unroll
    for (int rt = 0; rt < 5; rt++)
      af[rt] = *((const bf16x8*)(Abf + (rt*16 + lm)*136 + k0));
    #pragma unroll
    for (int rt = 0; rt < 5; rt++)
      #pragma unroll
      for (int cj = 0; cj < 3; cj++)
        acc[rt][cj] = __builtin_amdgcn_mfma_f32_16x16x32_bf16(af[rt], bf[cj], acc[rt][cj], 0, 0, 0);
  }
  #pragma unroll
  for (int cj = 0; cj < 3; cj++) {
    int o = colbase + cj*16 + lm;
    float s = 0.f, s2 = 0.f, mx = -__builtin_inff(), mn = __builtin_inff();
    #pragma unroll
    for (int rt = 0; rt < 5; rt++) {
      #pragma unroll
      for (int reg = 0; reg < 4; reg++) {
        float h = acc[rt][cj][reg];
        s += h; s2 += h*h;
        mx = fmaxf(mx, h); mn = fminf(mn, h);
      }
    }
    hmax2[(size_t)(p0 + quad)*192 + o] = f2h(mx);
    hmin2[(size_t)(p0 + quad)*192 + o] = f2h(mn);
    s  += __shfl_xor(s, 16);  s  += __shfl_xor(s, 32);
    s2 += __shfl_xor(s2, 16); s2 += __shfl_xor(s2, 32);
    if (lane < 16) {
      float* dst = stats2sh + ((size_t)(bi & 255)*192 + o)*2;
      atomicAdd(dst, s); atomicAdd(dst + 1, s2);
    }
  }
}

// ---------- 11) conv3 via bf16 MFMA: ch0-63 from x1h (already bf16), ch64-255 from fp16 hmax2/hmin2 ----------
__global__ void __launch_bounds__(256) k_conv3m(
   const unsigned short* __restrict__ x1h,
   const unsigned short* __restrict__ hmax2, const unsigned short* __restrict__ hmin2,
   const float* __restrict__ scale2, const float* __restrict__ shift2,
   const unsigned short* __restrict__ wt3h, float* __restrict__ stats3sh,
   unsigned* __restrict__ hmax3u, unsigned* __restrict__ hmin3u) {
  __shared__ short As[64*264];
  int tid = threadIdx.x;
  int mt = blockIdx.x >> 2, cb = blockIdx.x & 3;
  int rowbase = mt*64;
  int b = rowbase >> 10;
  int c4 = tid & 63;
  float4 sc, sh;
  if (c4 >= 16) {
    sc = *((const float4*)(scale2 + (c4*4 - 64)));
    sh = *((const float4*)(shift2 + (c4*4 - 64)));
  }
  #pragma unroll 4
  for (int i = 0; i < 16; i++) {
    int r = (tid >> 6) + i*4;
    int p = rowbase + r;
    if (c4 < 16) {
      // channels 0..63: x1h already holds f2bf(relu(BN1(h))) in (B,N,64) layout
      *((ushort4*)(As + r*264 + c4*4)) =
        *((const ushort4*)(x1h + (size_t)p*64 + c4*4));
    } else {
      ushort4 hx4 = *((const ushort4*)(hmax2 + (size_t)p*192 + (c4*4 - 64)));
      ushort4 hn4 = *((const ushort4*)(hmin2 + (size_t)p*192 + (c4*4 - 64)));
      ushort4 o4;
      o4.x = f2bf(fmaxf(fmaf(sc.x, (sc.x >= 0.f ? h2f(hx4.x) : h2f(hn4.x)), sh.x), 0.f));
      o4.y = f2bf(fmaxf(fmaf(sc.y, (sc.y >= 0.f ? h2f(hx4.y) : h2f(hn4.y)), sh.y), 0.f));
      o4.z = f2bf(fmaxf(fmaf(sc.z, (sc.z >= 0.f ? h2f(hx4.z) : h2f(hn4.z)), sh.z), 0.f));
      o4.w = f2bf(fmaxf(fmaf(sc.w, (sc.w >= 0.f ? h2f(hx4.w) : h2f(hn4.w)), sh.w), 0.f));
      *((ushort4*)(As + r*264 + c4*4)) = o4;
    }
  }
  __syncthreads();
  int wave = tid >> 6, lane = tid & 63;
  int quad = lane >> 4, lm = lane & 15;
  int colbase = cb*256 + wave*64;
  f32x4 acc[4][4];
  #pragma unroll
  for (int ri = 0; ri < 4; ri++)
    #pragma unroll
    for (int cj = 0; cj < 4; cj++) acc[ri][cj] = (f32x4){0.f, 0.f, 0.f, 0.f};
  for (int kt = 0; kt < 8; kt++) {
    int k0 = kt*32 + quad*8;
    bf16x8 bf[4];
    #pragma unroll
    for (int cj = 0; cj < 4; cj++)
      bf[cj] = *((const bf16x8*)(wt3h + (size_t)(colbase + cj*16 + lm)*256 + k0));
    bf16x8 af[4];
    #pragma unroll
    for (int ri = 0; ri < 4; ri++)
      af[ri] = *((const bf16x8*)(As + (ri*16 + lm)*264 + k0));
    #pragma unroll
    for (int ri = 0; ri < 4; ri++)
      #pragma unroll
      for (int cj = 0; cj < 4; cj++)
        acc[ri][cj] = __builtin_amdgcn_mfma_f32_16x16x32_bf16(af[ri], bf[cj], acc[ri][cj], 0, 0, 0);
  }
  #pragma unroll
  for (int cj = 0; cj < 4; cj++) {
    float s = 0.f, s2 = 0.f, mx = -__builtin_inff(), mn = __builtin_inff();
    #pragma unroll
    for (int ri = 0; ri < 4; ri++) {
      #pragma unroll
      for (int reg = 0; reg < 4; reg++) {
        float h = acc[ri][cj][reg];
        s += h; s2 += h*h; mx = fmaxf(mx, h); mn = fminf(mn, h);
      }
    }
    s  += __shfl_xor(s, 16);  s  += __shfl_xor(s, 32);
    s2 += __shfl_xor(s2, 16); s2 += __shfl_xor(s2, 32);
    mx = fmaxf(mx, __shfl_xor(mx, 16)); mx = fmaxf(mx, __shfl_xor(mx, 32));
    mn = fminf(mn, __shfl_xor(mn, 16)); mn = fminf(mn, __shfl_xor(mn, 32));
    if (lane < 16) {
      int col = colbase + cj*16 + lane;
      float* dst = stats3sh + ((size_t)(blockIdx.x & 63)*1024 + col)*2;
      atomicAdd(dst, s);
      atomicAdd(dst + 1, s2);
      atomicMax(hmax3u + b*1024 + col, fkey(mx));
      atomicMin(hmin3u + b*1024 + col, fkey(mn));
    }
  }
}

// ---------- 12) head, split for weight-read parallelism ----------
__device__ float blk_reduce(float v, float* red, int tid) {
  red[tid] = v; __syncthreads();
  for (int st = 128; st > 0; st >>= 1) {
    if (tid < st) red[tid] += red[tid + st];
    __syncthreads();
  }
  float r = red[0]; __syncthreads();
  return r;
}

__global__ void __launch_bounds__(256) k_head1(const unsigned* __restrict__ hmax3u,
    const unsigned* __restrict__ hmin3u,
    const float* __restrict__ scale3, const float* __restrict__ shift3,
    const float* __restrict__ fc1w, const float* __restrict__ fc1b,
    float* __restrict__ h1buf) {
  __shared__ __align__(16) float V[1024];
  int b = blockIdx.x >> 5, oc = blockIdx.x & 31;
  int tid = threadIdx.x;
  for (int o = tid; o < 1024; o += 256) {
    float a = scale3[o];
    unsigned u = (a >= 0.f) ? hmax3u[b*1024 + o] : hmin3u[b*1024 + o];
    V[o] = fmaxf(fmaf(a, fkeyinv(u), shift3[o]), 0.f);
  }
  __syncthreads();
  int ty = tid >> 4, tx = tid & 15;
  int o = oc*16 + ty;
  const float4* wr = (const float4*)(fc1w + (size_t)o*1024) + tx*16;
  const float4* vv = (const float4*)V + tx*16;
  float s = 0.f;
  #pragma unroll
  for (int i = 0; i < 16; i++) {
    float4 w = wr[i]; float4 v = vv[i];
    s = fmaf(w.x, v.x, s); s = fmaf(w.y, v.y, s);
    s = fmaf(w.z, v.z, s); s = fmaf(w.w, v.w, s);
  }
  s += __shfl_xor(s, 1); s += __shfl_xor(s, 2);
  s += __shfl_xor(s, 4); s += __shfl_xor(s, 8);
  if (tx == 0) h1buf[b*512 + o] = s + fc1b[o];
}

__global__ void __launch_bounds__(256) k_head2(const float* __restrict__ h1buf,
    const float* __restrict__ ln1g, const float* __restrict__ ln1b,
    const float* __restrict__ fc2w, const float* __restrict__ fc2b,
    float* __restrict__ h2buf) {
  __shared__ __align__(16) float H1[512];
  __shared__ float red[256];
  int b = blockIdx.x >> 3, oc = blockIdx.x & 7;
  int tid = threadIdx.x;
  float v0 = h1buf[b*512 + tid], v1 = h1buf[b*512 + 256 + tid];
  float s = blk_reduce(v0 + v1, red, tid);
  float s2 = blk_reduce(v0*v0 + v1*v1, red, tid);
  float m = s / 512.f;
  float var = s2 / 512.f - m*m;
  float inv = 1.0f / sqrtf(var + 1e-5f);
  H1[tid] = fmaxf((v0 - m)*inv*ln1g[tid] + ln1b[tid], 0.f);
  H1[256 + tid] = fmaxf((v1 - m)*inv*ln1g[256 + tid] + ln1b[256 + tid], 0.f);
  __syncthreads();
  int ty = tid >> 3, tx = tid & 7;
  int o = oc*32 + ty;
  const float4* wr = (const float4*)(fc2w + (size_t)o*512) + tx*16;
  const float4* vv = (const float4*)H1 + tx*16;
  float t = 0.f;
  #pragma unroll
  for (int i = 0; i < 16; i++) {
    float4 w = wr[i]; float4 v = vv[i];
    t = fmaf(w.x, v.x, t); t = fmaf(w.y, v.y, t);
    t = fmaf(w.z, v.z, t); t = fmaf(w.w, v.w, t);
  }
  t += __shfl_xor(t, 1); t += __shfl_xor(t, 2); t += __shfl_xor(t, 4);
  if (tx == 0) h2buf[b*256 + o] = t + fc2b[o];
}

__global__ void __launch_bounds__(256) k_head3(const float* __restrict__ h2buf,
    const float* __restrict__ ln2g, const float* __restrict__ ln2b,
    const float* __restrict__ outw, const float* __restrict__ outb,
    float* __restrict__ out) {
  __shared__ __align__(16) float H2[256];
  __shared__ float red[256];
  int b = blockIdx.x, tid = threadIdx.x;
  float h2v = h2buf[b*256 + tid];
  float ss = blk_reduce(h2v, red, tid);
  float ss2 = blk_reduce(h2v*h2v, red, tid);
  float m2 = ss / 256.f;
  float var2 = ss2 / 256.f - m2*m2;
  float inv2 = 1.0f / sqrtf(var2 + 1e-5f);
  H2[tid] = fmaxf((h2v - m2)*inv2*ln2g[tid] + ln2b[tid], 0.f);
  __syncthreads();
  if (tid < 40) {
    const float4* wr = (const float4*)(outw + (size_t)tid*256);
    float t = 0.f;
    for (int c4 = 0; c4 < 64; c4++) {
      float4 w = wr[c4]; float4 vv = ((const float4*)H2)[c4];
      t = fmaf(w.x, vv.x, t); t = fmaf(w.y, vv.y, t);
      t = fmaf(w.z, vv.z, t); t = fmaf(w.w, vv.w, t);
    }
    red[tid] = t + outb[tid];
  }
  __syncthreads();
  if (tid == 0) {
    float mx = -__builtin_inff();
    for (int i2 = 0; i2 < 40; i2++) mx = fmaxf(mx, red[i2]);
    float se = 0.f;
    for (int i2 = 0; i2 < 40; i2++) se += expf(red[i2] - mx);
    float lse = mx + logf(se);
    for (int i2 = 0; i2 < 40; i2++) out[b*40 + i2] = red[i2] - lse;
  }
}

extern "C" void kernel_launch(void* const* d_in, const int* in_sizes, int n_in,
                              void* d_out, int out_size, void* d_ws, size_t ws_size,
                              hipStream_t stream) {
  (void)in_sizes; (void)n_in; (void)out_size; (void)ws_size;
  const float* x    = (const float*)d_in[0];
  const float* w1   = (const float*)d_in[1];
  const float* bn1g = (const float*)d_in[2];
  const float* bn1b = (const float*)d_in[3];
  const float* w2   = (const float*)d_in[4];
  const float* bn2g = (const float*)d_in[5];
  const float* bn2b = (const float*)d_in[6];
  const float* w3   = (const float*)d_in[7];
  const float* bn3g = (const float*)d_in[8];
  const float* bn3b = (const float*)d_in[9];
  const float* fc1w = (const float*)d_in[10];
  const float* fc1b = (const float*)d_in[11];
  const float* ln1g = (const float*)d_in[12];
  const float* ln1b = (const float*)d_in[13];
  const float* fc2w = (const float*)d_in[14];
  const float* fc2b = (const float*)d_in[15];
  const float* ln2g = (const float*)d_in[16];
  const float* ln2b = (const float*)d_in[17];
  const float* outw = (const float*)d_in[18];
  const float* outb = (const float*)d_in[19];
  float* out = (float*)d_out;

  float* ws = (float*)d_ws;
  size_t off = 0;
  float* xp1   = ws + off; off += 49152;
  float* hmax1 = ws + off; off += 1048576;
  float* hmin1 = ws + off; off += 1048576;
  float* xp2   = ws + off; off += 1048576;
  float* hmax2f = ws + off; off += 3145728;  // holds keypartA (knn1 partials) then fp16 hmax2
  float* hmin2f = ws + off; off += 3145728;  // fp16 hmin2
  unsigned* keypart2 = (unsigned*)(ws + off); off += 1310720;  // knn2 partials, 80/pt
  unsigned short* w2h = (unsigned short*)(ws + off); off += 24576;
  unsigned short* wt3h = (unsigned short*)(ws + off); off += 131072;
  float* x1bf  = ws + off; off += 1048576;   // x1 bf16 hi (2MB) + lo (2MB), (B,N,64) layout
  float* xx1   = ws + off; off += 16384;
  float* h1buf = ws + off; off += 8192;
  float* h2buf = ws + off; off += 4096;
  float* scale1 = ws + off; off += 64;
  float* shift1 = ws + off; off += 64;
  float* scale2 = ws + off; off += 192;
  float* shift2 = ws + off; off += 192;
  float* scale3 = ws + off; off += 1024;
  float* shift3 = ws + off; off += 1024;
  float* stats1sh = ws + off;                         // fp32 stats
  float* stats2sh = stats1sh + 64*64*2;
  float* stats3sh = stats2sh + (size_t)256*192*2;
  unsigned* hmax3u = (unsigned*)(stats3sh + (size_t)64*1024*2);
  unsigned* hmin3u = hmax3u + 16384;
  unsigned* keypartA = (unsigned*)hmax2f;
  unsigned short* x1h = (unsigned short*)x1bf;
  unsigned short* x1l = x1h + 1048576;
  unsigned short* hmax2 = (unsigned short*)hmax2f;
  unsigned short* hmin2 = (unsigned short*)hmin2f;

  size_t zero_bytes = ((size_t)64*64*2 + (size_t)256*192*2 + (size_t)64*1024*2)*4 + (size_t)16384*4;
  hipMemsetAsync(stats1sh, 0, zero_bytes, stream);
  hipMemsetAsync(hmin3u, 0xFF, (size_t)16384*4, stream);

  k_prep_knn1<<<1536, 256, 0, stream>>>(x, xp1, w2, w3, w2h, wt3h, keypartA);
  k_conv1<<<1024, 256, 0, stream>>>(xp1, keypartA, w1, hmax1, hmin1, stats1sh);
  k_bn_reduce<<<64, 64, 0, stream>>>(stats1sh, 64, 64, 327680.0, bn1g, bn1b, scale1, shift1);
  k_bn1_apply<<<256, 256, 0, stream>>>(hmax1, hmin1, scale1, shift1, xp2, x1h, x1l, xx1);
  k_knn2g<<<1024, 256, 0, stream>>>(x1h, x1l, xx1, keypart2);
  k_conv2m<<<4096, 256, 0, stream>>>(xp2, keypart2, w2h, hmax2, hmin2, stats2sh);
  k_bn_reduce<<<192, 64, 0, stream>>>(stats2sh, 192, 256, 327680.0, bn2g, bn2b, scale2, shift2);
  k_conv3m<<<1024, 256, 0, stream>>>(x1h, hmax2, hmin2, scale2, shift2,
                                     wt3h, stats3sh, hmax3u, hmin3u);
  k_bn_reduce<<<1024, 64, 0, stream>>>(stats3sh, 1024, 64, 16384.0, bn3g, bn3b, scale3, shift3);
  k_head1<<<512, 256, 0, stream>>>(hmax3u, hmin3u, scale3, shift3, fc1w, fc1b, h1buf);
  k_head2<<<128, 256, 0, stream>>>(h1buf, ln1g, ln1b, fc2w, fc2b, h2buf);
  k_head3<<<16, 256, 0, stream>>>(h2buf, ln2g, ln2b, outw, outb, out);
}

// Round 10
// 329.380 us; speedup vs baseline: 1.0627x; 1.0427x over previous
//
#include <hip/hip_runtime.h>
#include <math.h>

#define B_ 16
#define N_ 1024
#define KNN 20
#define NPAIR (B_*N_)

typedef __attribute__((ext_vector_type(8))) short bf16x8;
typedef __attribute__((ext_vector_type(4))) float f32x4;

// ---------- helpers ----------
__device__ __forceinline__ unsigned fkey(float f) {
  unsigned u = __float_as_uint(f);
  return (u & 0x80000000u) ? ~u : (u | 0x80000000u);
}
__device__ __forceinline__ float fkeyinv(unsigned u) {
  unsigned b = (u & 0x80000000u) ? (u ^ 0x80000000u) : ~u;
  return __uint_as_float(b);
}
__device__ __forceinline__ unsigned short f2bf(float x) {  // RNE float->bf16
  unsigned u = __float_as_uint(x);
  unsigned r = (u + 0x7FFFu + ((u >> 16) & 1u)) >> 16;
  return (unsigned short)r;
}
__device__ __forceinline__ float bf2f(unsigned short u) {
  return __uint_as_float(((unsigned)u) << 16);
}
__device__ __forceinline__ unsigned short f2h(float x) {   // RNE float->fp16
  _Float16 h = (_Float16)x;
  return *(unsigned short*)&h;
}
__device__ __forceinline__ float h2f(unsigned short u) {
  _Float16 h = *(_Float16*)&u;
  return (float)h;
}
// packed knn key: top 22 bits of fkey(d) | (1023 - idx). u32 '>' == dist desc, idx asc.
__device__ __forceinline__ unsigned knnkey(float d, int idx) {
  return (fkey(d) & 0xFFFFFC00u) | (unsigned)(1023 - idx);
}

// Branchless sorted-insert (descending) of packed u32 key: 2 ops/stage.
__device__ __forceinline__ void topk_insert_u32(unsigned (&kl)[KNN], unsigned nk) {
  kl[KNN-1] = nk;
  #pragma unroll
  for (int i = KNN-1; i > 0; i--) {
    unsigned hi = max(kl[i-1], kl[i]);
    unsigned lo = min(kl[i-1], kl[i]);
    kl[i-1] = hi; kl[i] = lo;
  }
}

// count of elements strictly greater than v in sorted-desc list L of 20 (5-step bsearch)
__device__ __forceinline__ int cnt_gt(const unsigned* __restrict__ L, unsigned v) {
  int j = 0;
  #pragma unroll
  for (int s = 16; s; s >>= 1) {
    int nj = j + s;
    if (nj <= KNN && L[nj-1] > v) j = nj;
  }
  return j;
}

// ---------- 1) fused prep + knn1: blocks 0..511 = knn1 8-way split; 512..1535 = prep ----------
__global__ void __launch_bounds__(256) k_prep_knn1(const float* __restrict__ x,
        float* __restrict__ xp1, const float* __restrict__ w2, const float* __restrict__ w3,
        unsigned short* __restrict__ w2h, unsigned short* __restrict__ wt3h,
        unsigned* __restrict__ keypart) {
  __shared__ float P[N_*3];
  __shared__ float XX[N_];
  if (blockIdx.x >= 512) {
    int i = (blockIdx.x - 512) * 256 + threadIdx.x;
    if (i < NPAIR) {
      float a0 = x[i*3+0], a1 = x[i*3+1], a2 = x[i*3+2];
      float n = sqrtf(a0*a0 + a1*a1 + a2*a2);
      n = fmaxf(n, 1e-15f);
      float th = tanhf(0.1f * n);
      float sc = th / (0.1f * n);
      float ny = fmaxf(th * 10.0f, 1e-15f);
      float mxn = (1.0f - 4e-3f) / 0.1f;
      if (ny > mxn) sc *= mxn / ny;
      xp1[i*3+0] = sc*a0; xp1[i*3+1] = sc*a1; xp1[i*3+2] = sc*a2;
    }
    if (i < 192*128) w2h[i] = f2bf(w2[i]);
    wt3h[i] = f2bf(w3[i]);
    return;
  }
  int blk = blockIdx.x;
  int b = blk >> 5, rc = (blk >> 3) & 3, cc = blk & 7;
  const float* xb = x + b*N_*3;
  for (int e = threadIdx.x; e < N_*3; e += 256) P[e] = xb[e];
  __syncthreads();
  for (int j = threadIdx.x; j < N_; j += 256) {
    float q0 = P[j*3], q1 = P[j*3+1], q2 = P[j*3+2];
    XX[j] = q0*q0 + q1*q1 + q2*q2;
  }
  __syncthreads();
  int r = rc*256 + threadIdx.x;
  float q0 = P[r*3], q1 = P[r*3+1], q2 = P[r*3+2];
  float xxq = XX[r];
  unsigned kl[KNN];
  #pragma unroll
  for (int i = 0; i < KNN; i++) kl[i] = 0u;
  int cbase = cc*128;
  for (int jj = 0; jj < 128; jj++) {
    int j = cbase + jj;
    float dot = q0*P[j*3] + q1*P[j*3+1] + q2*P[j*3+2];
    float d = 2.0f*dot - xxq - XX[j];
    unsigned nk = knnkey(d, j);
    if (nk > kl[KNN-1]) topk_insert_u32(kl, nk);
  }
  int p = b*N_ + r;
  unsigned* pe = keypart + (size_t)p*160 + cc*20;
  #pragma unroll
  for (int i = 0; i < KNN; i++) pe[i] = kl[i];
}

// ---------- 3) conv1 fused v2: parallel pairwise merge tree (8->4->2->1), fp32 stats ----------
__global__ void __launch_bounds__(256) k_conv1(const float* __restrict__ xp1,
                        const unsigned* __restrict__ keypart,
                        const float* __restrict__ w1, float* __restrict__ hmax1,
                        float* __restrict__ hmin1, float* __restrict__ stats1sh) {
  __shared__ float F[4][KNN][6];
  __shared__ float red[4][64][2];
  __shared__ int idxs[16][KNN];
  __shared__ unsigned keybuf[2560];   // 16 pairs x 160 keys, 10 KB
  __shared__ unsigned out1[1280];     // level-1 merged: 16 pts x 4 lists x 20
  __shared__ unsigned out2[640];      // level-2 merged: 16 pts x 2 lists x 20
  int g = threadIdx.x >> 6, lane = threadIdx.x & 63;
  int tid = threadIdx.x;
  int pbase = blockIdx.x * 16;
  {
    const unsigned* src = keypart + (size_t)pbase*160;
    for (int e = tid; e < 2560; e += 256) keybuf[e] = src[e];
  }
  float w[6];
  #pragma unroll
  for (int c = 0; c < 6; c++) w[c] = w1[lane*6 + c];
  __syncthreads();
  // L1: merge (2m, 2m+1) -> out1[pt][m][.]  (2560 items, all parallel)
  for (int e = tid; e < 2560; e += 256) {
    int pt = e / 160, rem = e - pt*160;
    int m = rem / 40, i = rem - m*40;
    const unsigned* A = keybuf + pt*160 + (2*m)*20;
    const unsigned* Bl = A + 20;
    unsigned v; const unsigned* S; int own;
    if (i < 20) { v = A[i]; S = Bl; own = i; }
    else { v = Bl[i-20]; S = A; own = i-20; }
    int rank = own + cnt_gt(S, v);
    if (rank < KNN) out1[(pt*4 + m)*20 + rank] = v;
  }
  __syncthreads();
  // L2: merge (2m2, 2m2+1) of out1 -> out2[pt][m2][.]  (1280 items)
  for (int e = tid; e < 1280; e += 256) {
    int pt = e / 80, rem = e - pt*80;
    int m2 = rem / 40, i = rem - m2*40;
    const unsigned* A = out1 + (pt*4 + 2*m2)*20;
    const unsigned* Bl = A + 20;
    unsigned v; const unsigned* S; int own;
    if (i < 20) { v = A[i]; S = Bl; own = i; }
    else { v = Bl[i-20]; S = A; own = i-20; }
    int rank = own + cnt_gt(S, v);
    if (rank < KNN) out2[(pt*2 + m2)*20 + rank] = v;
  }
  __syncthreads();
  // L3: final merge -> idxs  (640 items)
  for (int e = tid; e < 640; e += 256) {
    int pt = e / 40, i = e - pt*40;
    const unsigned* A = out2 + pt*40;
    const unsigned* Bl = A + 20;
    unsigned v; const unsigned* S; int own;
    if (i < 20) { v = A[i]; S = Bl; own = i; }
    else { v = Bl[i-20]; S = A; own = i-20; }
    int rank = own + cnt_gt(S, v);
    if (rank < KNN) idxs[pt][rank] = 1023 - (int)(v & 1023u);
  }
  float sum = 0.f, sumsq = 0.f;
  __syncthreads();
  for (int it = 0; it < 4; ++it) {
    int p = pbase + it*4 + g;
    if (lane < KNN) {
      int nb = idxs[it*4 + g][lane];
      int bb = p >> 10;
      const float* xc = xp1 + p*3;
      const float* ft = xp1 + (bb*N_ + nb)*3;
      float x0 = ft[0], x1 = ft[1], x2v = ft[2];
      float c0 = xc[0], c1 = xc[1], c2 = xc[2];
      float X2 = x0*x0 + x1*x1 + x2v*x2v;
      float Y2 = c0*c0 + c1*c1 + c2*c2;
      float XY = -(x0*c0 + x1*c1 + x2v*c2);
      float den = fmaxf(1.0f + 0.02f*XY + 1e-4f*X2*Y2, 1e-15f);
      float s1 = (1.0f + 0.02f*XY + 0.01f*Y2) / den;
      float s2 = (1.0f - 0.01f*X2) / den;
      F[g][lane][0] = s1*x0 - s2*c0;
      F[g][lane][1] = s1*x1 - s2*c1;
      F[g][lane][2] = s1*x2v - s2*c2;
      F[g][lane][3] = c0; F[g][lane][4] = c1; F[g][lane][5] = c2;
    }
    __syncthreads();
    float mx = -__builtin_inff(), mn = __builtin_inff();
    for (int k = 0; k < KNN; k++) {
      float h = 0.f;
      #pragma unroll
      for (int c = 0; c < 6; c++) h = fmaf(w[c], F[g][k][c], h);
      mx = fmaxf(mx, h); mn = fminf(mn, h);
      sum += h; sumsq += h*h;
    }
    hmax1[(pbase + it*4 + g)*64 + lane] = mx;
    hmin1[(pbase + it*4 + g)*64 + lane] = mn;
    __syncthreads();
  }
  red[g][lane][0] = sum; red[g][lane][1] = sumsq;
  __syncthreads();
  if (g == 0) {
    float s  = red[0][lane][0] + red[1][lane][0] + red[2][lane][0] + red[3][lane][0];
    float s2 = red[0][lane][1] + red[1][lane][1] + red[2][lane][1] + red[3][lane][1];
    float* dst = stats1sh + ((size_t)(blockIdx.x & 63)*64 + lane)*2;
    atomicAdd(dst, s);
    atomicAdd(dst + 1, s2);
  }
}

// ---------- BN stat reduce v4 (fp32 slots, f64 cross-slot accumulation) ----------
__global__ void __launch_bounds__(64) k_bn_reduce(const float* __restrict__ sh, int nch, int nslots,
                            double cnt,
                            const float* __restrict__ g, const float* __restrict__ bb,
                            float* __restrict__ scale, float* __restrict__ shift) {
  int o = blockIdx.x, t = threadIdx.x;
  double s = 0.0, s2 = 0.0;
  for (int sl = t; sl < nslots; sl += 64) {
    s  += (double)sh[((size_t)sl*nch + o)*2];
    s2 += (double)sh[((size_t)sl*nch + o)*2 + 1];
  }
  #pragma unroll
  for (int off = 32; off > 0; off >>= 1) { s += __shfl_xor(s, off); s2 += __shfl_xor(s2, off); }
  if (t == 0) {
    double m = s / cnt;
    double v = s2 / cnt - m*m;
    float a = g[o] / sqrtf((float)v + 1e-5f);
    scale[o] = a;
    shift[o] = bb[o] - a * (float)m;
  }
}

// ---------- 5) BN1 apply + relu + e2p + bf16 hi/lo split for MFMA knn2 + |x1|^2 ----------
__global__ void __launch_bounds__(256) k_bn1_apply(const float* __restrict__ hmax1, const float* __restrict__ hmin1,
                            const float* __restrict__ scale1, const float* __restrict__ shift1,
                            float* __restrict__ xp2,
                            unsigned short* __restrict__ x1h, unsigned short* __restrict__ x1l,
                            float* __restrict__ xx1) {
  int b = blockIdx.x >> 4, nc = blockIdx.x & 15;
  int c = threadIdx.x & 63, sub = threadIdx.x >> 6;
  int n0 = nc*64 + sub*16;
  float a = scale1[c], t = shift1[c];
  #pragma unroll
  for (int i = 0; i < 16; i++) {
    int p = b*1024 + n0 + i;
    float h = (a >= 0.f) ? hmax1[(size_t)p*64 + c] : hmin1[(size_t)p*64 + c];
    float x1 = fmaxf(fmaf(a, h, t), 0.f);
    // split-bf16: x1 = hi + lo with both bf16; dot via 4-term MFMA is fp32-accurate to ~2^-17
    unsigned short hb = f2bf(x1);
    x1h[(size_t)p*64 + c] = hb;
    x1l[(size_t)p*64 + c] = f2bf(x1 - bf2f(hb));
    float n2 = x1*x1;
    #pragma unroll
    for (int off = 32; off > 0; off >>= 1) n2 += __shfl_xor(n2, off);
    if (c == 0) xx1[p] = n2;
    float n1 = fmaxf(sqrtf(n2), 1e-15f);
    float th = tanhf(0.1f * n1);
    float sc = th / (0.1f * n1);
    float ny = fmaxf(th * 10.0f, 1e-15f);
    float mxn = (1.0f - 4e-3f) / 0.1f;
    if (ny > mxn) sc *= mxn / ny;
    xp2[(size_t)p*64 + c] = sc * x1;
  }
}

// ---------- 6) knn2 v12: register scan + bitonic sort/merge top-k (no serial insert chain) ----------
// Scan: MFMA + 2-round shfl_xor butterfly transpose -> each lane holds its query's 16 cands in regs.
// Selection per stage: sort16 (bitonic asc, 80 CE) -> half-cleaner vs kl (16 max) -> bitonic
// merge-32 desc (80 CE). All static register indices, log-depth ILP, no guarded dependent chain.
// Same keys & total order as v11 -> identical neighbor sets. Tail: register-linear rank-merge.
__global__ void __launch_bounds__(256) k_knn2g(const unsigned short* __restrict__ x1h,
        const unsigned short* __restrict__ x1l,
        const float* __restrict__ xx1, unsigned* __restrict__ keypart2) {
  __shared__ unsigned LU[5376];                  // 4 lists x 64q x 21 (21 KB)
  __shared__ unsigned MU[2688];                  // 2 merged x 64q x 21 (10.5 KB)
  int tid = threadIdx.x;
  int bi = blockIdx.x;
  int blk = ((bi & 7) << 7) + (bi >> 3);     // XCD-affine swizzle (1024 = 8*128, bijective)
  int b = blk >> 6, qc = (blk >> 2) & 15, cc = blk & 3;
  int qbase = qc*64, ccbase = cc*256;
  int wave = tid >> 6, lane = tid & 63;
  int lm = lane & 15, kq = lane >> 4;
  const size_t base = (size_t)b * 65536;     // b*1024*64

  // Q fragments (hi/lo) held in registers for the whole kernel: 4 qtiles x 2 ksteps
  bf16x8 Qh[4][2], Ql[4][2];
  #pragma unroll
  for (int qt = 0; qt < 4; qt++) {
    size_t ro = base + (size_t)(qbase + qt*16 + lm)*64 + kq*8;
    #pragma unroll
    for (int ks = 0; ks < 2; ks++) {
      Qh[qt][ks] = *((const bf16x8*)(x1h + ro + ks*32));
      Ql[qt][ks] = *((const bf16x8*)(x1l + ro + ks*32));
    }
  }
  unsigned kl[KNN];
  #pragma unroll
  for (int i = 0; i < KNN; i++) kl[i] = 0u;

  for (int st = 0; st < 4; ++st) {
    int cb0 = ccbase + st*64;
    // A fragments: this wave's 16 candidates, hi/lo
    size_t co = base + (size_t)(cb0 + wave*16 + lm)*64 + kq*8;
    bf16x8 Ah[2], Al[2];
    #pragma unroll
    for (int ks = 0; ks < 2; ks++) {
      Ah[ks] = *((const bf16x8*)(x1h + co + ks*32));
      Al[ks] = *((const bf16x8*)(x1l + co + ks*32));
    }
    float4 xxc = *((const float4*)(xx1 + b*1024 + cb0 + wave*16 + kq*4));
    f32x4 acc[4];
    #pragma unroll
    for (int qt = 0; qt < 4; qt++) acc[qt] = (f32x4){0.f, 0.f, 0.f, 0.f};
    #pragma unroll
    for (int ks = 0; ks < 2; ks++) {
      #pragma unroll
      for (int qt = 0; qt < 4; qt++) {
        acc[qt] = __builtin_amdgcn_mfma_f32_16x16x32_bf16(Ah[ks], Qh[qt][ks], acc[qt], 0, 0, 0);
        acc[qt] = __builtin_amdgcn_mfma_f32_16x16x32_bf16(Ah[ks], Ql[qt][ks], acc[qt], 0, 0, 0);
        acc[qt] = __builtin_amdgcn_mfma_f32_16x16x32_bf16(Al[ks], Qh[qt][ks], acc[qt], 0, 0, 0);
        acc[qt] = __builtin_amdgcn_mfma_f32_16x16x32_bf16(Al[ks], Ql[qt][ks], acc[qt], 0, 0, 0);
      }
    }
    // dist adjust while layout is [qt][cand r of own kq group]: xxcv[r] matches cand kq*4+r
    // (-xxq omitted: constant per query row, rank-invariant)
    f32x4 xxv = (f32x4){xxc.x, xxc.y, xxc.z, xxc.w};
    #pragma unroll
    for (int qt = 0; qt < 4; qt++) acc[qt] = acc[qt]*2.0f - xxv;
    // 4x4 cross-lane block transpose within {lm, lm+16, lm+32, lm+48}:
    // after: acc[qt][r] = D[lane][qt*4+r]
    {
      f32x4 s0, s1, r0, r1;
      bool h1 = (kq & 1) != 0;
      if (h1) { s0 = acc[0]; s1 = acc[2]; } else { s0 = acc[1]; s1 = acc[3]; }
      #pragma unroll
      for (int e = 0; e < 4; e++) { r0[e] = __shfl_xor(s0[e], 16); r1[e] = __shfl_xor(s1[e], 16); }
      if (h1) { acc[0] = r0; acc[2] = r1; } else { acc[1] = r0; acc[3] = r1; }
      bool h2 = (kq & 2) != 0;
      if (h2) { s0 = acc[0]; s1 = acc[1]; } else { s0 = acc[2]; s1 = acc[3]; }
      #pragma unroll
      for (int e = 0; e < 4; e++) { r0[e] = __shfl_xor(s0[e], 32); r1[e] = __shfl_xor(s1[e], 32); }
      if (h2) { acc[0] = r0; acc[1] = r1; } else { acc[2] = r0; acc[3] = r1; }
    }
    // keys for this stage's 16 candidates (unconditional)
    unsigned bb[16];
    #pragma unroll
    for (int c = 0; c < 16; c++)
      bb[c] = knnkey(acc[c >> 2][c & 3], cb0 + wave*16 + c);
    // bitonic sort16 ASCENDING (static network, 80 CEs)
    #pragma unroll
    for (int k = 2; k <= 16; k <<= 1) {
      #pragma unroll
      for (int j = k >> 1; j > 0; j >>= 1) {
        #pragma unroll
        for (int i = 0; i < 16; i++) {
          int l = i ^ j;
          if (l > i) {
            unsigned x = bb[i], y = bb[l];
            unsigned mn = min(x, y), mx = max(x, y);
            bool up = ((i & k) == 0);
            bb[i] = up ? mn : mx;
            bb[l] = up ? mx : mn;
          }
        }
      }
    }
    // half-cleaner: s = [kl(desc,20)+12 zeros ++ 16 zeros+bb(asc)] is bitonic;
    // t[i] = max(s[i], s[i+32]) = top-32 multiset, bitonic.
    unsigned t[32];
    #pragma unroll
    for (int i = 0; i < 16; i++) t[i] = kl[i];
    #pragma unroll
    for (int i = 16; i < 32; i++) {
      unsigned a = (i < KNN) ? kl[i] : 0u;
      t[i] = max(a, bb[i - 16]);
    }
    // bitonic merge-32 DESCENDING (max to lower index): strides 16..1, 80 CEs
    #pragma unroll
    for (int j = 16; j > 0; j >>= 1) {
      #pragma unroll
      for (int i = 0; i < 32; i++) {
        int l = i ^ j;
        if (l > i) {
          unsigned x = t[i], y = t[l];
          t[i] = max(x, y); t[l] = min(x, y);
        }
      }
    }
    #pragma unroll
    for (int i = 0; i < KNN; i++) kl[i] = t[i];
  }
  // publish per-wave lists
  #pragma unroll
  for (int i = 0; i < KNN; i++) LU[wave*1344 + lane*21 + i] = kl[i];
  __syncthreads();
  // merge L1: (L0,L1)->M0, (L2,L3)->M1.  256 units = (pair, side, q); register-linear rank.
  {
    int pair = tid >> 7, side = (tid >> 6) & 1, q = tid & 63;
    const unsigned* own = LU + (pair*2 + side)*1344 + q*21;
    const unsigned* oth = LU + (pair*2 + 1 - side)*1344 + q*21;
    unsigned ow[KNN], ot[KNN];
    #pragma unroll
    for (int i = 0; i < KNN; i++) { ow[i] = own[i]; ot[i] = oth[i]; }
    unsigned* dst = MU + pair*1344 + q*21;
    #pragma unroll
    for (int i = 0; i < KNN; i++) {
      int r = i;
      #pragma unroll
      for (int j = 0; j < KNN; j++) r += (ot[j] > ow[i]) ? 1 : 0;
      if (r < KNN) dst[r] = ow[i];
    }
  }
  __syncthreads();
  // merge L2: (M0,M1) -> keypart2.  128 units = (side, q); register-linear rank.
  if (tid < 128) {
    int side = tid >> 6, q = tid & 63;
    const unsigned* own = MU + side*1344 + q*21;
    const unsigned* oth = MU + (1 - side)*1344 + q*21;
    unsigned ow[KNN], ot[KNN];
    #pragma unroll
    for (int i = 0; i < KNN; i++) { ow[i] = own[i]; ot[i] = oth[i]; }
    unsigned* pe = keypart2 + (size_t)(b*N_ + qbase + q)*80 + cc*20;
    #pragma unroll
    for (int i = 0; i < KNN; i++) {
      int r = i;
      #pragma unroll
      for (int j = 0; j < KNN; j++) r += (ot[j] > ow[i]) ? 1 : 0;
      if (r < KNN) pe[r] = ow[i];
    }
  }
}

// ---------- 9) conv2 via bf16 MFMA v11: rank-merge + fp32 center + fp16 hmax/hmin + fp32 stats ----------
__global__ void __launch_bounds__(256) k_conv2m(const float* __restrict__ xp2,
    const unsigned* __restrict__ keypart2, const unsigned short* __restrict__ w2h,
    unsigned short* __restrict__ hmax2, unsigned short* __restrict__ hmin2,
    float* __restrict__ stats2sh) {
  __shared__ __align__(16) short Abf[80*136];
  __shared__ __align__(16) float Cf[4][64];      // fp32 centers for Mobius math
  __shared__ float Yc[4];
  __shared__ int nbr[80];                        // logical order [pt*20 + k]
  __shared__ unsigned keybuf[320];               // 4 pairs x 80 keys
  int tid = threadIdx.x;
  int bi = blockIdx.x;
  int g512 = ((bi & 7) << 9) + (bi >> 3);
  int p0 = g512 * 4;
  int b = p0 >> 10;
  // Region A: stage merge keys (all threads) + center rows/Y2 (first wave) concurrently
  for (int e = tid; e < 320; e += 256) keybuf[e] = keypart2[(size_t)p0*80 + e];
  if (tid < 64) {
    int pt = tid >> 4, qq = tid & 15;
    float4 cv = *((const float4*)(xp2 + (size_t)(p0 + pt)*64) + qq);
    *((float4*)&Cf[pt][qq*4]) = cv;
    float y2 = cv.x*cv.x + cv.y*cv.y + cv.z*cv.z + cv.w*cv.w;
    #pragma unroll
    for (int off = 8; off > 0; off >>= 1) y2 += __shfl_xor(y2, off);
    if (qq == 0) Yc[pt] = y2;
    ushort4 cb;
    cb.x = f2bf(cv.x); cb.y = f2bf(cv.y); cb.z = f2bf(cv.z); cb.w = f2bf(cv.w);
    // replicate center into the 20 MFMA rows of this point: rows a*16 + pt*4 + j
    #pragma unroll
    for (int a = 0; a < 5; a++)
      #pragma unroll
      for (int j2 = 0; j2 < 4; j2++)
        *((ushort4*)(Abf + (a*16 + pt*4 + j2)*136 + 64 + qq*4)) = cb;
  }
  __syncthreads();
  // Region B: parallel rank-based 4-way merge. 320 items; rank = own idx + 3 binary searches.
  for (int e = tid; e < 320; e += 256) {
    int pt = e / 80;
    int rem = e - pt*80;
    int c = rem / 20;
    int i = rem - c*20;
    const unsigned* LB = keybuf + pt*80;
    unsigned v = LB[c*20 + i];
    int rank = i;
    #pragma unroll
    for (int c2 = 0; c2 < 4; c2++) {
      if (c2 == c) continue;
      rank += cnt_gt(LB + c2*20, v);
    }
    if (rank < KNN) nbr[pt*20 + rank] = 1023 - (int)(v & 1023u);
  }
  __syncthreads();
  // Region C: gather + Mobius in one pass, all fp32 (center from Cf), single divide
  for (int e = tid; e < 80*16; e += 256) {
    int r = e >> 4, qq = e & 15;
    int q = (r >> 2) & 3;
    int L = 20*q + 4*(r >> 4) + (r & 3);
    float4 f = *((const float4*)(xp2 + (size_t)(b*N_ + nbr[L])*64) + qq);
    float4 cvf = *((const float4*)&Cf[q][qq*4]);
    float X2 = f.x*f.x + f.y*f.y + f.z*f.z + f.w*f.w;
    float XY = -(f.x*cvf.x + f.y*cvf.y + f.z*cvf.z + f.w*cvf.w);
    #pragma unroll
    for (int off = 8; off > 0; off >>= 1) {
      X2 += __shfl_xor(X2, off);
      XY += __shfl_xor(XY, off);
    }
    float Y2 = Yc[q];
    float den = fmaxf(1.0f + 0.02f*XY + 1e-4f*X2*Y2, 1e-15f);
    float inv = 1.0f / den;
    float s1 = (1.0f + 0.02f*XY + 0.01f*Y2) * inv;
    float s2 = (1.0f - 0.01f*X2) * inv;
    ushort4 mo;
    mo.x = f2bf(s1*f.x - s2*cvf.x);
    mo.y = f2bf(s1*f.y - s2*cvf.y);
    mo.z = f2bf(s1*f.z - s2*cvf.z);
    mo.w = f2bf(s1*f.w - s2*cvf.w);
    *((ushort4*)(Abf + r*136 + qq*4)) = mo;
  }
  __syncthreads();
  // Region D: MFMA + register epilogue (fp16 max/min stores, fp32 stats atomics)
  int wave = tid >> 6, lane = tid & 63;
  int quad = lane >> 4, lm = lane & 15;
  int colbase = wave*48;
  f32x4 acc[5][3];
  #pragma unroll
  for (int rt = 0; rt < 5; rt++)
    #pragma unroll
    for (int cj = 0; cj < 3; cj++) acc[rt][cj] = (f32x4){0.f, 0.f, 0.f, 0.f};
  #pragma unroll
  for (int kt = 0; kt < 4; kt++) {
    int k0 = kt*32 + quad*8;
    bf16x8 bf[3];
    #pragma unroll
    for (int cj = 0; cj < 3; cj++)
      bf[cj] = *((const bf16x8*)(w2h + (size_t)(colbase + cj*16 + lm)*128 + k0));
    bf16x8 af[5];
    #pragma unroll
    for (int rt = 0; rt < 5; rt++)
      af[rt] = *((const bf16x8*)(Abf + (rt*16 + lm)*136 + k0));
    #pragma unroll
    for (int rt = 0; rt < 5; rt++)
      #pragma unroll
      for (int cj = 0; cj < 3; cj++)
        acc[rt][cj] = __builtin_amdgcn_mfma_f32_16x16x32_bf16(af[rt], bf[cj], acc[rt][cj], 0, 0, 0);
  }
  #pragma unroll
  for (int cj = 0; cj < 3; cj++) {
    int o = colbase + cj*16 + lm;
    float s = 0.f, s2 = 0.f, mx = -__builtin_inff(), mn = __builtin_inff();
    #pragma unroll
    for (int rt = 0; rt < 5; rt++) {
      #pragma unroll
      for (int reg = 0; reg < 4; reg++) {
        float h = acc[rt][cj][reg];
        s += h; s2 += h*h;
        mx = fmaxf(mx, h); mn = fminf(mn, h);
      }
    }
    hmax2[(size_t)(p0 + quad)*192 + o] = f2h(mx);
    hmin2[(size_t)(p0 + quad)*192 + o] = f2h(mn);
    s  += __shfl_xor(s, 16);  s  += __shfl_xor(s, 32);
    s2 += __shfl_xor(s2, 16); s2 += __shfl_xor(s2, 32);
    if (lane < 16) {
      float* dst = stats2sh + ((size_t)(bi & 255)*192 + o)*2;
      atomicAdd(dst, s); atomicAdd(dst + 1, s2);
    }
  }
}

// ---------- 11) conv3 via bf16 MFMA: ch0-63 from x1h (already bf16), ch64-255 from fp16 hmax2/hmin2 ----------
__global__ void __launch_bounds__(256) k_conv3m(
   const unsigned short* __restrict__ x1h,
   const unsigned short* __restrict__ hmax2, const unsigned short* __restrict__ hmin2,
   const float* __restrict__ scale2, const float* __restrict__ shift2,
   const unsigned short* __restrict__ wt3h, float* __restrict__ stats3sh,
   unsigned* __restrict__ hmax3u, unsigned* __restrict__ hmin3u) {
  __shared__ short As[64*264];
  int tid = threadIdx.x;
  int mt = blockIdx.x >> 2, cb = blockIdx.x & 3;
  int rowbase = mt*64;
  int b = rowbase >> 10;
  int c4 = tid & 63;
  float4 sc, sh;
  if (c4 >= 16) {
    sc = *((const float4*)(scale2 + (c4*4 - 64)));
    sh = *((const float4*)(shift2 + (c4*4 - 64)));
  }
  #pragma unroll 4
  for (int i = 0; i < 16; i++) {
    int r = (tid >> 6) + i*4;
    int p = rowbase + r;
    if (c4 < 16) {
      // channels 0..63: x1h already holds f2bf(relu(BN1(h))) in (B,N,64) layout
      *((ushort4*)(As + r*264 + c4*4)) =
        *((const ushort4*)(x1h + (size_t)p*64 + c4*4));
    } else {
      ushort4 hx4 = *((const ushort4*)(hmax2 + (size_t)p*192 + (c4*4 - 64)));
      ushort4 hn4 = *((const ushort4*)(hmin2 + (size_t)p*192 + (c4*4 - 64)));
      ushort4 o4;
      o4.x = f2bf(fmaxf(fmaf(sc.x, (sc.x >= 0.f ? h2f(hx4.x) : h2f(hn4.x)), sh.x), 0.f));
      o4.y = f2bf(fmaxf(fmaf(sc.y, (sc.y >= 0.f ? h2f(hx4.y) : h2f(hn4.y)), sh.y), 0.f));
      o4.z = f2bf(fmaxf(fmaf(sc.z, (sc.z >= 0.f ? h2f(hx4.z) : h2f(hn4.z)), sh.z), 0.f));
      o4.w = f2bf(fmaxf(fmaf(sc.w, (sc.w >= 0.f ? h2f(hx4.w) : h2f(hn4.w)), sh.w), 0.f));
      *((ushort4*)(As + r*264 + c4*4)) = o4;
    }
  }
  __syncthreads();
  int wave = tid >> 6, lane = tid & 63;
  int quad = lane >> 4, lm = lane & 15;
  int colbase = cb*256 + wave*64;
  f32x4 acc[4][4];
  #pragma unroll
  for (int ri = 0; ri < 4; ri++)
    #pragma unroll
    for (int cj = 0; cj < 4; cj++) acc[ri][cj] = (f32x4){0.f, 0.f, 0.f, 0.f};
  for (int kt = 0; kt < 8; kt++) {
    int k0 = kt*32 + quad*8;
    bf16x8 bf[4];
    #pragma unroll
    for (int cj = 0; cj < 4; cj++)
      bf[cj] = *((const bf16x8*)(wt3h + (size_t)(colbase + cj*16 + lm)*256 + k0));
    bf16x8 af[4];
    #pragma unroll
    for (int ri = 0; ri < 4; ri++)
      af[ri] = *((const bf16x8*)(As + (ri*16 + lm)*264 + k0));
    #pragma unroll
    for (int ri = 0; ri < 4; ri++)
      #pragma unroll
      for (int cj = 0; cj < 4; cj++)
        acc[ri][cj] = __builtin_amdgcn_mfma_f32_16x16x32_bf16(af[ri], bf[cj], acc[ri][cj], 0, 0, 0);
  }
  #pragma unroll
  for (int cj = 0; cj < 4; cj++) {
    float s = 0.f, s2 = 0.f, mx = -__builtin_inff(), mn = __builtin_inff();
    #pragma unroll
    for (int ri = 0; ri < 4; ri++) {
      #pragma unroll
      for (int reg = 0; reg < 4; reg++) {
        float h = acc[ri][cj][reg];
        s += h; s2 += h*h; mx = fmaxf(mx, h); mn = fminf(mn, h);
      }
    }
    s  += __shfl_xor(s, 16);  s  += __shfl_xor(s, 32);
    s2 += __shfl_xor(s2, 16); s2 += __shfl_xor(s2, 32);
    mx = fmaxf(mx, __shfl_xor(mx, 16)); mx = fmaxf(mx, __shfl_xor(mx, 32));
    mn = fminf(mn, __shfl_xor(mn, 16)); mn = fminf(mn, __shfl_xor(mn, 32));
    if (lane < 16) {
      int col = colbase + cj*16 + lane;
      float* dst = stats3sh + ((size_t)(blockIdx.x & 63)*1024 + col)*2;
      atomicAdd(dst, s);
      atomicAdd(dst + 1, s2);
      atomicMax(hmax3u + b*1024 + col, fkey(mx));
      atomicMin(hmin3u + b*1024 + col, fkey(mn));
    }
  }
}

// ---------- 12) head, split for weight-read parallelism ----------
__device__ float blk_reduce(float v, float* red, int tid) {
  red[tid] = v; __syncthreads();
  for (int st = 128; st > 0; st >>= 1) {
    if (tid < st) red[tid] += red[tid + st];
    __syncthreads();
  }
  float r = red[0]; __syncthreads();
  return r;
}

__global__ void __launch_bounds__(256) k_head1(const unsigned* __restrict__ hmax3u,
    const unsigned* __restrict__ hmin3u,
    const float* __restrict__ scale3, const float* __restrict__ shift3,
    const float* __restrict__ fc1w, const float* __restrict__ fc1b,
    float* __restrict__ h1buf) {
  __shared__ __align__(16) float V[1024];
  int b = blockIdx.x >> 5, oc = blockIdx.x & 31;
  int tid = threadIdx.x;
  for (int o = tid; o < 1024; o += 256) {
    float a = scale3[o];
    unsigned u = (a >= 0.f) ? hmax3u[b*1024 + o] : hmin3u[b*1024 + o];
    V[o] = fmaxf(fmaf(a, fkeyinv(u), shift3[o]), 0.f);
  }
  __syncthreads();
  int ty = tid >> 4, tx = tid & 15;
  int o = oc*16 + ty;
  const float4* wr = (const float4*)(fc1w + (size_t)o*1024) + tx*16;
  const float4* vv = (const float4*)V + tx*16;
  float s = 0.f;
  #pragma unroll
  for (int i = 0; i < 16; i++) {
    float4 w = wr[i]; float4 v = vv[i];
    s = fmaf(w.x, v.x, s); s = fmaf(w.y, v.y, s);
    s = fmaf(w.z, v.z, s); s = fmaf(w.w, v.w, s);
  }
  s += __shfl_xor(s, 1); s += __shfl_xor(s, 2);
  s += __shfl_xor(s, 4); s += __shfl_xor(s, 8);
  if (tx == 0) h1buf[b*512 + o] = s + fc1b[o];
}

__global__ void __launch_bounds__(256) k_head2(const float* __restrict__ h1buf,
    const float* __restrict__ ln1g, const float* __restrict__ ln1b,
    const float* __restrict__ fc2w, const float* __restrict__ fc2b,
    float* __restrict__ h2buf) {
  __shared__ __align__(16) float H1[512];
  __shared__ float red[256];
  int b = blockIdx.x >> 3, oc = blockIdx.x & 7;
  int tid = threadIdx.x;
  float v0 = h1buf[b*512 + tid], v1 = h1buf[b*512 + 256 + tid];
  float s = blk_reduce(v0 + v1, red, tid);
  float s2 = blk_reduce(v0*v0 + v1*v1, red, tid);
  float m = s / 512.f;
  float var = s2 / 512.f - m*m;
  float inv = 1.0f / sqrtf(var + 1e-5f);
  H1[tid] = fmaxf((v0 - m)*inv*ln1g[tid] + ln1b[tid], 0.f);
  H1[256 + tid] = fmaxf((v1 - m)*inv*ln1g[256 + tid] + ln1b[256 + tid], 0.f);
  __syncthreads();
  int ty = tid >> 3, tx = tid & 7;
  int o = oc*32 + ty;
  const float4* wr = (const float4*)(fc2w + (size_t)o*512) + tx*16;
  const float4* vv = (const float4*)H1 + tx*16;
  float t = 0.f;
  #pragma unroll
  for (int i = 0; i < 16; i++) {
    float4 w = wr[i]; float4 v = vv[i];
    t = fmaf(w.x, v.x, t); t = fmaf(w.y, v.y, t);
    t = fmaf(w.z, v.z, t); t = fmaf(w.w, v.w, t);
  }
  t += __shfl_xor(t, 1); t += __shfl_xor(t, 2); t += __shfl_xor(t, 4);
  if (tx == 0) h2buf[b*256 + o] = t + fc2b[o];
}

__global__ void __launch_bounds__(256) k_head3(const float* __restrict__ h2buf,
    const float* __restrict__ ln2g, const float* __restrict__ ln2b,
    const float* __restrict__ outw, const float* __restrict__ outb,
    float* __restrict__ out) {
  __shared__ __align__(16) float H2[256];
  __shared__ float red[256];
  int b = blockIdx.x, tid = threadIdx.x;
  float h2v = h2buf[b*256 + tid];
  float ss = blk_reduce(h2v, red, tid);
  float ss2 = blk_reduce(h2v*h2v, red, tid);
  float m2 = ss / 256.f;
  float var2 = ss2 / 256.f - m2*m2;
  float inv2 = 1.0f / sqrtf(var2 + 1e-5f);
  H2[tid] = fmaxf((h2v - m2)*inv2*ln2g[tid] + ln2b[tid], 0.f);
  __syncthreads();
  if (tid < 40) {
    const float4* wr = (const float4*)(outw + (size_t)tid*256);
    float t = 0.f;
    for (int c4 = 0; c4 < 64; c4++) {
      float4 w = wr[c4]; float4 vv = ((const float4*)H2)[c4];
      t = fmaf(w.x, vv.x, t); t = fmaf(w.y, vv.y, t);
      t = fmaf(w.z, vv.z, t); t = fmaf(w.w, vv.w, t);
    }
    red[tid] = t + outb[tid];
  }
  __syncthreads();
  if (tid == 0) {
    float mx = -__builtin_inff();
    for (int i2 = 0; i2 < 40; i2++) mx = fmaxf(mx, red[i2]);
    float se = 0.f;
    for (int i2 = 0; i2 < 40; i2++) se += expf(red[i2] - mx);
    float lse = mx + logf(se);
    for (int i2 = 0; i2 < 40; i2++) out[b*40 + i2] = red[i2] - lse;
  }
}

extern "C" void kernel_launch(void* const* d_in, const int* in_sizes, int n_in,
                              void* d_out, int out_size, void* d_ws, size_t ws_size,
                              hipStream_t stream) {
  (void)in_sizes; (void)n_in; (void)out_size; (void)ws_size;
  const float* x    = (const float*)d_in[0];
  const float* w1   = (const float*)d_in[1];
  const float* bn1g = (const float*)d_in[2];
  const float* bn1b = (const float*)d_in[3];
  const float* w2   = (const float*)d_in[4];
  const float* bn2g = (const float*)d_in[5];
  const float* bn2b = (const float*)d_in[6];
  const float* w3   = (const float*)d_in[7];
  const float* bn3g = (const float*)d_in[8];
  const float* bn3b = (const float*)d_in[9];
  const float* fc1w = (const float*)d_in[10];
  const float* fc1b = (const float*)d_in[11];
  const float* ln1g = (const float*)d_in[12];
  const float* ln1b = (const float*)d_in[13];
  const float* fc2w = (const float*)d_in[14];
  const float* fc2b = (const float*)d_in[15];
  const float* ln2g = (const float*)d_in[16];
  const float* ln2b = (const float*)d_in[17];
  const float* outw = (const float*)d_in[18];
  const float* outb = (const float*)d_in[19];
  float* out = (float*)d_out;

  float* ws = (float*)d_ws;
  size_t off = 0;
  float* xp1   = ws + off; off += 49152;
  float* hmax1 = ws + off; off += 1048576;
  float* hmin1 = ws + off; off += 1048576;
  float* xp2   = ws + off; off += 1048576;
  float* hmax2f = ws + off; off += 3145728;  // holds keypartA (knn1 partials) then fp16 hmax2
  float* hmin2f = ws + off; off += 3145728;  // fp16 hmin2
  unsigned* keypart2 = (unsigned*)(ws + off); off += 1310720;  // knn2 partials, 80/pt
  unsigned short* w2h = (unsigned short*)(ws + off); off += 24576;
  unsigned short* wt3h = (unsigned short*)(ws + off); off += 131072;
  float* x1bf  = ws + off; off += 1048576;   // x1 bf16 hi (2MB) + lo (2MB), (B,N,64) layout
  float* xx1   = ws + off; off += 16384;
  float* h1buf = ws + off; off += 8192;
  float* h2buf = ws + off; off += 4096;
  float* scale1 = ws + off; off += 64;
  float* shift1 = ws + off; off += 64;
  float* scale2 = ws + off; off += 192;
  float* shift2 = ws + off; off += 192;
  float* scale3 = ws + off; off += 1024;
  float* shift3 = ws + off; off += 1024;
  float* stats1sh = ws + off;                         // fp32 stats
  float* stats2sh = stats1sh + 64*64*2;
  float* stats3sh = stats2sh + (size_t)256*192*2;
  unsigned* hmax3u = (unsigned*)(stats3sh + (size_t)64*1024*2);
  unsigned* hmin3u = hmax3u + 16384;
  unsigned* keypartA = (unsigned*)hmax2f;
  unsigned short* x1h = (unsigned short*)x1bf;
  unsigned short* x1l = x1h + 1048576;
  unsigned short* hmax2 = (unsigned short*)hmax2f;
  unsigned short* hmin2 = (unsigned short*)hmin2f;

  size_t zero_bytes = ((size_t)64*64*2 + (size_t)256*192*2 + (size_t)64*1024*2)*4 + (size_t)16384*4;
  hipMemsetAsync(stats1sh, 0, zero_bytes, stream);
  hipMemsetAsync(hmin3u, 0xFF, (size_t)16384*4, stream);

  k_prep_knn1<<<1536, 256, 0, stream>>>(x, xp1, w2, w3, w2h, wt3h, keypartA);
  k_conv1<<<1024, 256, 0, stream>>>(xp1, keypartA, w1, hmax1, hmin1, stats1sh);
  k_bn_reduce<<<64, 64, 0, stream>>>(stats1sh, 64, 64, 327680.0, bn1g, bn1b, scale1, shift1);
  k_bn1_apply<<<256, 256, 0, stream>>>(hmax1, hmin1, scale1, shift1, xp2, x1h, x1l, xx1);
  k_knn2g<<<1024, 256, 0, stream>>>(x1h, x1l, xx1, keypart2);
  k_conv2m<<<4096, 256, 0, stream>>>(xp2, keypart2, w2h, hmax2, hmin2, stats2sh);
  k_bn_reduce<<<192, 64, 0, stream>>>(stats2sh, 192, 256, 327680.0, bn2g, bn2b, scale2, shift2);
  k_conv3m<<<1024, 256, 0, stream>>>(x1h, hmax2, hmin2, scale2, shift2,
                                     wt3h, stats3sh, hmax3u, hmin3u);
  k_bn_reduce<<<1024, 64, 0, stream>>>(stats3sh, 1024, 64, 16384.0, bn3g, bn3b, scale3, shift3);
  k_head1<<<512, 256, 0, stream>>>(hmax3u, hmin3u, scale3, shift3, fc1w, fc1b, h1buf);
  k_head2<<<128, 256, 0, stream>>>(h1buf, ln1g, ln1b, fc2w, fc2b, h2buf);
  k_head3<<<16, 256, 0, stream>>>(h2buf, ln2g, ln2b, outw, outb, out);
}

// Round 11
// 306.285 us; speedup vs baseline: 1.1428x; 1.0754x over previous
//
#include <hip/hip_runtime.h>
#include <math.h>

#define B_ 16
#define N_ 1024
#define KNN 20
#define NPAIR (B_*N_)

typedef __attribute__((ext_vector_type(8))) short bf16x8;
typedef __attribute__((ext_vector_type(4))) float f32x4;

// ---------- helpers ----------
__device__ __forceinline__ unsigned fkey(float f) {
  unsigned u = __float_as_uint(f);
  return (u & 0x80000000u) ? ~u : (u | 0x80000000u);
}
__device__ __forceinline__ float fkeyinv(unsigned u) {
  unsigned b = (u & 0x80000000u) ? (u ^ 0x80000000u) : ~u;
  return __uint_as_float(b);
}
__device__ __forceinline__ unsigned short f2bf(float x) {  // RNE float->bf16
  unsigned u = __float_as_uint(x);
  unsigned r = (u + 0x7FFFu + ((u >> 16) & 1u)) >> 16;
  return (unsigned short)r;
}
__device__ __forceinline__ float bf2f(unsigned short u) {
  return __uint_as_float(((unsigned)u) << 16);
}
__device__ __forceinline__ unsigned short f2h(float x) {   // RNE float->fp16
  _Float16 h = (_Float16)x;
  return *(unsigned short*)&h;
}
__device__ __forceinline__ float h2f(unsigned short u) {
  _Float16 h = *(_Float16*)&u;
  return (float)h;
}
// packed knn key: top 22 bits of fkey(d) | (1023 - idx). u32 '>' == dist desc, idx asc.
__device__ __forceinline__ unsigned knnkey(float d, int idx) {
  return (fkey(d) & 0xFFFFFC00u) | (unsigned)(1023 - idx);
}

// Bitonic top-k update: kl (sorted desc, KNN) <- top-KNN of (kl U bb[16]).
// bb gets bitonic-sorted ASC in place; half-cleaner + merge-32 DESC. All static indices.
__device__ __forceinline__ void topk_bitonic16(unsigned (&kl)[KNN], unsigned (&bb)[16]) {
  #pragma unroll
  for (int k = 2; k <= 16; k <<= 1) {
    #pragma unroll
    for (int j = k >> 1; j > 0; j >>= 1) {
      #pragma unroll
      for (int i = 0; i < 16; i++) {
        int l = i ^ j;
        if (l > i) {
          unsigned x = bb[i], y = bb[l];
          unsigned mn = min(x, y), mx = max(x, y);
          bool up = ((i & k) == 0);
          bb[i] = up ? mn : mx;
          bb[l] = up ? mx : mn;
        }
      }
    }
  }
  unsigned t[32];
  #pragma unroll
  for (int i = 0; i < 16; i++) t[i] = kl[i];
  #pragma unroll
  for (int i = 16; i < 32; i++) {
    unsigned a = (i < KNN) ? kl[i] : 0u;
    t[i] = max(a, bb[i - 16]);
  }
  #pragma unroll
  for (int j = 16; j > 0; j >>= 1) {
    #pragma unroll
    for (int i = 0; i < 32; i++) {
      int l = i ^ j;
      if (l > i) {
        unsigned x = t[i], y = t[l];
        t[i] = max(x, y); t[l] = min(x, y);
      }
    }
  }
  #pragma unroll
  for (int i = 0; i < KNN; i++) kl[i] = t[i];
}

// ---------- 1) fused prep + knn1: blocks 0..511 = knn1 8-way split; 512..1535 = prep ----------
__global__ void __launch_bounds__(256) k_prep_knn1(const float* __restrict__ x,
        float* __restrict__ xp1, const float* __restrict__ w2, const float* __restrict__ w3,
        unsigned short* __restrict__ w2h, unsigned short* __restrict__ wt3h,
        unsigned* __restrict__ keypart) {
  __shared__ float P[N_*3];
  __shared__ float XX[N_];
  if (blockIdx.x >= 512) {
    int i = (blockIdx.x - 512) * 256 + threadIdx.x;
    if (i < NPAIR) {
      float a0 = x[i*3+0], a1 = x[i*3+1], a2 = x[i*3+2];
      float n = sqrtf(a0*a0 + a1*a1 + a2*a2);
      n = fmaxf(n, 1e-15f);
      float th = tanhf(0.1f * n);
      float sc = th / (0.1f * n);
      float ny = fmaxf(th * 10.0f, 1e-15f);
      float mxn = (1.0f - 4e-3f) / 0.1f;
      if (ny > mxn) sc *= mxn / ny;
      xp1[i*3+0] = sc*a0; xp1[i*3+1] = sc*a1; xp1[i*3+2] = sc*a2;
    }
    if (i < 192*128) w2h[i] = f2bf(w2[i]);
    wt3h[i] = f2bf(w3[i]);
    return;
  }
  int blk = blockIdx.x;
  int b = blk >> 5, rc = (blk >> 3) & 3, cc = blk & 7;
  const float* xb = x + b*N_*3;
  for (int e = threadIdx.x; e < N_*3; e += 256) P[e] = xb[e];
  __syncthreads();
  for (int j = threadIdx.x; j < N_; j += 256) {
    float q0 = P[j*3], q1 = P[j*3+1], q2 = P[j*3+2];
    XX[j] = q0*q0 + q1*q1 + q2*q2;
  }
  __syncthreads();
  int r = rc*256 + threadIdx.x;
  float q0 = P[r*3], q1 = P[r*3+1], q2 = P[r*3+2];
  float xxq = XX[r];
  unsigned kl[KNN];
  #pragma unroll
  for (int i = 0; i < KNN; i++) kl[i] = 0u;
  int cbase = cc*128;
  // bitonic chunked scan: 8 chunks x 16 candidates (no serial guarded insert chain)
  for (int ch = 0; ch < 8; ch++) {
    unsigned bb[16];
    #pragma unroll
    for (int jj = 0; jj < 16; jj++) {
      int j = cbase + ch*16 + jj;
      float dot = q0*P[j*3] + q1*P[j*3+1] + q2*P[j*3+2];
      float d = 2.0f*dot - xxq - XX[j];
      bb[jj] = knnkey(d, j);
    }
    topk_bitonic16(kl, bb);
  }
  int p = b*N_ + r;
  unsigned* pe = keypart + (size_t)p*160 + cc*20;
  #pragma unroll
  for (int i = 0; i < KNN; i++) pe[i] = kl[i];
}

// ---------- 3) conv1 fused v3: streaming-count merge tree (8->4->2->1), fp32 stats ----------
__global__ void __launch_bounds__(256) k_conv1(const float* __restrict__ xp1,
                        const unsigned* __restrict__ keypart,
                        const float* __restrict__ w1, float* __restrict__ hmax1,
                        float* __restrict__ hmin1, float* __restrict__ stats1sh) {
  __shared__ float F[4][KNN][6];
  __shared__ float red[4][64][2];
  __shared__ int idxs[16][KNN];
  __shared__ unsigned keybuf[2560];   // 16 pairs x 160 keys, 10 KB
  __shared__ unsigned out1[1280];     // level-1 merged: 16 pts x 4 lists x 20
  __shared__ unsigned out2[640];      // level-2 merged: 16 pts x 2 lists x 20
  int g = threadIdx.x >> 6, lane = threadIdx.x & 63;
  int tid = threadIdx.x;
  int pbase = blockIdx.x * 16;
  {
    const unsigned* src = keypart + (size_t)pbase*160;
    for (int e = tid; e < 2560; e += 256) keybuf[e] = src[e];
  }
  float w[6];
  #pragma unroll
  for (int c = 0; c < 6; c++) w[c] = w1[lane*6 + c];
  __syncthreads();
  // L1: merge (2m, 2m+1) -> out1. rank = count over the pair's 40 keys (unique keys:
  // own sorted-desc list contributes exactly the own index). 40 pipelined LDS reads.
  for (int e = tid; e < 2560; e += 256) {
    int pt = e / 160, rem = e - pt*160;
    int m = rem / 40, i = rem - m*40;
    const unsigned* A = keybuf + pt*160 + (2*m)*20;   // 40 contiguous keys
    unsigned v = A[i];
    int rank = 0;
    #pragma unroll
    for (int j = 0; j < 40; j++) rank += (A[j] > v) ? 1 : 0;
    if (rank < KNN) out1[(pt*4 + m)*20 + rank] = v;
  }
  __syncthreads();
  // L2: merge (2m2, 2m2+1) of out1 -> out2  (1280 items)
  for (int e = tid; e < 1280; e += 256) {
    int pt = e / 80, rem = e - pt*80;
    int m2 = rem / 40, i = rem - m2*40;
    const unsigned* A = out1 + (pt*4 + 2*m2)*20;
    unsigned v = A[i];
    int rank = 0;
    #pragma unroll
    for (int j = 0; j < 40; j++) rank += (A[j] > v) ? 1 : 0;
    if (rank < KNN) out2[(pt*2 + m2)*20 + rank] = v;
  }
  __syncthreads();
  // L3: final merge -> idxs  (640 items)
  for (int e = tid; e < 640; e += 256) {
    int pt = e / 40, i = e - pt*40;
    const unsigned* A = out2 + pt*40;
    unsigned v = A[i];
    int rank = 0;
    #pragma unroll
    for (int j = 0; j < 40; j++) rank += (A[j] > v) ? 1 : 0;
    if (rank < KNN) idxs[pt][rank] = 1023 - (int)(v & 1023u);
  }
  float sum = 0.f, sumsq = 0.f;
  __syncthreads();
  for (int it = 0; it < 4; ++it) {
    int p = pbase + it*4 + g;
    if (lane < KNN) {
      int nb = idxs[it*4 + g][lane];
      int bb = p >> 10;
      const float* xc = xp1 + p*3;
      const float* ft = xp1 + (bb*N_ + nb)*3;
      float x0 = ft[0], x1 = ft[1], x2v = ft[2];
      float c0 = xc[0], c1 = xc[1], c2 = xc[2];
      float X2 = x0*x0 + x1*x1 + x2v*x2v;
      float Y2 = c0*c0 + c1*c1 + c2*c2;
      float XY = -(x0*c0 + x1*c1 + x2v*c2);
      float den = fmaxf(1.0f + 0.02f*XY + 1e-4f*X2*Y2, 1e-15f);
      float s1 = (1.0f + 0.02f*XY + 0.01f*Y2) / den;
      float s2 = (1.0f - 0.01f*X2) / den;
      F[g][lane][0] = s1*x0 - s2*c0;
      F[g][lane][1] = s1*x1 - s2*c1;
      F[g][lane][2] = s1*x2v - s2*c2;
      F[g][lane][3] = c0; F[g][lane][4] = c1; F[g][lane][5] = c2;
    }
    __syncthreads();
    float mx = -__builtin_inff(), mn = __builtin_inff();
    for (int k = 0; k < KNN; k++) {
      float h = 0.f;
      #pragma unroll
      for (int c = 0; c < 6; c++) h = fmaf(w[c], F[g][k][c], h);
      mx = fmaxf(mx, h); mn = fminf(mn, h);
      sum += h; sumsq += h*h;
    }
    hmax1[(pbase + it*4 + g)*64 + lane] = mx;
    hmin1[(pbase + it*4 + g)*64 + lane] = mn;
    __syncthreads();
  }
  red[g][lane][0] = sum; red[g][lane][1] = sumsq;
  __syncthreads();
  if (g == 0) {
    float s  = red[0][lane][0] + red[1][lane][0] + red[2][lane][0] + red[3][lane][0];
    float s2 = red[0][lane][1] + red[1][lane][1] + red[2][lane][1] + red[3][lane][1];
    float* dst = stats1sh + ((size_t)(blockIdx.x & 63)*64 + lane)*2;
    atomicAdd(dst, s);
    atomicAdd(dst + 1, s2);
  }
}

// ---------- BN stat reduce v4 (fp32 slots, f64 cross-slot accumulation) ----------
__global__ void __launch_bounds__(64) k_bn_reduce(const float* __restrict__ sh, int nch, int nslots,
                            double cnt,
                            const float* __restrict__ g, const float* __restrict__ bb,
                            float* __restrict__ scale, float* __restrict__ shift) {
  int o = blockIdx.x, t = threadIdx.x;
  double s = 0.0, s2 = 0.0;
  for (int sl = t; sl < nslots; sl += 64) {
    s  += (double)sh[((size_t)sl*nch + o)*2];
    s2 += (double)sh[((size_t)sl*nch + o)*2 + 1];
  }
  #pragma unroll
  for (int off = 32; off > 0; off >>= 1) { s += __shfl_xor(s, off); s2 += __shfl_xor(s2, off); }
  if (t == 0) {
    double m = s / cnt;
    double v = s2 / cnt - m*m;
    float a = g[o] / sqrtf((float)v + 1e-5f);
    scale[o] = a;
    shift[o] = bb[o] - a * (float)m;
  }
}

// ---------- 5) BN1 apply + relu + e2p + bf16 hi/lo split for MFMA knn2 + |x1|^2 ----------
__global__ void __launch_bounds__(256) k_bn1_apply(const float* __restrict__ hmax1, const float* __restrict__ hmin1,
                            const float* __restrict__ scale1, const float* __restrict__ shift1,
                            float* __restrict__ xp2,
                            unsigned short* __restrict__ x1h, unsigned short* __restrict__ x1l,
                            float* __restrict__ xx1) {
  int b = blockIdx.x >> 4, nc = blockIdx.x & 15;
  int c = threadIdx.x & 63, sub = threadIdx.x >> 6;
  int n0 = nc*64 + sub*16;
  float a = scale1[c], t = shift1[c];
  #pragma unroll
  for (int i = 0; i < 16; i++) {
    int p = b*1024 + n0 + i;
    float h = (a >= 0.f) ? hmax1[(size_t)p*64 + c] : hmin1[(size_t)p*64 + c];
    float x1 = fmaxf(fmaf(a, h, t), 0.f);
    // split-bf16: x1 = hi + lo with both bf16; dot via 4-term MFMA is fp32-accurate to ~2^-17
    unsigned short hb = f2bf(x1);
    x1h[(size_t)p*64 + c] = hb;
    x1l[(size_t)p*64 + c] = f2bf(x1 - bf2f(hb));
    float n2 = x1*x1;
    #pragma unroll
    for (int off = 32; off > 0; off >>= 1) n2 += __shfl_xor(n2, off);
    if (c == 0) xx1[p] = n2;
    float n1 = fmaxf(sqrtf(n2), 1e-15f);
    float th = tanhf(0.1f * n1);
    float sc = th / (0.1f * n1);
    float ny = fmaxf(th * 10.0f, 1e-15f);
    float mxn = (1.0f - 4e-3f) / 0.1f;
    if (ny > mxn) sc *= mxn / ny;
    xp2[(size_t)p*64 + c] = sc * x1;
  }
}

// ---------- 6) knn2 v12: register scan + bitonic top-k + register-linear rank-merge ----------
__global__ void __launch_bounds__(256) k_knn2g(const unsigned short* __restrict__ x1h,
        const unsigned short* __restrict__ x1l,
        const float* __restrict__ xx1, unsigned* __restrict__ keypart2) {
  __shared__ unsigned LU[5376];                  // 4 lists x 64q x 21 (21 KB)
  __shared__ unsigned MU[2688];                  // 2 merged x 64q x 21 (10.5 KB)
  int tid = threadIdx.x;
  int bi = blockIdx.x;
  int blk = ((bi & 7) << 7) + (bi >> 3);     // XCD-affine swizzle (1024 = 8*128, bijective)
  int b = blk >> 6, qc = (blk >> 2) & 15, cc = blk & 3;
  int qbase = qc*64, ccbase = cc*256;
  int wave = tid >> 6, lane = tid & 63;
  int lm = lane & 15, kq = lane >> 4;
  const size_t base = (size_t)b * 65536;     // b*1024*64

  // Q fragments (hi/lo) held in registers for the whole kernel: 4 qtiles x 2 ksteps
  bf16x8 Qh[4][2], Ql[4][2];
  #pragma unroll
  for (int qt = 0; qt < 4; qt++) {
    size_t ro = base + (size_t)(qbase + qt*16 + lm)*64 + kq*8;
    #pragma unroll
    for (int ks = 0; ks < 2; ks++) {
      Qh[qt][ks] = *((const bf16x8*)(x1h + ro + ks*32));
      Ql[qt][ks] = *((const bf16x8*)(x1l + ro + ks*32));
    }
  }
  unsigned kl[KNN];
  #pragma unroll
  for (int i = 0; i < KNN; i++) kl[i] = 0u;

  for (int st = 0; st < 4; ++st) {
    int cb0 = ccbase + st*64;
    // A fragments: this wave's 16 candidates, hi/lo
    size_t co = base + (size_t)(cb0 + wave*16 + lm)*64 + kq*8;
    bf16x8 Ah[2], Al[2];
    #pragma unroll
    for (int ks = 0; ks < 2; ks++) {
      Ah[ks] = *((const bf16x8*)(x1h + co + ks*32));
      Al[ks] = *((const bf16x8*)(x1l + co + ks*32));
    }
    float4 xxc = *((const float4*)(xx1 + b*1024 + cb0 + wave*16 + kq*4));
    f32x4 acc[4];
    #pragma unroll
    for (int qt = 0; qt < 4; qt++) acc[qt] = (f32x4){0.f, 0.f, 0.f, 0.f};
    #pragma unroll
    for (int ks = 0; ks < 2; ks++) {
      #pragma unroll
      for (int qt = 0; qt < 4; qt++) {
        acc[qt] = __builtin_amdgcn_mfma_f32_16x16x32_bf16(Ah[ks], Qh[qt][ks], acc[qt], 0, 0, 0);
        acc[qt] = __builtin_amdgcn_mfma_f32_16x16x32_bf16(Ah[ks], Ql[qt][ks], acc[qt], 0, 0, 0);
        acc[qt] = __builtin_amdgcn_mfma_f32_16x16x32_bf16(Al[ks], Qh[qt][ks], acc[qt], 0, 0, 0);
        acc[qt] = __builtin_amdgcn_mfma_f32_16x16x32_bf16(Al[ks], Ql[qt][ks], acc[qt], 0, 0, 0);
      }
    }
    // dist adjust while layout is [qt][cand r of own kq group]: xxcv[r] matches cand kq*4+r
    // (-xxq omitted: constant per query row, rank-invariant)
    f32x4 xxv = (f32x4){xxc.x, xxc.y, xxc.z, xxc.w};
    #pragma unroll
    for (int qt = 0; qt < 4; qt++) acc[qt] = acc[qt]*2.0f - xxv;
    // 4x4 cross-lane block transpose within {lm, lm+16, lm+32, lm+48}:
    // after: acc[qt][r] = D[lane][qt*4+r]
    {
      f32x4 s0, s1, r0, r1;
      bool h1 = (kq & 1) != 0;
      if (h1) { s0 = acc[0]; s1 = acc[2]; } else { s0 = acc[1]; s1 = acc[3]; }
      #pragma unroll
      for (int e = 0; e < 4; e++) { r0[e] = __shfl_xor(s0[e], 16); r1[e] = __shfl_xor(s1[e], 16); }
      if (h1) { acc[0] = r0; acc[2] = r1; } else { acc[1] = r0; acc[3] = r1; }
      bool h2 = (kq & 2) != 0;
      if (h2) { s0 = acc[0]; s1 = acc[1]; } else { s0 = acc[2]; s1 = acc[3]; }
      #pragma unroll
      for (int e = 0; e < 4; e++) { r0[e] = __shfl_xor(s0[e], 32); r1[e] = __shfl_xor(s1[e], 32); }
      if (h2) { acc[0] = r0; acc[1] = r1; } else { acc[2] = r0; acc[3] = r1; }
    }
    // keys for this stage's 16 candidates (unconditional), then bitonic top-k update
    unsigned bb[16];
    #pragma unroll
    for (int c = 0; c < 16; c++)
      bb[c] = knnkey(acc[c >> 2][c & 3], cb0 + wave*16 + c);
    topk_bitonic16(kl, bb);
  }
  // publish per-wave lists
  #pragma unroll
  for (int i = 0; i < KNN; i++) LU[wave*1344 + lane*21 + i] = kl[i];
  __syncthreads();
  // merge L1: (L0,L1)->M0, (L2,L3)->M1.  256 units = (pair, side, q); register-linear rank.
  {
    int pair = tid >> 7, side = (tid >> 6) & 1, q = tid & 63;
    const unsigned* own = LU + (pair*2 + side)*1344 + q*21;
    const unsigned* oth = LU + (pair*2 + 1 - side)*1344 + q*21;
    unsigned ow[KNN], ot[KNN];
    #pragma unroll
    for (int i = 0; i < KNN; i++) { ow[i] = own[i]; ot[i] = oth[i]; }
    unsigned* dst = MU + pair*1344 + q*21;
    #pragma unroll
    for (int i = 0; i < KNN; i++) {
      int r = i;
      #pragma unroll
      for (int j = 0; j < KNN; j++) r += (ot[j] > ow[i]) ? 1 : 0;
      if (r < KNN) dst[r] = ow[i];
    }
  }
  __syncthreads();
  // merge L2: (M0,M1) -> keypart2.  128 units = (side, q); register-linear rank.
  if (tid < 128) {
    int side = tid >> 6, q = tid & 63;
    const unsigned* own = MU + side*1344 + q*21;
    const unsigned* oth = MU + (1 - side)*1344 + q*21;
    unsigned ow[KNN], ot[KNN];
    #pragma unroll
    for (int i = 0; i < KNN; i++) { ow[i] = own[i]; ot[i] = oth[i]; }
    unsigned* pe = keypart2 + (size_t)(b*N_ + qbase + q)*80 + cc*20;
    #pragma unroll
    for (int i = 0; i < KNN; i++) {
      int r = i;
      #pragma unroll
      for (int j = 0; j < KNN; j++) r += (ot[j] > ow[i]) ? 1 : 0;
      if (r < KNN) pe[r] = ow[i];
    }
  }
}

// ---------- 9) conv2 via bf16 MFMA v12: streaming-count merge + fp32 center + fp16 outs ----------
__global__ void __launch_bounds__(256) k_conv2m(const float* __restrict__ xp2,
    const unsigned* __restrict__ keypart2, const unsigned short* __restrict__ w2h,
    unsigned short* __restrict__ hmax2, unsigned short* __restrict__ hmin2,
    float* __restrict__ stats2sh) {
  __shared__ __align__(16) short Abf[80*136];
  __shared__ __align__(16) float Cf[4][64];      // fp32 centers for Mobius math
  __shared__ float Yc[4];
  __shared__ int nbr[80];                        // logical order [pt*20 + k]
  __shared__ unsigned keybuf[320];               // 4 pairs x 80 keys
  int tid = threadIdx.x;
  int bi = blockIdx.x;
  int g512 = ((bi & 7) << 9) + (bi >> 3);
  int p0 = g512 * 4;
  int b = p0 >> 10;
  // Region A: stage merge keys (all threads) + center rows/Y2 (first wave) concurrently
  for (int e = tid; e < 320; e += 256) keybuf[e] = keypart2[(size_t)p0*80 + e];
  if (tid < 64) {
    int pt = tid >> 4, qq = tid & 15;
    float4 cv = *((const float4*)(xp2 + (size_t)(p0 + pt)*64) + qq);
    *((float4*)&Cf[pt][qq*4]) = cv;
    float y2 = cv.x*cv.x + cv.y*cv.y + cv.z*cv.z + cv.w*cv.w;
    #pragma unroll
    for (int off = 8; off > 0; off >>= 1) y2 += __shfl_xor(y2, off);
    if (qq == 0) Yc[pt] = y2;
    ushort4 cb;
    cb.x = f2bf(cv.x); cb.y = f2bf(cv.y); cb.z = f2bf(cv.z); cb.w = f2bf(cv.w);
    // replicate center into the 20 MFMA rows of this point: rows a*16 + pt*4 + j
    #pragma unroll
    for (int a = 0; a < 5; a++)
      #pragma unroll
      for (int j2 = 0; j2 < 4; j2++)
        *((ushort4*)(Abf + (a*16 + pt*4 + j2)*136 + 64 + qq*4)) = cb;
  }
  __syncthreads();
  // Region B: parallel 4-way merge via streaming count over all 80 keys (unique keys:
  // own sorted-desc list contributes exactly the own index). 80 pipelined LDS reads/unit.
  for (int e = tid; e < 320; e += 256) {
    int pt = e / 80;
    int rem = e - pt*80;
    const unsigned* LB = keybuf + pt*80;
    unsigned v = LB[rem];
    int rank = 0;
    #pragma unroll
    for (int j = 0; j < 80; j++) rank += (LB[j] > v) ? 1 : 0;
    if (rank < KNN) nbr[pt*20 + rank] = 1023 - (int)(v & 1023u);
  }
  __syncthreads();
  // Region C: gather + Mobius in one pass, all fp32 (center from Cf), single divide
  for (int e = tid; e < 80*16; e += 256) {
    int r = e >> 4, qq = e & 15;
    int q = (r >> 2) & 3;
    int L = 20*q + 4*(r >> 4) + (r & 3);
    float4 f = *((const float4*)(xp2 + (size_t)(b*N_ + nbr[L])*64) + qq);
    float4 cvf = *((const float4*)&Cf[q][qq*4]);
    float X2 = f.x*f.x + f.y*f.y + f.z*f.z + f.w*f.w;
    float XY = -(f.x*cvf.x + f.y*cvf.y + f.z*cvf.z + f.w*cvf.w);
    #pragma unroll
    for (int off = 8; off > 0; off >>= 1) {
      X2 += __shfl_xor(X2, off);
      XY += __shfl_xor(XY, off);
    }
    float Y2 = Yc[q];
    float den = fmaxf(1.0f + 0.02f*XY + 1e-4f*X2*Y2, 1e-15f);
    float inv = 1.0f / den;
    float s1 = (1.0f + 0.02f*XY + 0.01f*Y2) * inv;
    float s2 = (1.0f - 0.01f*X2) * inv;
    ushort4 mo;
    mo.x = f2bf(s1*f.x - s2*cvf.x);
    mo.y = f2bf(s1*f.y - s2*cvf.y);
    mo.z = f2bf(s1*f.z - s2*cvf.z);
    mo.w = f2bf(s1*f.w - s2*cvf.w);
    *((ushort4*)(Abf + r*136 + qq*4)) = mo;
  }
  __syncthreads();
  // Region D: MFMA + register epilogue (fp16 max/min stores, fp32 stats atomics)
  int wave = tid >> 6, lane = tid & 63;
  int quad = lane >> 4, lm = lane & 15;
  int colbase = wave*48;
  f32x4 acc[5][3];
  #pragma unroll
  for (int rt = 0; rt < 5; rt++)
    #pragma unroll
    for (int cj = 0; cj < 3; cj++) acc[rt][cj] = (f32x4){0.f, 0.f, 0.f, 0.f};
  #pragma unroll
  for (int kt = 0; kt < 4; kt++) {
    int k0 = kt*32 + quad*8;
    bf16x8 bf[3];
    #pragma unroll
    for (int cj = 0; cj < 3; cj++)
      bf[cj] = *((const bf16x8*)(w2h + (size_t)(colbase + cj*16 + lm)*128 + k0));
    bf16x8 af[5];
    #pragma unroll
    for (int rt = 0; rt < 5; rt++)
      af[rt] = *((const bf16x8*)(Abf + (rt*16 + lm)*136 + k0));
    #pragma unroll
    for (int rt = 0; rt < 5; rt++)
      #pragma unroll
      for (int cj = 0; cj < 3; cj++)
        acc[rt][cj] = __builtin_amdgcn_mfma_f32_16x16x32_bf16(af[rt], bf[cj], acc[rt][cj], 0, 0, 0);
  }
  #pragma unroll
  for (int cj = 0; cj < 3; cj++) {
    int o = colbase + cj*16 + lm;
    float s = 0.f, s2 = 0.f, mx = -__builtin_inff(), mn = __builtin_inff();
    #pragma unroll
    for (int rt = 0; rt < 5; rt++) {
      #pragma unroll
      for (int reg = 0; reg < 4; reg++) {
        float h = acc[rt][cj][reg];
        s += h; s2 += h*h;
        mx = fmaxf(mx, h); mn = fminf(mn, h);
      }
    }
    hmax2[(size_t)(p0 + quad)*192 + o] = f2h(mx);
    hmin2[(size_t)(p0 + quad)*192 + o] = f2h(mn);
    s  += __shfl_xor(s, 16);  s  += __shfl_xor(s, 32);
    s2 += __shfl_xor(s2, 16); s2 += __shfl_xor(s2, 32);
    if (lane < 16) {
      float* dst = stats2sh + ((size_t)(bi & 255)*192 + o)*2;
      atomicAdd(dst, s); atomicAdd(dst + 1, s2);
    }
  }
}

// ---------- 11) conv3 via bf16 MFMA: ch0-63 from x1h (already bf16), ch64-255 from fp16 hmax2/hmin2 ----------
__global__ void __launch_bounds__(256) k_conv3m(
   const unsigned short* __restrict__ x1h,
   const unsigned short* __restrict__ hmax2, const unsigned short* __restrict__ hmin2,
   const float* __restrict__ scale2, const float* __restrict__ shift2,
   const unsigned short* __restrict__ wt3h, float* __restrict__ stats3sh,
   unsigned* __restrict__ hmax3u, unsigned* __restrict__ hmin3u) {
  __shared__ short As[64*264];
  int tid = threadIdx.x;
  int mt = blockIdx.x >> 2, cb = blockIdx.x & 3;
  int rowbase = mt*64;
  int b = rowbase >> 10;
  int c4 = tid & 63;
  float4 sc, sh;
  if (c4 >= 16) {
    sc = *((const float4*)(scale2 + (c4*4 - 64)));
    sh = *((const float4*)(shift2 + (c4*4 - 64)));
  }
  #pragma unroll 4
  for (int i = 0; i < 16; i++) {
    int r = (tid >> 6) + i*4;
    int p = rowbase + r;
    if (c4 < 16) {
      // channels 0..63: x1h already holds f2bf(relu(BN1(h))) in (B,N,64) layout
      *((ushort4*)(As + r*264 + c4*4)) =
        *((const ushort4*)(x1h + (size_t)p*64 + c4*4));
    } else {
      ushort4 hx4 = *((const ushort4*)(hmax2 + (size_t)p*192 + (c4*4 - 64)));
      ushort4 hn4 = *((const ushort4*)(hmin2 + (size_t)p*192 + (c4*4 - 64)));
      ushort4 o4;
      o4.x = f2bf(fmaxf(fmaf(sc.x, (sc.x >= 0.f ? h2f(hx4.x) : h2f(hn4.x)), sh.x), 0.f));
      o4.y = f2bf(fmaxf(fmaf(sc.y, (sc.y >= 0.f ? h2f(hx4.y) : h2f(hn4.y)), sh.y), 0.f));
      o4.z = f2bf(fmaxf(fmaf(sc.z, (sc.z >= 0.f ? h2f(hx4.z) : h2f(hn4.z)), sh.z), 0.f));
      o4.w = f2bf(fmaxf(fmaf(sc.w, (sc.w >= 0.f ? h2f(hx4.w) : h2f(hn4.w)), sh.w), 0.f));
      *((ushort4*)(As + r*264 + c4*4)) = o4;
    }
  }
  __syncthreads();
  int wave = tid >> 6, lane = tid & 63;
  int quad = lane >> 4, lm = lane & 15;
  int colbase = cb*256 + wave*64;
  f32x4 acc[4][4];
  #pragma unroll
  for (int ri = 0; ri < 4; ri++)
    #pragma unroll
    for (int cj = 0; cj < 4; cj++) acc[ri][cj] = (f32x4){0.f, 0.f, 0.f, 0.f};
  for (int kt = 0; kt < 8; kt++) {
    int k0 = kt*32 + quad*8;
    bf16x8 bf[4];
    #pragma unroll
    for (int cj = 0; cj < 4; cj++)
      bf[cj] = *((const bf16x8*)(wt3h + (size_t)(colbase + cj*16 + lm)*256 + k0));
    bf16x8 af[4];
    #pragma unroll
    for (int ri = 0; ri < 4; ri++)
      af[ri] = *((const bf16x8*)(As + (ri*16 + lm)*264 + k0));
    #pragma unroll
    for (int ri = 0; ri < 4; ri++)
      #pragma unroll
      for (int cj = 0; cj < 4; cj++)
        acc[ri][cj] = __builtin_amdgcn_mfma_f32_16x16x32_bf16(af[ri], bf[cj], acc[ri][cj], 0, 0, 0);
  }
  #pragma unroll
  for (int cj = 0; cj < 4; cj++) {
    float s = 0.f, s2 = 0.f, mx = -__builtin_inff(), mn = __builtin_inff();
    #pragma unroll
    for (int ri = 0; ri < 4; ri++) {
      #pragma unroll
      for (int reg = 0; reg < 4; reg++) {
        float h = acc[ri][cj][reg];
        s += h; s2 += h*h; mx = fmaxf(mx, h); mn = fminf(mn, h);
      }
    }
    s  += __shfl_xor(s, 16);  s  += __shfl_xor(s, 32);
    s2 += __shfl_xor(s2, 16); s2 += __shfl_xor(s2, 32);
    mx = fmaxf(mx, __shfl_xor(mx, 16)); mx = fmaxf(mx, __shfl_xor(mx, 32));
    mn = fminf(mn, __shfl_xor(mn, 16)); mn = fminf(mn, __shfl_xor(mn, 32));
    if (lane < 16) {
      int col = colbase + cj*16 + lane;
      float* dst = stats3sh + ((size_t)(blockIdx.x & 63)*1024 + col)*2;
      atomicAdd(dst, s);
      atomicAdd(dst + 1, s2);
      atomicMax(hmax3u + b*1024 + col, fkey(mx));
      atomicMin(hmin3u + b*1024 + col, fkey(mn));
    }
  }
}

// ---------- 12) head, split for weight-read parallelism ----------
__device__ float blk_reduce(float v, float* red, int tid) {
  red[tid] = v; __syncthreads();
  for (int st = 128; st > 0; st >>= 1) {
    if (tid < st) red[tid] += red[tid + st];
    __syncthreads();
  }
  float r = red[0]; __syncthreads();
  return r;
}

__global__ void __launch_bounds__(256) k_head1(const unsigned* __restrict__ hmax3u,
    const unsigned* __restrict__ hmin3u,
    const float* __restrict__ scale3, const float* __restrict__ shift3,
    const float* __restrict__ fc1w, const float* __restrict__ fc1b,
    float* __restrict__ h1buf) {
  __shared__ __align__(16) float V[1024];
  int b = blockIdx.x >> 5, oc = blockIdx.x & 31;
  int tid = threadIdx.x;
  for (int o = tid; o < 1024; o += 256) {
    float a = scale3[o];
    unsigned u = (a >= 0.f) ? hmax3u[b*1024 + o] : hmin3u[b*1024 + o];
    V[o] = fmaxf(fmaf(a, fkeyinv(u), shift3[o]), 0.f);
  }
  __syncthreads();
  int ty = tid >> 4, tx = tid & 15;
  int o = oc*16 + ty;
  const float4* wr = (const float4*)(fc1w + (size_t)o*1024) + tx*16;
  const float4* vv = (const float4*)V + tx*16;
  float s = 0.f;
  #pragma unroll
  for (int i = 0; i < 16; i++) {
    float4 w = wr[i]; float4 v = vv[i];
    s = fmaf(w.x, v.x, s); s = fmaf(w.y, v.y, s);
    s = fmaf(w.z, v.z, s); s = fmaf(w.w, v.w, s);
  }
  s += __shfl_xor(s, 1); s += __shfl_xor(s, 2);
  s += __shfl_xor(s, 4); s += __shfl_xor(s, 8);
  if (tx == 0) h1buf[b*512 + o] = s + fc1b[o];
}

__global__ void __launch_bounds__(256) k_head2(const float* __restrict__ h1buf,
    const float* __restrict__ ln1g, const float* __restrict__ ln1b,
    const float* __restrict__ fc2w, const float* __restrict__ fc2b,
    float* __restrict__ h2buf) {
  __shared__ __align__(16) float H1[512];
  __shared__ float red[256];
  int b = blockIdx.x >> 3, oc = blockIdx.x & 7;
  int tid = threadIdx.x;
  float v0 = h1buf[b*512 + tid], v1 = h1buf[b*512 + 256 + tid];
  float s = blk_reduce(v0 + v1, red, tid);
  float s2 = blk_reduce(v0*v0 + v1*v1, red, tid);
  float m = s / 512.f;
  float var = s2 / 512.f - m*m;
  float inv = 1.0f / sqrtf(var + 1e-5f);
  H1[tid] = fmaxf((v0 - m)*inv*ln1g[tid] + ln1b[tid], 0.f);
  H1[256 + tid] = fmaxf((v1 - m)*inv*ln1g[256 + tid] + ln1b[256 + tid], 0.f);
  __syncthreads();
  int ty = tid >> 3, tx = tid & 7;
  int o = oc*32 + ty;
  const float4* wr = (const float4*)(fc2w + (size_t)o*512) + tx*16;
  const float4* vv = (const float4*)H1 + tx*16;
  float t = 0.f;
  #pragma unroll
  for (int i = 0; i < 16; i++) {
    float4 w = wr[i]; float4 v = vv[i];
    t = fmaf(w.x, v.x, t); t = fmaf(w.y, v.y, t);
    t = fmaf(w.z, v.z, t); t = fmaf(w.w, v.w, t);
  }
  t += __shfl_xor(t, 1); t += __shfl_xor(t, 2); t += __shfl_xor(t, 4);
  if (tx == 0) h2buf[b*256 + o] = t + fc2b[o];
}

__global__ void __launch_bounds__(256) k_head3(const float* __restrict__ h2buf,
    const float* __restrict__ ln2g, const float* __restrict__ ln2b,
    const float* __restrict__ outw, const float* __restrict__ outb,
    float* __restrict__ out) {
  __shared__ __align__(16) float H2[256];
  __shared__ float red[256];
  int b = blockIdx.x, tid = threadIdx.x;
  float h2v = h2buf[b*256 + tid];
  float ss = blk_reduce(h2v, red, tid);
  float ss2 = blk_reduce(h2v*h2v, red, tid);
  float m2 = ss / 256.f;
  float var2 = ss2 / 256.f - m2*m2;
  float inv2 = 1.0f / sqrtf(var2 + 1e-5f);
  H2[tid] = fmaxf((h2v - m2)*inv2*ln2g[tid] + ln2b[tid], 0.f);
  __syncthreads();
  if (tid < 40) {
    const float4* wr = (const float4*)(outw + (size_t)tid*256);
    float t = 0.f;
    for (int c4 = 0; c4 < 64; c4++) {
      float4 w = wr[c4]; float4 vv = ((const float4*)H2)[c4];
      t = fmaf(w.x, vv.x, t); t = fmaf(w.y, vv.y, t);
      t = fmaf(w.z, vv.z, t); t = fmaf(w.w, vv.w, t);
    }
    red[tid] = t + outb[tid];
  }
  __syncthreads();
  if (tid == 0) {
    float mx = -__builtin_inff();
    for (int i2 = 0; i2 < 40; i2++) mx = fmaxf(mx, red[i2]);
    float se = 0.f;
    for (int i2 = 0; i2 < 40; i2++) se += expf(red[i2] - mx);
    float lse = mx + logf(se);
    for (int i2 = 0; i2 < 40; i2++) out[b*40 + i2] = red[i2] - lse;
  }
}

extern "C" void kernel_launch(void* const* d_in, const int* in_sizes, int n_in,
                              void* d_out, int out_size, void* d_ws, size_t ws_size,
                              hipStream_t stream) {
  (void)in_sizes; (void)n_in; (void)out_size; (void)ws_size;
  const float* x    = (const float*)d_in[0];
  const float* w1   = (const float*)d_in[1];
  const float* bn1g = (const float*)d_in[2];
  const float* bn1b = (const float*)d_in[3];
  const float* w2   = (const float*)d_in[4];
  const float* bn2g = (const float*)d_in[5];
  const float* bn2b = (const float*)d_in[6];
  const float* w3   = (const float*)d_in[7];
  const float* bn3g = (const float*)d_in[8];
  const float* bn3b = (const float*)d_in[9];
  const float* fc1w = (const float*)d_in[10];
  const float* fc1b = (const float*)d_in[11];
  const float* ln1g = (const float*)d_in[12];
  const float* ln1b = (const float*)d_in[13];
  const float* fc2w = (const float*)d_in[14];
  const float* fc2b = (const float*)d_in[15];
  const float* ln2g = (const float*)d_in[16];
  const float* ln2b = (const float*)d_in[17];
  const float* outw = (const float*)d_in[18];
  const float* outb = (const float*)d_in[19];
  float* out = (float*)d_out;

  float* ws = (float*)d_ws;
  size_t off = 0;
  float* xp1   = ws + off; off += 49152;
  float* hmax1 = ws + off; off += 1048576;
  float* hmin1 = ws + off; off += 1048576;
  float* xp2   = ws + off; off += 1048576;
  float* hmax2f = ws + off; off += 3145728;  // holds keypartA (knn1 partials) then fp16 hmax2
  float* hmin2f = ws + off; off += 3145728;  // fp16 hmin2
  unsigned* keypart2 = (unsigned*)(ws + off); off += 1310720;  // knn2 partials, 80/pt
  unsigned short* w2h = (unsigned short*)(ws + off); off += 24576;
  unsigned short* wt3h = (unsigned short*)(ws + off); off += 131072;
  float* x1bf  = ws + off; off += 1048576;   // x1 bf16 hi (2MB) + lo (2MB), (B,N,64) layout
  float* xx1   = ws + off; off += 16384;
  float* h1buf = ws + off; off += 8192;
  float* h2buf = ws + off; off += 4096;
  float* scale1 = ws + off; off += 64;
  float* shift1 = ws + off; off += 64;
  float* scale2 = ws + off; off += 192;
  float* shift2 = ws + off; off += 192;
  float* scale3 = ws + off; off += 1024;
  float* shift3 = ws + off; off += 1024;
  float* stats1sh = ws + off;                         // fp32 stats
  float* stats2sh = stats1sh + 64*64*2;
  float* stats3sh = stats2sh + (size_t)256*192*2;
  unsigned* hmax3u = (unsigned*)(stats3sh + (size_t)64*1024*2);
  unsigned* hmin3u = hmax3u + 16384;
  unsigned* keypartA = (unsigned*)hmax2f;
  unsigned short* x1h = (unsigned short*)x1bf;
  unsigned short* x1l = x1h + 1048576;
  unsigned short* hmax2 = (unsigned short*)hmax2f;
  unsigned short* hmin2 = (unsigned short*)hmin2f;

  size_t zero_bytes = ((size_t)64*64*2 + (size_t)256*192*2 + (size_t)64*1024*2)*4 + (size_t)16384*4;
  hipMemsetAsync(stats1sh, 0, zero_bytes, stream);
  hipMemsetAsync(hmin3u, 0xFF, (size_t)16384*4, stream);

  k_prep_knn1<<<1536, 256, 0, stream>>>(x, xp1, w2, w3, w2h, wt3h, keypartA);
  k_conv1<<<1024, 256, 0, stream>>>(xp1, keypartA, w1, hmax1, hmin1, stats1sh);
  k_bn_reduce<<<64, 64, 0, stream>>>(stats1sh, 64, 64, 327680.0, bn1g, bn1b, scale1, shift1);
  k_bn1_apply<<<256, 256, 0, stream>>>(hmax1, hmin1, scale1, shift1, xp2, x1h, x1l, xx1);
  k_knn2g<<<1024, 256, 0, stream>>>(x1h, x1l, xx1, keypart2);
  k_conv2m<<<4096, 256, 0, stream>>>(xp2, keypart2, w2h, hmax2, hmin2, stats2sh);
  k_bn_reduce<<<192, 64, 0, stream>>>(stats2sh, 192, 256, 327680.0, bn2g, bn2b, scale2, shift2);
  k_conv3m<<<1024, 256, 0, stream>>>(x1h, hmax2, hmin2, scale2, shift2,
                                     wt3h, stats3sh, hmax3u, hmin3u);
  k_bn_reduce<<<1024, 64, 0, stream>>>(stats3sh, 1024, 64, 16384.0, bn3g, bn3b, scale3, shift3);
  k_head1<<<512, 256, 0, stream>>>(hmax3u, hmin3u, scale3, shift3, fc1w, fc1b, h1buf);
  k_head2<<<128, 256, 0, stream>>>(h1buf, ln1g, ln1b, fc2w, fc2b, h2buf);
  k_head3<<<16, 256, 0, stream>>>(h2buf, ln2g, ln2b, outw, outb, out);
}

// Round 12
// 303.585 us; speedup vs baseline: 1.1530x; 1.0089x over previous
//
#include <hip/hip_runtime.h>
#include <math.h>

#define B_ 16
#define N_ 1024
#define KNN 20
#define NPAIR (B_*N_)

typedef __attribute__((ext_vector_type(8))) short bf16x8;
typedef __attribute__((ext_vector_type(4))) float f32x4;

// ---------- helpers ----------
__device__ __forceinline__ unsigned fkey(float f) {
  unsigned u = __float_as_uint(f);
  return (u & 0x80000000u) ? ~u : (u | 0x80000000u);
}
__device__ __forceinline__ float fkeyinv(unsigned u) {
  unsigned b = (u & 0x80000000u) ? (u ^ 0x80000000u) : ~u;
  return __uint_as_float(b);
}
__device__ __forceinline__ unsigned short f2bf(float x) {  // RNE float->bf16
  unsigned u = __float_as_uint(x);
  unsigned r = (u + 0x7FFFu + ((u >> 16) & 1u)) >> 16;
  return (unsigned short)r;
}
__device__ __forceinline__ float bf2f(unsigned short u) {
  return __uint_as_float(((unsigned)u) << 16);
}
__device__ __forceinline__ unsigned short f2h(float x) {   // RNE float->fp16
  _Float16 h = (_Float16)x;
  return *(unsigned short*)&h;
}
__device__ __forceinline__ float h2f(unsigned short u) {
  _Float16 h = *(_Float16*)&u;
  return (float)h;
}
// packed knn key: top 22 bits of fkey(d) | (1023 - idx). u32 '>' == dist desc, idx asc.
__device__ __forceinline__ unsigned knnkey(float d, int idx) {
  return (fkey(d) & 0xFFFFFC00u) | (unsigned)(1023 - idx);
}

// Bitonic top-k update: kl (sorted desc, KNN) <- top-KNN of (kl U bb[16]).
// bb gets bitonic-sorted ASC in place; half-cleaner + merge-32 DESC. All static indices.
__device__ __forceinline__ void topk_bitonic16(unsigned (&kl)[KNN], unsigned (&bb)[16]) {
  #pragma unroll
  for (int k = 2; k <= 16; k <<= 1) {
    #pragma unroll
    for (int j = k >> 1; j > 0; j >>= 1) {
      #pragma unroll
      for (int i = 0; i < 16; i++) {
        int l = i ^ j;
        if (l > i) {
          unsigned x = bb[i], y = bb[l];
          unsigned mn = min(x, y), mx = max(x, y);
          bool up = ((i & k) == 0);
          bb[i] = up ? mn : mx;
          bb[l] = up ? mx : mn;
        }
      }
    }
  }
  unsigned t[32];
  #pragma unroll
  for (int i = 0; i < 16; i++) t[i] = kl[i];
  #pragma unroll
  for (int i = 16; i < 32; i++) {
    unsigned a = (i < KNN) ? kl[i] : 0u;
    t[i] = max(a, bb[i - 16]);
  }
  #pragma unroll
  for (int j = 16; j > 0; j >>= 1) {
    #pragma unroll
    for (int i = 0; i < 32; i++) {
      int l = i ^ j;
      if (l > i) {
        unsigned x = t[i], y = t[l];
        t[i] = max(x, y); t[l] = min(x, y);
      }
    }
  }
  #pragma unroll
  for (int i = 0; i < KNN; i++) kl[i] = t[i];
}

// ---------- 1) fused prep + knn1 + workspace-init: blocks 0..511 = knn1; 512..1535 = prep ----------
__global__ void __launch_bounds__(256) k_prep_knn1(const float* __restrict__ x,
        float* __restrict__ xp1, const float* __restrict__ w2, const float* __restrict__ w3,
        unsigned short* __restrict__ w2h, unsigned short* __restrict__ wt3h,
        unsigned* __restrict__ keypart,
        unsigned* __restrict__ zer0, unsigned* __restrict__ hmin3u) {
  __shared__ float P[N_*3];
  __shared__ float XX[N_];
  if (blockIdx.x >= 512) {
    int i = (blockIdx.x - 512) * 256 + threadIdx.x;
    if (i < NPAIR) {
      float a0 = x[i*3+0], a1 = x[i*3+1], a2 = x[i*3+2];
      float n = sqrtf(a0*a0 + a1*a1 + a2*a2);
      n = fmaxf(n, 1e-15f);
      float th = tanhf(0.1f * n);
      float sc = th / (0.1f * n);
      float ny = fmaxf(th * 10.0f, 1e-15f);
      float mxn = (1.0f - 4e-3f) / 0.1f;
      if (ny > mxn) sc *= mxn / ny;
      xp1[i*3+0] = sc*a0; xp1[i*3+1] = sc*a1; xp1[i*3+2] = sc*a2;
    }
    if (i < 192*128) w2h[i] = f2bf(w2[i]);
    wt3h[i] = f2bf(w3[i]);
    // workspace init (replaces 2 hipMemsetAsync dispatches): stats1+stats2+stats3+hmax3u = 0,
    // hmin3u = 0xFFFFFFFF. Stream order guarantees completion before any consumer kernel.
    for (unsigned j = i; j < 253952u; j += 262144u) zer0[j] = 0u;
    for (unsigned j = i; j < 16384u; j += 262144u) hmin3u[j] = 0xFFFFFFFFu;
    return;
  }
  int blk = blockIdx.x;
  int b = blk >> 5, rc = (blk >> 3) & 3, cc = blk & 7;
  const float* xb = x + b*N_*3;
  for (int e = threadIdx.x; e < N_*3; e += 256) P[e] = xb[e];
  __syncthreads();
  for (int j = threadIdx.x; j < N_; j += 256) {
    float q0 = P[j*3], q1 = P[j*3+1], q2 = P[j*3+2];
    XX[j] = q0*q0 + q1*q1 + q2*q2;
  }
  __syncthreads();
  int r = rc*256 + threadIdx.x;
  float q0 = P[r*3], q1 = P[r*3+1], q2 = P[r*3+2];
  float xxq = XX[r];
  unsigned kl[KNN];
  #pragma unroll
  for (int i = 0; i < KNN; i++) kl[i] = 0u;
  int cbase = cc*128;
  // bitonic chunked scan: 8 chunks x 16 candidates (no serial guarded insert chain)
  for (int ch = 0; ch < 8; ch++) {
    unsigned bb[16];
    #pragma unroll
    for (int jj = 0; jj < 16; jj++) {
      int j = cbase + ch*16 + jj;
      float dot = q0*P[j*3] + q1*P[j*3+1] + q2*P[j*3+2];
      float d = 2.0f*dot - xxq - XX[j];
      bb[jj] = knnkey(d, j);
    }
    topk_bitonic16(kl, bb);
  }
  int p = b*N_ + r;
  unsigned* pe = keypart + (size_t)p*160 + cc*20;
  #pragma unroll
  for (int i = 0; i < KNN; i++) pe[i] = kl[i];
}

// ---------- 3) conv1 fused v3: streaming-count merge tree (8->4->2->1), fp32 stats ----------
__global__ void __launch_bounds__(256) k_conv1(const float* __restrict__ xp1,
                        const unsigned* __restrict__ keypart,
                        const float* __restrict__ w1, float* __restrict__ hmax1,
                        float* __restrict__ hmin1, float* __restrict__ stats1sh) {
  __shared__ float F[4][KNN][6];
  __shared__ float red[4][64][2];
  __shared__ int idxs[16][KNN];
  __shared__ unsigned keybuf[2560];   // 16 pairs x 160 keys, 10 KB
  __shared__ unsigned out1[1280];     // level-1 merged: 16 pts x 4 lists x 20
  __shared__ unsigned out2[640];      // level-2 merged: 16 pts x 2 lists x 20
  int g = threadIdx.x >> 6, lane = threadIdx.x & 63;
  int tid = threadIdx.x;
  int pbase = blockIdx.x * 16;
  {
    const unsigned* src = keypart + (size_t)pbase*160;
    for (int e = tid; e < 2560; e += 256) keybuf[e] = src[e];
  }
  float w[6];
  #pragma unroll
  for (int c = 0; c < 6; c++) w[c] = w1[lane*6 + c];
  __syncthreads();
  // L1: merge (2m, 2m+1) -> out1. rank = count over the pair's 40 keys (unique keys:
  // own sorted-desc list contributes exactly the own index). 40 pipelined LDS reads.
  for (int e = tid; e < 2560; e += 256) {
    int pt = e / 160, rem = e - pt*160;
    int m = rem / 40, i = rem - m*40;
    const unsigned* A = keybuf + pt*160 + (2*m)*20;   // 40 contiguous keys
    unsigned v = A[i];
    int rank = 0;
    #pragma unroll
    for (int j = 0; j < 40; j++) rank += (A[j] > v) ? 1 : 0;
    if (rank < KNN) out1[(pt*4 + m)*20 + rank] = v;
  }
  __syncthreads();
  // L2: merge (2m2, 2m2+1) of out1 -> out2  (1280 items)
  for (int e = tid; e < 1280; e += 256) {
    int pt = e / 80, rem = e - pt*80;
    int m2 = rem / 40, i = rem - m2*40;
    const unsigned* A = out1 + (pt*4 + 2*m2)*20;
    unsigned v = A[i];
    int rank = 0;
    #pragma unroll
    for (int j = 0; j < 40; j++) rank += (A[j] > v) ? 1 : 0;
    if (rank < KNN) out2[(pt*2 + m2)*20 + rank] = v;
  }
  __syncthreads();
  // L3: final merge -> idxs  (640 items)
  for (int e = tid; e < 640; e += 256) {
    int pt = e / 40, i = e - pt*40;
    const unsigned* A = out2 + pt*40;
    unsigned v = A[i];
    int rank = 0;
    #pragma unroll
    for (int j = 0; j < 40; j++) rank += (A[j] > v) ? 1 : 0;
    if (rank < KNN) idxs[pt][rank] = 1023 - (int)(v & 1023u);
  }
  float sum = 0.f, sumsq = 0.f;
  __syncthreads();
  for (int it = 0; it < 4; ++it) {
    int p = pbase + it*4 + g;
    if (lane < KNN) {
      int nb = idxs[it*4 + g][lane];
      int bb = p >> 10;
      const float* xc = xp1 + p*3;
      const float* ft = xp1 + (bb*N_ + nb)*3;
      float x0 = ft[0], x1 = ft[1], x2v = ft[2];
      float c0 = xc[0], c1 = xc[1], c2 = xc[2];
      float X2 = x0*x0 + x1*x1 + x2v*x2v;
      float Y2 = c0*c0 + c1*c1 + c2*c2;
      float XY = -(x0*c0 + x1*c1 + x2v*c2);
      float den = fmaxf(1.0f + 0.02f*XY + 1e-4f*X2*Y2, 1e-15f);
      float s1 = (1.0f + 0.02f*XY + 0.01f*Y2) / den;
      float s2 = (1.0f - 0.01f*X2) / den;
      F[g][lane][0] = s1*x0 - s2*c0;
      F[g][lane][1] = s1*x1 - s2*c1;
      F[g][lane][2] = s1*x2v - s2*c2;
      F[g][lane][3] = c0; F[g][lane][4] = c1; F[g][lane][5] = c2;
    }
    __syncthreads();
    float mx = -__builtin_inff(), mn = __builtin_inff();
    for (int k = 0; k < KNN; k++) {
      float h = 0.f;
      #pragma unroll
      for (int c = 0; c < 6; c++) h = fmaf(w[c], F[g][k][c], h);
      mx = fmaxf(mx, h); mn = fminf(mn, h);
      sum += h; sumsq += h*h;
    }
    hmax1[(pbase + it*4 + g)*64 + lane] = mx;
    hmin1[(pbase + it*4 + g)*64 + lane] = mn;
    __syncthreads();
  }
  red[g][lane][0] = sum; red[g][lane][1] = sumsq;
  __syncthreads();
  if (g == 0) {
    float s  = red[0][lane][0] + red[1][lane][0] + red[2][lane][0] + red[3][lane][0];
    float s2 = red[0][lane][1] + red[1][lane][1] + red[2][lane][1] + red[3][lane][1];
    float* dst = stats1sh + ((size_t)(blockIdx.x & 63)*64 + lane)*2;
    atomicAdd(dst, s);
    atomicAdd(dst + 1, s2);
  }
}

// ---------- BN stat reduce v4 (fp32 slots, f64 cross-slot accumulation) ----------
__global__ void __launch_bounds__(64) k_bn_reduce(const float* __restrict__ sh, int nch, int nslots,
                            double cnt,
                            const float* __restrict__ g, const float* __restrict__ bb,
                            float* __restrict__ scale, float* __restrict__ shift) {
  int o = blockIdx.x, t = threadIdx.x;
  double s = 0.0, s2 = 0.0;
  for (int sl = t; sl < nslots; sl += 64) {
    s  += (double)sh[((size_t)sl*nch + o)*2];
    s2 += (double)sh[((size_t)sl*nch + o)*2 + 1];
  }
  #pragma unroll
  for (int off = 32; off > 0; off >>= 1) { s += __shfl_xor(s, off); s2 += __shfl_xor(s2, off); }
  if (t == 0) {
    double m = s / cnt;
    double v = s2 / cnt - m*m;
    float a = g[o] / sqrtf((float)v + 1e-5f);
    scale[o] = a;
    shift[o] = bb[o] - a * (float)m;
  }
}

// ---------- 5) BN1 reduce (inline) + apply + relu + e2p + bf16 hi/lo split + |x1|^2 ----------
__global__ void __launch_bounds__(256) k_bn1_apply(const float* __restrict__ hmax1, const float* __restrict__ hmin1,
                            const float* __restrict__ stats1sh,
                            const float* __restrict__ bn1g, const float* __restrict__ bn1b,
                            float* __restrict__ xp2,
                            unsigned short* __restrict__ x1h, unsigned short* __restrict__ x1l,
                            float* __restrict__ xx1) {
  int b = blockIdx.x >> 4, nc = blockIdx.x & 15;
  int c = threadIdx.x & 63, sub = threadIdx.x >> 6;
  int n0 = nc*64 + sub*16;
  // inline BN1 stat reduction: 64 fp32 slots for this thread's channel, f64 accumulation
  // (replaces the k_bn_reduce<<<64>>> launch; 32KB region is L2-resident, reads broadcast)
  double s = 0.0, s2 = 0.0;
  for (int sl = 0; sl < 64; sl++) {
    s  += (double)stats1sh[((size_t)sl*64 + c)*2];
    s2 += (double)stats1sh[((size_t)sl*64 + c)*2 + 1];
  }
  double m = s / 327680.0;
  double v = s2 / 327680.0 - m*m;
  float a = bn1g[c] / sqrtf((float)v + 1e-5f);
  float t = bn1b[c] - a * (float)m;
  #pragma unroll
  for (int i = 0; i < 16; i++) {
    int p = b*1024 + n0 + i;
    float h = (a >= 0.f) ? hmax1[(size_t)p*64 + c] : hmin1[(size_t)p*64 + c];
    float x1 = fmaxf(fmaf(a, h, t), 0.f);
    // split-bf16: x1 = hi + lo with both bf16; dot via 4-term MFMA is fp32-accurate to ~2^-17
    unsigned short hb = f2bf(x1);
    x1h[(size_t)p*64 + c] = hb;
    x1l[(size_t)p*64 + c] = f2bf(x1 - bf2f(hb));
    float n2 = x1*x1;
    #pragma unroll
    for (int off = 32; off > 0; off >>= 1) n2 += __shfl_xor(n2, off);
    if (c == 0) xx1[p] = n2;
    float n1 = fmaxf(sqrtf(n2), 1e-15f);
    float th = tanhf(0.1f * n1);
    float sc = th / (0.1f * n1);
    float ny = fmaxf(th * 10.0f, 1e-15f);
    float mxn = (1.0f - 4e-3f) / 0.1f;
    if (ny > mxn) sc *= mxn / ny;
    xp2[(size_t)p*64 + c] = sc * x1;
  }
}

// ---------- 6) knn2 v12: register scan + bitonic top-k + register-linear rank-merge ----------
__global__ void __launch_bounds__(256) k_knn2g(const unsigned short* __restrict__ x1h,
        const unsigned short* __restrict__ x1l,
        const float* __restrict__ xx1, unsigned* __restrict__ keypart2) {
  __shared__ unsigned LU[5376];                  // 4 lists x 64q x 21 (21 KB)
  __shared__ unsigned MU[2688];                  // 2 merged x 64q x 21 (10.5 KB)
  int tid = threadIdx.x;
  int bi = blockIdx.x;
  int blk = ((bi & 7) << 7) + (bi >> 3);     // XCD-affine swizzle (1024 = 8*128, bijective)
  int b = blk >> 6, qc = (blk >> 2) & 15, cc = blk & 3;
  int qbase = qc*64, ccbase = cc*256;
  int wave = tid >> 6, lane = tid & 63;
  int lm = lane & 15, kq = lane >> 4;
  const size_t base = (size_t)b * 65536;     // b*1024*64

  // Q fragments (hi/lo) held in registers for the whole kernel: 4 qtiles x 2 ksteps
  bf16x8 Qh[4][2], Ql[4][2];
  #pragma unroll
  for (int qt = 0; qt < 4; qt++) {
    size_t ro = base + (size_t)(qbase + qt*16 + lm)*64 + kq*8;
    #pragma unroll
    for (int ks = 0; ks < 2; ks++) {
      Qh[qt][ks] = *((const bf16x8*)(x1h + ro + ks*32));
      Ql[qt][ks] = *((const bf16x8*)(x1l + ro + ks*32));
    }
  }
  unsigned kl[KNN];
  #pragma unroll
  for (int i = 0; i < KNN; i++) kl[i] = 0u;

  for (int st = 0; st < 4; ++st) {
    int cb0 = ccbase + st*64;
    // A fragments: this wave's 16 candidates, hi/lo
    size_t co = base + (size_t)(cb0 + wave*16 + lm)*64 + kq*8;
    bf16x8 Ah[2], Al[2];
    #pragma unroll
    for (int ks = 0; ks < 2; ks++) {
      Ah[ks] = *((const bf16x8*)(x1h + co + ks*32));
      Al[ks] = *((const bf16x8*)(x1l + co + ks*32));
    }
    float4 xxc = *((const float4*)(xx1 + b*1024 + cb0 + wave*16 + kq*4));
    f32x4 acc[4];
    #pragma unroll
    for (int qt = 0; qt < 4; qt++) acc[qt] = (f32x4){0.f, 0.f, 0.f, 0.f};
    #pragma unroll
    for (int ks = 0; ks < 2; ks++) {
      #pragma unroll
      for (int qt = 0; qt < 4; qt++) {
        acc[qt] = __builtin_amdgcn_mfma_f32_16x16x32_bf16(Ah[ks], Qh[qt][ks], acc[qt], 0, 0, 0);
        acc[qt] = __builtin_amdgcn_mfma_f32_16x16x32_bf16(Ah[ks], Ql[qt][ks], acc[qt], 0, 0, 0);
        acc[qt] = __builtin_amdgcn_mfma_f32_16x16x32_bf16(Al[ks], Qh[qt][ks], acc[qt], 0, 0, 0);
        acc[qt] = __builtin_amdgcn_mfma_f32_16x16x32_bf16(Al[ks], Ql[qt][ks], acc[qt], 0, 0, 0);
      }
    }
    // dist adjust while layout is [qt][cand r of own kq group]: xxcv[r] matches cand kq*4+r
    // (-xxq omitted: constant per query row, rank-invariant)
    f32x4 xxv = (f32x4){xxc.x, xxc.y, xxc.z, xxc.w};
    #pragma unroll
    for (int qt = 0; qt < 4; qt++) acc[qt] = acc[qt]*2.0f - xxv;
    // 4x4 cross-lane block transpose within {lm, lm+16, lm+32, lm+48}:
    // after: acc[qt][r] = D[lane][qt*4+r]
    {
      f32x4 s0, s1, r0, r1;
      bool h1 = (kq & 1) != 0;
      if (h1) { s0 = acc[0]; s1 = acc[2]; } else { s0 = acc[1]; s1 = acc[3]; }
      #pragma unroll
      for (int e = 0; e < 4; e++) { r0[e] = __shfl_xor(s0[e], 16); r1[e] = __shfl_xor(s1[e], 16); }
      if (h1) { acc[0] = r0; acc[2] = r1; } else { acc[1] = r0; acc[3] = r1; }
      bool h2 = (kq & 2) != 0;
      if (h2) { s0 = acc[0]; s1 = acc[1]; } else { s0 = acc[2]; s1 = acc[3]; }
      #pragma unroll
      for (int e = 0; e < 4; e++) { r0[e] = __shfl_xor(s0[e], 32); r1[e] = __shfl_xor(s1[e], 32); }
      if (h2) { acc[0] = r0; acc[1] = r1; } else { acc[2] = r0; acc[3] = r1; }
    }
    // keys for this stage's 16 candidates (unconditional), then bitonic top-k update
    unsigned bb[16];
    #pragma unroll
    for (int c = 0; c < 16; c++)
      bb[c] = knnkey(acc[c >> 2][c & 3], cb0 + wave*16 + c);
    topk_bitonic16(kl, bb);
  }
  // publish per-wave lists
  #pragma unroll
  for (int i = 0; i < KNN; i++) LU[wave*1344 + lane*21 + i] = kl[i];
  __syncthreads();
  // merge L1: (L0,L1)->M0, (L2,L3)->M1.  256 units = (pair, side, q); register-linear rank.
  {
    int pair = tid >> 7, side = (tid >> 6) & 1, q = tid & 63;
    const unsigned* own = LU + (pair*2 + side)*1344 + q*21;
    const unsigned* oth = LU + (pair*2 + 1 - side)*1344 + q*21;
    unsigned ow[KNN], ot[KNN];
    #pragma unroll
    for (int i = 0; i < KNN; i++) { ow[i] = own[i]; ot[i] = oth[i]; }
    unsigned* dst = MU + pair*1344 + q*21;
    #pragma unroll
    for (int i = 0; i < KNN; i++) {
      int r = i;
      #pragma unroll
      for (int j = 0; j < KNN; j++) r += (ot[j] > ow[i]) ? 1 : 0;
      if (r < KNN) dst[r] = ow[i];
    }
  }
  __syncthreads();
  // merge L2: (M0,M1) -> keypart2.  128 units = (side, q); register-linear rank.
  if (tid < 128) {
    int side = tid >> 6, q = tid & 63;
    const unsigned* own = MU + side*1344 + q*21;
    const unsigned* oth = MU + (1 - side)*1344 + q*21;
    unsigned ow[KNN], ot[KNN];
    #pragma unroll
    for (int i = 0; i < KNN; i++) { ow[i] = own[i]; ot[i] = oth[i]; }
    unsigned* pe = keypart2 + (size_t)(b*N_ + qbase + q)*80 + cc*20;
    #pragma unroll
    for (int i = 0; i < KNN; i++) {
      int r = i;
      #pragma unroll
      for (int j = 0; j < KNN; j++) r += (ot[j] > ow[i]) ? 1 : 0;
      if (r < KNN) pe[r] = ow[i];
    }
  }
}

// ---------- 9) conv2 via bf16 MFMA v12: streaming-count merge + fp32 center + fp16 outs ----------
__global__ void __launch_bounds__(256) k_conv2m(const float* __restrict__ xp2,
    const unsigned* __restrict__ keypart2, const unsigned short* __restrict__ w2h,
    unsigned short* __restrict__ hmax2, unsigned short* __restrict__ hmin2,
    float* __restrict__ stats2sh) {
  __shared__ __align__(16) short Abf[80*136];
  __shared__ __align__(16) float Cf[4][64];      // fp32 centers for Mobius math
  __shared__ float Yc[4];
  __shared__ int nbr[80];                        // logical order [pt*20 + k]
  __shared__ unsigned keybuf[320];               // 4 pairs x 80 keys
  int tid = threadIdx.x;
  int bi = blockIdx.x;
  int g512 = ((bi & 7) << 9) + (bi >> 3);
  int p0 = g512 * 4;
  int b = p0 >> 10;
  // Region A: stage merge keys (all threads) + center rows/Y2 (first wave) concurrently
  for (int e = tid; e < 320; e += 256) keybuf[e] = keypart2[(size_t)p0*80 + e];
  if (tid < 64) {
    int pt = tid >> 4, qq = tid & 15;
    float4 cv = *((const float4*)(xp2 + (size_t)(p0 + pt)*64) + qq);
    *((float4*)&Cf[pt][qq*4]) = cv;
    float y2 = cv.x*cv.x + cv.y*cv.y + cv.z*cv.z + cv.w*cv.w;
    #pragma unroll
    for (int off = 8; off > 0; off >>= 1) y2 += __shfl_xor(y2, off);
    if (qq == 0) Yc[pt] = y2;
    ushort4 cb;
    cb.x = f2bf(cv.x); cb.y = f2bf(cv.y); cb.z = f2bf(cv.z); cb.w = f2bf(cv.w);
    // replicate center into the 20 MFMA rows of this point: rows a*16 + pt*4 + j
    #pragma unroll
    for (int a = 0; a < 5; a++)
      #pragma unroll
      for (int j2 = 0; j2 < 4; j2++)
        *((ushort4*)(Abf + (a*16 + pt*4 + j2)*136 + 64 + qq*4)) = cb;
  }
  __syncthreads();
  // Region B: parallel 4-way merge via streaming count over all 80 keys (unique keys:
  // own sorted-desc list contributes exactly the own index). 80 pipelined LDS reads/unit.
  for (int e = tid; e < 320; e += 256) {
    int pt = e / 80;
    int rem = e - pt*80;
    const unsigned* LB = keybuf + pt*80;
    unsigned v = LB[rem];
    int rank = 0;
    #pragma unroll
    for (int j = 0; j < 80; j++) rank += (LB[j] > v) ? 1 : 0;
    if (rank < KNN) nbr[pt*20 + rank] = 1023 - (int)(v & 1023u);
  }
  __syncthreads();
  // Region C: gather + Mobius in one pass, all fp32 (center from Cf), single divide
  for (int e = tid; e < 80*16; e += 256) {
    int r = e >> 4, qq = e & 15;
    int q = (r >> 2) & 3;
    int L = 20*q + 4*(r >> 4) + (r & 3);
    float4 f = *((const float4*)(xp2 + (size_t)(b*N_ + nbr[L])*64) + qq);
    float4 cvf = *((const float4*)&Cf[q][qq*4]);
    float X2 = f.x*f.x + f.y*f.y + f.z*f.z + f.w*f.w;
    float XY = -(f.x*cvf.x + f.y*cvf.y + f.z*cvf.z + f.w*cvf.w);
    #pragma unroll
    for (int off = 8; off > 0; off >>= 1) {
      X2 += __shfl_xor(X2, off);
      XY += __shfl_xor(XY, off);
    }
    float Y2 = Yc[q];
    float den = fmaxf(1.0f + 0.02f*XY + 1e-4f*X2*Y2, 1e-15f);
    float inv = 1.0f / den;
    float s1 = (1.0f + 0.02f*XY + 0.01f*Y2) * inv;
    float s2 = (1.0f - 0.01f*X2) * inv;
    ushort4 mo;
    mo.x = f2bf(s1*f.x - s2*cvf.x);
    mo.y = f2bf(s1*f.y - s2*cvf.y);
    mo.z = f2bf(s1*f.z - s2*cvf.z);
    mo.w = f2bf(s1*f.w - s2*cvf.w);
    *((ushort4*)(Abf + r*136 + qq*4)) = mo;
  }
  __syncthreads();
  // Region D: MFMA + register epilogue (fp16 max/min stores, fp32 stats atomics)
  int wave = tid >> 6, lane = tid & 63;
  int quad = lane >> 4, lm = lane & 15;
  int colbase = wave*48;
  f32x4 acc[5][3];
  #pragma unroll
  for (int rt = 0; rt < 5; rt++)
    #pragma unroll
    for (int cj = 0; cj < 3; cj++) acc[rt][cj] = (f32x4){0.f, 0.f, 0.f, 0.f};
  #pragma unroll
  for (int kt = 0; kt < 4; kt++) {
    int k0 = kt*32 + quad*8;
    bf16x8 bf[3];
    #pragma unroll
    for (int cj = 0; cj < 3; cj++)
      bf[cj] = *((const bf16x8*)(w2h + (size_t)(colbase + cj*16 + lm)*128 + k0));
    bf16x8 af[5];
    #pragma unroll
    for (int rt = 0; rt < 5; rt++)
      af[rt] = *((const bf16x8*)(Abf + (rt*16 + lm)*136 + k0));
    #pragma unroll
    for (int rt = 0; rt < 5; rt++)
      #pragma unroll
      for (int cj = 0; cj < 3; cj++)
        acc[rt][cj] = __builtin_amdgcn_mfma_f32_16x16x32_bf16(af[rt], bf[cj], acc[rt][cj], 0, 0, 0);
  }
  #pragma unroll
  for (int cj = 0; cj < 3; cj++) {
    int o = colbase + cj*16 + lm;
    float s = 0.f, s2 = 0.f, mx = -__builtin_inff(), mn = __builtin_inff();
    #pragma unroll
    for (int rt = 0; rt < 5; rt++) {
      #pragma unroll
      for (int reg = 0; reg < 4; reg++) {
        float h = acc[rt][cj][reg];
        s += h; s2 += h*h;
        mx = fmaxf(mx, h); mn = fminf(mn, h);
      }
    }
    hmax2[(size_t)(p0 + quad)*192 + o] = f2h(mx);
    hmin2[(size_t)(p0 + quad)*192 + o] = f2h(mn);
    s  += __shfl_xor(s, 16);  s  += __shfl_xor(s, 32);
    s2 += __shfl_xor(s2, 16); s2 += __shfl_xor(s2, 32);
    if (lane < 16) {
      float* dst = stats2sh + ((size_t)(bi & 255)*192 + o)*2;
      atomicAdd(dst, s); atomicAdd(dst + 1, s2);
    }
  }
}

// ---------- 11) conv3 via bf16 MFMA: ch0-63 from x1h (already bf16), ch64-255 from fp16 hmax2/hmin2 ----------
__global__ void __launch_bounds__(256) k_conv3m(
   const unsigned short* __restrict__ x1h,
   const unsigned short* __restrict__ hmax2, const unsigned short* __restrict__ hmin2,
   const float* __restrict__ scale2, const float* __restrict__ shift2,
   const unsigned short* __restrict__ wt3h, float* __restrict__ stats3sh,
   unsigned* __restrict__ hmax3u, unsigned* __restrict__ hmin3u) {
  __shared__ short As[64*264];
  int tid = threadIdx.x;
  int mt = blockIdx.x >> 2, cb = blockIdx.x & 3;
  int rowbase = mt*64;
  int b = rowbase >> 10;
  int c4 = tid & 63;
  float4 sc, sh;
  if (c4 >= 16) {
    sc = *((const float4*)(scale2 + (c4*4 - 64)));
    sh = *((const float4*)(shift2 + (c4*4 - 64)));
  }
  #pragma unroll 4
  for (int i = 0; i < 16; i++) {
    int r = (tid >> 6) + i*4;
    int p = rowbase + r;
    if (c4 < 16) {
      // channels 0..63: x1h already holds f2bf(relu(BN1(h))) in (B,N,64) layout
      *((ushort4*)(As + r*264 + c4*4)) =
        *((const ushort4*)(x1h + (size_t)p*64 + c4*4));
    } else {
      ushort4 hx4 = *((const ushort4*)(hmax2 + (size_t)p*192 + (c4*4 - 64)));
      ushort4 hn4 = *((const ushort4*)(hmin2 + (size_t)p*192 + (c4*4 - 64)));
      ushort4 o4;
      o4.x = f2bf(fmaxf(fmaf(sc.x, (sc.x >= 0.f ? h2f(hx4.x) : h2f(hn4.x)), sh.x), 0.f));
      o4.y = f2bf(fmaxf(fmaf(sc.y, (sc.y >= 0.f ? h2f(hx4.y) : h2f(hn4.y)), sh.y), 0.f));
      o4.z = f2bf(fmaxf(fmaf(sc.z, (sc.z >= 0.f ? h2f(hx4.z) : h2f(hn4.z)), sh.z), 0.f));
      o4.w = f2bf(fmaxf(fmaf(sc.w, (sc.w >= 0.f ? h2f(hx4.w) : h2f(hn4.w)), sh.w), 0.f));
      *((ushort4*)(As + r*264 + c4*4)) = o4;
    }
  }
  __syncthreads();
  int wave = tid >> 6, lane = tid & 63;
  int quad = lane >> 4, lm = lane & 15;
  int colbase = cb*256 + wave*64;
  f32x4 acc[4][4];
  #pragma unroll
  for (int ri = 0; ri < 4; ri++)
    #pragma unroll
    for (int cj = 0; cj < 4; cj++) acc[ri][cj] = (f32x4){0.f, 0.f, 0.f, 0.f};
  for (int kt = 0; kt < 8; kt++) {
    int k0 = kt*32 + quad*8;
    bf16x8 bf[4];
    #pragma unroll
    for (int cj = 0; cj < 4; cj++)
      bf[cj] = *((const bf16x8*)(wt3h + (size_t)(colbase + cj*16 + lm)*256 + k0));
    bf16x8 af[4];
    #pragma unroll
    for (int ri = 0; ri < 4; ri++)
      af[ri] = *((const bf16x8*)(As + (ri*16 + lm)*264 + k0));
    #pragma unroll
    for (int ri = 0; ri < 4; ri++)
      #pragma unroll
      for (int cj = 0; cj < 4; cj++)
        acc[ri][cj] = __builtin_amdgcn_mfma_f32_16x16x32_bf16(af[ri], bf[cj], acc[ri][cj], 0, 0, 0);
  }
  #pragma unroll
  for (int cj = 0; cj < 4; cj++) {
    float s = 0.f, s2 = 0.f, mx = -__builtin_inff(), mn = __builtin_inff();
    #pragma unroll
    for (int ri = 0; ri < 4; ri++) {
      #pragma unroll
      for (int reg = 0; reg < 4; reg++) {
        float h = acc[ri][cj][reg];
        s += h; s2 += h*h; mx = fmaxf(mx, h); mn = fminf(mn, h);
      }
    }
    s  += __shfl_xor(s, 16);  s  += __shfl_xor(s, 32);
    s2 += __shfl_xor(s2, 16); s2 += __shfl_xor(s2, 32);
    mx = fmaxf(mx, __shfl_xor(mx, 16)); mx = fmaxf(mx, __shfl_xor(mx, 32));
    mn = fminf(mn, __shfl_xor(mn, 16)); mn = fminf(mn, __shfl_xor(mn, 32));
    if (lane < 16) {
      int col = colbase + cj*16 + lane;
      float* dst = stats3sh + ((size_t)(blockIdx.x & 63)*1024 + col)*2;
      atomicAdd(dst, s);
      atomicAdd(dst + 1, s2);
      atomicMax(hmax3u + b*1024 + col, fkey(mx));
      atomicMin(hmin3u + b*1024 + col, fkey(mn));
    }
  }
}

// ---------- 12) head, split for weight-read parallelism ----------
__device__ float blk_reduce(float v, float* red, int tid) {
  red[tid] = v; __syncthreads();
  for (int st = 128; st > 0; st >>= 1) {
    if (tid < st) red[tid] += red[tid + st];
    __syncthreads();
  }
  float r = red[0]; __syncthreads();
  return r;
}

__global__ void __launch_bounds__(256) k_head1(const unsigned* __restrict__ hmax3u,
    const unsigned* __restrict__ hmin3u,
    const float* __restrict__ scale3, const float* __restrict__ shift3,
    const float* __restrict__ fc1w, const float* __restrict__ fc1b,
    float* __restrict__ h1buf) {
  __shared__ __align__(16) float V[1024];
  int b = blockIdx.x >> 5, oc = blockIdx.x & 31;
  int tid = threadIdx.x;
  for (int o = tid; o < 1024; o += 256) {
    float a = scale3[o];
    unsigned u = (a >= 0.f) ? hmax3u[b*1024 + o] : hmin3u[b*1024 + o];
    V[o] = fmaxf(fmaf(a, fkeyinv(u), shift3[o]), 0.f);
  }
  __syncthreads();
  int ty = tid >> 4, tx = tid & 15;
  int o = oc*16 + ty;
  const float4* wr = (const float4*)(fc1w + (size_t)o*1024) + tx*16;
  const float4* vv = (const float4*)V + tx*16;
  float s = 0.f;
  #pragma unroll
  for (int i = 0; i < 16; i++) {
    float4 w = wr[i]; float4 v = vv[i];
    s = fmaf(w.x, v.x, s); s = fmaf(w.y, v.y, s);
    s = fmaf(w.z, v.z, s); s = fmaf(w.w, v.w, s);
  }
  s += __shfl_xor(s, 1); s += __shfl_xor(s, 2);
  s += __shfl_xor(s, 4); s += __shfl_xor(s, 8);
  if (tx == 0) h1buf[b*512 + o] = s + fc1b[o];
}

__global__ void __launch_bounds__(256) k_head2(const float* __restrict__ h1buf,
    const float* __restrict__ ln1g, const float* __restrict__ ln1b,
    const float* __restrict__ fc2w, const float* __restrict__ fc2b,
    float* __restrict__ h2buf) {
  __shared__ __align__(16) float H1[512];
  __shared__ float red[256];
  int b = blockIdx.x >> 3, oc = blockIdx.x & 7;
  int tid = threadIdx.x;
  float v0 = h1buf[b*512 + tid], v1 = h1buf[b*512 + 256 + tid];
  float s = blk_reduce(v0 + v1, red, tid);
  float s2 = blk_reduce(v0*v0 + v1*v1, red, tid);
  float m = s / 512.f;
  float var = s2 / 512.f - m*m;
  float inv = 1.0f / sqrtf(var + 1e-5f);
  H1[tid] = fmaxf((v0 - m)*inv*ln1g[tid] + ln1b[tid], 0.f);
  H1[256 + tid] = fmaxf((v1 - m)*inv*ln1g[256 + tid] + ln1b[256 + tid], 0.f);
  __syncthreads();
  int ty = tid >> 3, tx = tid & 7;
  int o = oc*32 + ty;
  const float4* wr = (const float4*)(fc2w + (size_t)o*512) + tx*16;
  const float4* vv = (const float4*)H1 + tx*16;
  float t = 0.f;
  #pragma unroll
  for (int i = 0; i < 16; i++) {
    float4 w = wr[i]; float4 v = vv[i];
    t = fmaf(w.x, v.x, t); t = fmaf(w.y, v.y, t);
    t = fmaf(w.z, v.z, t); t = fmaf(w.w, v.w, t);
  }
  t += __shfl_xor(t, 1); t += __shfl_xor(t, 2); t += __shfl_xor(t, 4);
  if (tx == 0) h2buf[b*256 + o] = t + fc2b[o];
}

__global__ void __launch_bounds__(256) k_head3(const float* __restrict__ h2buf,
    const float* __restrict__ ln2g, const float* __restrict__ ln2b,
    const float* __restrict__ outw, const float* __restrict__ outb,
    float* __restrict__ out) {
  __shared__ __align__(16) float H2[256];
  __shared__ float red[256];
  int b = blockIdx.x, tid = threadIdx.x;
  float h2v = h2buf[b*256 + tid];
  float ss = blk_reduce(h2v, red, tid);
  float ss2 = blk_reduce(h2v*h2v, red, tid);
  float m2 = ss / 256.f;
  float var2 = ss2 / 256.f - m2*m2;
  float inv2 = 1.0f / sqrtf(var2 + 1e-5f);
  H2[tid] = fmaxf((h2v - m2)*inv2*ln2g[tid] + ln2b[tid], 0.f);
  __syncthreads();
  if (tid < 40) {
    const float4* wr = (const float4*)(outw + (size_t)tid*256);
    float t = 0.f;
    for (int c4 = 0; c4 < 64; c4++) {
      float4 w = wr[c4]; float4 vv = ((const float4*)H2)[c4];
      t = fmaf(w.x, vv.x, t); t = fmaf(w.y, vv.y, t);
      t = fmaf(w.z, vv.z, t); t = fmaf(w.w, vv.w, t);
    }
    red[tid] = t + outb[tid];
  }
  __syncthreads();
  if (tid == 0) {
    float mx = -__builtin_inff();
    for (int i2 = 0; i2 < 40; i2++) mx = fmaxf(mx, red[i2]);
    float se = 0.f;
    for (int i2 = 0; i2 < 40; i2++) se += expf(red[i2] - mx);
    float lse = mx + logf(se);
    for (int i2 = 0; i2 < 40; i2++) out[b*40 + i2] = red[i2] - lse;
  }
}

extern "C" void kernel_launch(void* const* d_in, const int* in_sizes, int n_in,
                              void* d_out, int out_size, void* d_ws, size_t ws_size,
                              hipStream_t stream) {
  (void)in_sizes; (void)n_in; (void)out_size; (void)ws_size;
  const float* x    = (const float*)d_in[0];
  const float* w1   = (const float*)d_in[1];
  const float* bn1g = (const float*)d_in[2];
  const float* bn1b = (const float*)d_in[3];
  const float* w2   = (const float*)d_in[4];
  const float* bn2g = (const float*)d_in[5];
  const float* bn2b = (const float*)d_in[6];
  const float* w3   = (const float*)d_in[7];
  const float* bn3g = (const float*)d_in[8];
  const float* bn3b = (const float*)d_in[9];
  const float* fc1w = (const float*)d_in[10];
  const float* fc1b = (const float*)d_in[11];
  const float* ln1g = (const float*)d_in[12];
  const float* ln1b = (const float*)d_in[13];
  const float* fc2w = (const float*)d_in[14];
  const float* fc2b = (const float*)d_in[15];
  const float* ln2g = (const float*)d_in[16];
  const float* ln2b = (const float*)d_in[17];
  const float* outw = (const float*)d_in[18];
  const float* outb = (const float*)d_in[19];
  float* out = (float*)d_out;

  float* ws = (float*)d_ws;
  size_t off = 0;
  float* xp1   = ws + off; off += 49152;
  float* hmax1 = ws + off; off += 1048576;
  float* hmin1 = ws + off; off += 1048576;
  float* xp2   = ws + off; off += 1048576;
  float* hmax2f = ws + off; off += 3145728;  // holds keypartA (knn1 partials) then fp16 hmax2
  float* hmin2f = ws + off; off += 3145728;  // fp16 hmin2
  unsigned* keypart2 = (unsigned*)(ws + off); off += 1310720;  // knn2 partials, 80/pt
  unsigned short* w2h = (unsigned short*)(ws + off); off += 24576;
  unsigned short* wt3h = (unsigned short*)(ws + off); off += 131072;
  float* x1bf  = ws + off; off += 1048576;   // x1 bf16 hi (2MB) + lo (2MB), (B,N,64) layout
  float* xx1   = ws + off; off += 16384;
  float* h1buf = ws + off; off += 8192;
  float* h2buf = ws + off; off += 4096;
  float* scale1 = ws + off; off += 64;   // (unused; BN1 reduce now inlined in k_bn1_apply)
  float* shift1 = ws + off; off += 64;
  float* scale2 = ws + off; off += 192;
  float* shift2 = ws + off; off += 192;
  float* scale3 = ws + off; off += 1024;
  float* shift3 = ws + off; off += 1024;
  float* stats1sh = ws + off;                         // fp32 stats
  float* stats2sh = stats1sh + 64*64*2;
  float* stats3sh = stats2sh + (size_t)256*192*2;
  unsigned* hmax3u = (unsigned*)(stats3sh + (size_t)64*1024*2);
  unsigned* hmin3u = hmax3u + 16384;
  unsigned* keypartA = (unsigned*)hmax2f;
  unsigned short* x1h = (unsigned short*)x1bf;
  unsigned short* x1l = x1h + 1048576;
  unsigned short* hmax2 = (unsigned short*)hmax2f;
  unsigned short* hmin2 = (unsigned short*)hmin2f;
  (void)scale1; (void)shift1;

  // workspace init is folded into k_prep_knn1 (zeroes stats1+stats2+stats3+hmax3u = 253952 u32,
  // sets hmin3u to 0xFF). Stream ordering guarantees visibility to all consumer kernels.
  k_prep_knn1<<<1536, 256, 0, stream>>>(x, xp1, w2, w3, w2h, wt3h, keypartA,
                                        (unsigned*)stats1sh, hmin3u);
  k_conv1<<<1024, 256, 0, stream>>>(xp1, keypartA, w1, hmax1, hmin1, stats1sh);
  k_bn1_apply<<<256, 256, 0, stream>>>(hmax1, hmin1, stats1sh, bn1g, bn1b, xp2, x1h, x1l, xx1);
  k_knn2g<<<1024, 256, 0, stream>>>(x1h, x1l, xx1, keypart2);
  k_conv2m<<<4096, 256, 0, stream>>>(xp2, keypart2, w2h, hmax2, hmin2, stats2sh);
  k_bn_reduce<<<192, 64, 0, stream>>>(stats2sh, 192, 256, 327680.0, bn2g, bn2b, scale2, shift2);
  k_conv3m<<<1024, 256, 0, stream>>>(x1h, hmax2, hmin2, scale2, shift2,
                                     wt3h, stats3sh, hmax3u, hmin3u);
  k_bn_reduce<<<1024, 64, 0, stream>>>(stats3sh, 1024, 64, 16384.0, bn3g, bn3b, scale3, shift3);
  k_head1<<<512, 256, 0, stream>>>(hmax3u, hmin3u, scale3, shift3, fc1w, fc1b, h1buf);
  k_head2<<<128, 256, 0, stream>>>(h1buf, ln1g, ln1b, fc2w, fc2b, h2buf);
  k_head3<<<16, 256, 0, stream>>>(h2buf, ln2g, ln2b, outw, outb, out);
}